// Round 1
// baseline (1321.168 us; speedup 1.0000x reference)
//
#include <hip/hip_runtime.h>
#include <math.h>

#define B_ 4
#define T_ 2048
#define D_ 512
#define H_ 8
#define DH_ 64
#define BT_ 8192
#define FF_ 2048
#define EPS_ 1e-5f
#define SCALE_ 0.04419417382415922f   // 512^-0.5

// ---------------------------------------------------------------------------
// LayerNorm: one wave per row of 512
// ---------------------------------------------------------------------------
__global__ __launch_bounds__(64) void ln_kernel(const float* __restrict__ X,
        const float* __restrict__ G, const float* __restrict__ Bb,
        float* __restrict__ Y)
{
    int row = blockIdx.x;
    int t = threadIdx.x;
    const float* xr = X + (size_t)row * D_;
    float4 v0 = *(const float4*)(xr + t * 4);
    float4 v1 = *(const float4*)(xr + 256 + t * 4);
    float sum = v0.x + v0.y + v0.z + v0.w + v1.x + v1.y + v1.z + v1.w;
    float ssq = v0.x*v0.x + v0.y*v0.y + v0.z*v0.z + v0.w*v0.w
              + v1.x*v1.x + v1.y*v1.y + v1.z*v1.z + v1.w*v1.w;
    #pragma unroll
    for (int off = 32; off > 0; off >>= 1) {
        sum += __shfl_down(sum, off);
        ssq += __shfl_down(ssq, off);
    }
    sum = __shfl(sum, 0);
    ssq = __shfl(ssq, 0);
    float mean = sum * (1.0f / D_);
    float var  = ssq * (1.0f / D_) - mean * mean;
    float rstd = rsqrtf(var + EPS_);

    float4 g0 = *(const float4*)(G + t * 4);
    float4 g1 = *(const float4*)(G + 256 + t * 4);
    float4 b0 = *(const float4*)(Bb + t * 4);
    float4 b1 = *(const float4*)(Bb + 256 + t * 4);
    float4 o0, o1;
    o0.x = (v0.x - mean) * rstd * g0.x + b0.x;
    o0.y = (v0.y - mean) * rstd * g0.y + b0.y;
    o0.z = (v0.z - mean) * rstd * g0.z + b0.z;
    o0.w = (v0.w - mean) * rstd * g0.w + b0.w;
    o1.x = (v1.x - mean) * rstd * g1.x + b1.x;
    o1.y = (v1.y - mean) * rstd * g1.y + b1.y;
    o1.z = (v1.z - mean) * rstd * g1.z + b1.z;
    o1.w = (v1.w - mean) * rstd * g1.w + b1.w;
    float* yr = Y + (size_t)row * D_;
    *(float4*)(yr + t * 4)       = o0;
    *(float4*)(yr + 256 + t * 4) = o1;
}

// ---------------------------------------------------------------------------
// Generic fp32 tiled GEMM: C[M,N] = A[M,K] @ B[K,N] (+bias)(+resid)(+relu)
// grid = (N/64, M/64), block = 256 (16x16, 4x4 per thread)
// ---------------------------------------------------------------------------
__global__ __launch_bounds__(256) void gemm_kernel(const float* __restrict__ A,
        const float* __restrict__ Bm, float* __restrict__ C,
        const float* __restrict__ bias, const float* __restrict__ resid,
        int M, int N, int K, int relu)
{
    __shared__ float As[16][68];
    __shared__ float Bs[16][68];
    int tid = threadIdx.x;
    int tx = tid & 15, ty = tid >> 4;
    int r0 = ty * 4, c0 = tx * 4;
    int m0 = blockIdx.y * 64, n0 = blockIdx.x * 64;

    int arow = tid >> 2;            // 0..63
    int acol = (tid & 3) * 4;       // 0,4,8,12
    int brow = tid >> 4;            // 0..15
    int bcol = (tid & 15) * 4;      // 0..60

    float acc[4][4] = {};

    for (int k0 = 0; k0 < K; k0 += 16) {
        float4 av = *(const float4*)(A + (size_t)(m0 + arow) * K + k0 + acol);
        float4 bv = *(const float4*)(Bm + (size_t)(k0 + brow) * N + n0 + bcol);
        As[acol + 0][arow] = av.x;
        As[acol + 1][arow] = av.y;
        As[acol + 2][arow] = av.z;
        As[acol + 3][arow] = av.w;
        *(float4*)(&Bs[brow][bcol]) = bv;
        __syncthreads();
        #pragma unroll
        for (int kk = 0; kk < 16; ++kk) {
            float4 a4 = *(const float4*)(&As[kk][r0]);
            float4 b4 = *(const float4*)(&Bs[kk][c0]);
            float avr[4] = {a4.x, a4.y, a4.z, a4.w};
            float bvr[4] = {b4.x, b4.y, b4.z, b4.w};
            #pragma unroll
            for (int i = 0; i < 4; ++i)
                #pragma unroll
                for (int j = 0; j < 4; ++j)
                    acc[i][j] += avr[i] * bvr[j];
        }
        __syncthreads();
    }

    #pragma unroll
    for (int i = 0; i < 4; ++i) {
        size_t row = (size_t)(m0 + r0 + i);
        size_t off = row * N + n0 + c0;
        float4 r4 = make_float4(acc[i][0], acc[i][1], acc[i][2], acc[i][3]);
        if (bias) {
            float4 b4 = *(const float4*)(bias + n0 + c0);
            r4.x += b4.x; r4.y += b4.y; r4.z += b4.z; r4.w += b4.w;
        }
        if (resid) {
            float4 x4 = *(const float4*)(resid + off);
            r4.x += x4.x; r4.y += x4.y; r4.z += x4.z; r4.w += x4.w;
        }
        if (relu) {
            r4.x = fmaxf(r4.x, 0.0f); r4.y = fmaxf(r4.y, 0.0f);
            r4.z = fmaxf(r4.z, 0.0f); r4.w = fmaxf(r4.w, 0.0f);
        }
        *(float4*)(C + off) = r4;
    }
}

// ---------------------------------------------------------------------------
// QKV: per-(matrix,head) GEMM [8192,512]@[512,64] -> [H,B*T,DH]
// grid = (BT/64, 24); blockIdx.y: sel = y>>3 (0=q,1=k,2=v), head = y&7
// ---------------------------------------------------------------------------
__global__ __launch_bounds__(256) void qkv_kernel(const float* __restrict__ Hb,
        const float* __restrict__ Wq, const float* __restrict__ Wk,
        const float* __restrict__ Wv,
        float* __restrict__ Qo, float* __restrict__ Ko, float* __restrict__ Vo)
{
    __shared__ float As[16][68];
    __shared__ float Bs[16][68];
    int tid = threadIdx.x;
    int tx = tid & 15, ty = tid >> 4;
    int r0 = ty * 4, c0 = tx * 4;
    int m0 = blockIdx.x * 64;
    int sel = blockIdx.y >> 3;
    int head = blockIdx.y & 7;
    const float* W = (sel == 0 ? Wq : (sel == 1 ? Wk : Wv)) + (size_t)head * D_ * DH_;
    float* Cout = (sel == 0 ? Qo : (sel == 1 ? Ko : Vo)) + (size_t)head * BT_ * DH_;

    int arow = tid >> 2;
    int acol = (tid & 3) * 4;
    int brow = tid >> 4;
    int bcol = (tid & 15) * 4;

    float acc[4][4] = {};

    for (int k0 = 0; k0 < D_; k0 += 16) {
        float4 av = *(const float4*)(Hb + (size_t)(m0 + arow) * D_ + k0 + acol);
        float4 bv = *(const float4*)(W + (size_t)(k0 + brow) * DH_ + bcol);
        As[acol + 0][arow] = av.x;
        As[acol + 1][arow] = av.y;
        As[acol + 2][arow] = av.z;
        As[acol + 3][arow] = av.w;
        *(float4*)(&Bs[brow][bcol]) = bv;
        __syncthreads();
        #pragma unroll
        for (int kk = 0; kk < 16; ++kk) {
            float4 a4 = *(const float4*)(&As[kk][r0]);
            float4 b4 = *(const float4*)(&Bs[kk][c0]);
            float avr[4] = {a4.x, a4.y, a4.z, a4.w};
            float bvr[4] = {b4.x, b4.y, b4.z, b4.w};
            #pragma unroll
            for (int i = 0; i < 4; ++i)
                #pragma unroll
                for (int j = 0; j < 4; ++j)
                    acc[i][j] += avr[i] * bvr[j];
        }
        __syncthreads();
    }

    #pragma unroll
    for (int i = 0; i < 4; ++i) {
        size_t off = (size_t)(m0 + r0 + i) * DH_ + c0;
        *(float4*)(Cout + off) = make_float4(acc[i][0], acc[i][1], acc[i][2], acc[i][3]);
    }
}

// ---------------------------------------------------------------------------
// Flash-style causal attention. grid = (T/64, B*H), block = 256.
// q,k,v in [H,B,T,DH]; output o in [B,T,H*DH].
// ---------------------------------------------------------------------------
__global__ __launch_bounds__(256) void attn_kernel(const float* __restrict__ Qb,
        const float* __restrict__ Kb, const float* __restrict__ Vb,
        float* __restrict__ Ob)
{
    __shared__ float Qt[64][68];   // Qt[d][r], pre-scaled
    __shared__ float Kt[64][68];   // Kt[d][c]
    __shared__ float Vs[64][68];   // Vs[token][d]
    __shared__ float Ps[64][68];   // Ps[r][c]
    __shared__ float red[64][17];
    __shared__ float mrow[64], lrow[64], arow[64];

    int tid = threadIdx.x;
    int tx = tid & 15, ty = tid >> 4;
    int r0 = ty * 4, c0 = tx * 4;
    int qi = blockIdx.x;
    int bh = blockIdx.y;
    int b = bh >> 3, h = bh & 7;
    const float* qbase = Qb + ((size_t)(h * B_ + b) * T_ + (size_t)qi * 64) * DH_;
    const float* kbase = Kb + (size_t)(h * B_ + b) * T_ * DH_;
    const float* vbase = Vb + (size_t)(h * B_ + b) * T_ * DH_;

    for (int idx = tid; idx < 1024; idx += 256) {
        int r = idx >> 4, c4 = (idx & 15) << 2;
        float4 q4 = *(const float4*)(qbase + r * DH_ + c4);
        Qt[c4 + 0][r] = q4.x * SCALE_;
        Qt[c4 + 1][r] = q4.y * SCALE_;
        Qt[c4 + 2][r] = q4.z * SCALE_;
        Qt[c4 + 3][r] = q4.w * SCALE_;
    }
    if (tid < 64) { mrow[tid] = -INFINITY; lrow[tid] = 0.0f; }

    float o[4][4] = {};

    for (int kj = 0; kj <= qi; ++kj) {
        __syncthreads();   // (A) prior iteration's Ps/Vs/Kt reads done
        for (int idx = tid; idx < 1024; idx += 256) {
            int r = idx >> 4, c4 = (idx & 15) << 2;
            float4 k4 = *(const float4*)(kbase + (size_t)(kj * 64 + r) * DH_ + c4);
            Kt[c4 + 0][r] = k4.x;
            Kt[c4 + 1][r] = k4.y;
            Kt[c4 + 2][r] = k4.z;
            Kt[c4 + 3][r] = k4.w;
            *(float4*)(&Vs[r][c4]) = *(const float4*)(vbase + (size_t)(kj * 64 + r) * DH_ + c4);
        }
        __syncthreads();   // (B)

        // S = Q K^T (Q pre-scaled)
        float s[4][4] = {};
        #pragma unroll 8
        for (int d = 0; d < DH_; ++d) {
            float4 qa = *(const float4*)(&Qt[d][r0]);
            float4 kb4 = *(const float4*)(&Kt[d][c0]);
            float qv[4] = {qa.x, qa.y, qa.z, qa.w};
            float kv[4] = {kb4.x, kb4.y, kb4.z, kb4.w};
            #pragma unroll
            for (int i = 0; i < 4; ++i)
                #pragma unroll
                for (int j = 0; j < 4; ++j)
                    s[i][j] += qv[i] * kv[j];
        }
        if (kj == qi) {
            #pragma unroll
            for (int i = 0; i < 4; ++i)
                #pragma unroll
                for (int j = 0; j < 4; ++j)
                    if (c0 + j > r0 + i) s[i][j] = -INFINITY;
        }

        // row max partials
        #pragma unroll
        for (int i = 0; i < 4; ++i) {
            float pm = fmaxf(fmaxf(s[i][0], s[i][1]), fmaxf(s[i][2], s[i][3]));
            red[r0 + i][tx] = pm;
        }
        __syncthreads();   // (C)
        if (tid < 64) {
            float mt = red[tid][0];
            #pragma unroll
            for (int j = 1; j < 16; ++j) mt = fmaxf(mt, red[tid][j]);
            float mo = mrow[tid];
            float mn = fmaxf(mo, mt);
            arow[tid] = __expf(mo - mn);
            mrow[tid] = mn;
        }
        __syncthreads();   // (D)

        // P = exp(S - m), row-sum partials
        #pragma unroll
        for (int i = 0; i < 4; ++i) {
            float mn = mrow[r0 + i];
            float p0 = __expf(s[i][0] - mn);
            float p1 = __expf(s[i][1] - mn);
            float p2 = __expf(s[i][2] - mn);
            float p3 = __expf(s[i][3] - mn);
            *(float4*)(&Ps[r0 + i][c0]) = make_float4(p0, p1, p2, p3);
            red[r0 + i][tx] = p0 + p1 + p2 + p3;
        }
        __syncthreads();   // (E)
        if (tid < 64) {
            float t2 = 0.0f;
            #pragma unroll
            for (int j = 0; j < 16; ++j) t2 += red[tid][j];
            lrow[tid] = lrow[tid] * arow[tid] + t2;
        }

        // O = alpha*O + P @ V
        #pragma unroll
        for (int i = 0; i < 4; ++i) {
            float a = arow[r0 + i];
            o[i][0] *= a; o[i][1] *= a; o[i][2] *= a; o[i][3] *= a;
        }
        #pragma unroll 4
        for (int c = 0; c < 64; ++c) {
            float4 vv = *(const float4*)(&Vs[c][c0]);
            float p0 = Ps[r0 + 0][c];
            float p1 = Ps[r0 + 1][c];
            float p2 = Ps[r0 + 2][c];
            float p3 = Ps[r0 + 3][c];
            o[0][0] += p0 * vv.x; o[0][1] += p0 * vv.y; o[0][2] += p0 * vv.z; o[0][3] += p0 * vv.w;
            o[1][0] += p1 * vv.x; o[1][1] += p1 * vv.y; o[1][2] += p1 * vv.z; o[1][3] += p1 * vv.w;
            o[2][0] += p2 * vv.x; o[2][1] += p2 * vv.y; o[2][2] += p2 * vv.z; o[2][3] += p2 * vv.w;
            o[3][0] += p3 * vv.x; o[3][1] += p3 * vv.y; o[3][2] += p3 * vv.z; o[3][3] += p3 * vv.w;
        }
    }
    __syncthreads();       // final lrow update visible

    float* obase = Ob + (size_t)(b * T_ + qi * 64) * D_ + h * DH_;
    #pragma unroll
    for (int i = 0; i < 4; ++i) {
        float inv = 1.0f / lrow[r0 + i];
        *(float4*)(obase + (size_t)(r0 + i) * D_ + c0) =
            make_float4(o[i][0] * inv, o[i][1] * inv, o[i][2] * inv, o[i][3] * inv);
    }
}

// ---------------------------------------------------------------------------
extern "C" void kernel_launch(void* const* d_in, const int* in_sizes, int n_in,
                              void* d_out, int out_size, void* d_ws, size_t ws_size,
                              hipStream_t stream) {
    (void)in_sizes; (void)n_in; (void)out_size; (void)ws_size;
    const float* x     = (const float*)d_in[0];
    const float* ln_g  = (const float*)d_in[1];
    const float* ln_b  = (const float*)d_in[2];
    const float* Wq    = (const float*)d_in[3];
    const float* Wk    = (const float*)d_in[4];
    const float* Wv    = (const float*)d_in[5];
    const float* Wproj = (const float*)d_in[6];
    const float* bproj = (const float*)d_in[7];
    const float* W1    = (const float*)d_in[8];
    const float* b1    = (const float*)d_in[9];
    const float* W2    = (const float*)d_in[10];
    const float* b2    = (const float*)d_in[11];
    float* out = (float*)d_out;

    float* ws_f = (float*)d_ws;
    // float offsets (16MB blocks of 4194304 floats):
    float* hbuf = ws_f;                  // h -> o -> h2 (serial reuse)
    float* qb   = ws_f + 4194304;
    float* kb   = ws_f + 8388608;
    float* vb   = ws_f + 12582912;
    float* ff1  = ws_f + 4194304;        // aliases q,k,v (dead after attention)
    float* x1   = ws_f + 20971520;       // [20971520, 25165824)

    // 1. h = LN(x)
    ln_kernel<<<dim3(BT_), dim3(64), 0, stream>>>(x, ln_g, ln_b, hbuf);
    // 2. q,k,v
    qkv_kernel<<<dim3(BT_ / 64, 24), dim3(256), 0, stream>>>(hbuf, Wq, Wk, Wv, qb, kb, vb);
    // 3. attention -> o (reuses hbuf)
    attn_kernel<<<dim3(T_ / 64, B_ * H_), dim3(256), 0, stream>>>(qb, kb, vb, hbuf);
    // 4. x1 = x + o @ Wproj + bproj
    gemm_kernel<<<dim3(D_ / 64, BT_ / 64), dim3(256), 0, stream>>>(
        hbuf, Wproj, x1, bproj, x, BT_, D_, D_, 0);
    // 5. h2 = LN(x1) (reuses hbuf)
    ln_kernel<<<dim3(BT_), dim3(64), 0, stream>>>(x1, ln_g, ln_b, hbuf);
    // 6. ff1 = relu(h2 @ W1 + b1)
    gemm_kernel<<<dim3(FF_ / 64, BT_ / 64), dim3(256), 0, stream>>>(
        hbuf, W1, ff1, b1, nullptr, BT_, FF_, D_, 1);
    // 7. out = x1 + ff1 @ W2 + b2
    gemm_kernel<<<dim3(D_ / 64, BT_ / 64), dim3(256), 0, stream>>>(
        ff1, W2, out, b2, x1, BT_, D_, FF_, 0);
}

// Round 2
// 382.122 us; speedup vs baseline: 3.4574x; 3.4574x over previous
//
#include <hip/hip_runtime.h>
#include <math.h>

#define B_ 4
#define T_ 2048
#define D_ 512
#define H_ 8
#define DH_ 64
#define BT_ 8192
#define FF_ 2048
#define EPS_ 1e-5f
#define SCALE_ 0.04419417382415922f   // 512^-0.5
#define NEGINF_ -1e30f

typedef short b16x8 __attribute__((ext_vector_type(8)));
typedef float f32x4 __attribute__((ext_vector_type(4)));

#define MFMA16(a, b, c) __builtin_amdgcn_mfma_f32_16x16x32_bf16(a, b, c, 0, 0, 0)

#define GLL16(gp, lp) \
    __builtin_amdgcn_global_load_lds((const __attribute__((address_space(1))) void*)(gp), \
                                     (__attribute__((address_space(3))) void*)(lp), 16, 0, 0)

// fp32 -> bf16 RNE (finite inputs)
static __device__ inline short f2bf(float f) {
    unsigned int u = __builtin_bit_cast(unsigned int, f);
    unsigned int r = (u + 0x7fffu + ((u >> 16) & 1u)) >> 16;
    return (short)r;
}

// ---------------------------------------------------------------------------
// LayerNorm: one wave per row of 512, fp32 in -> bf16 out
// ---------------------------------------------------------------------------
__global__ __launch_bounds__(64) void ln_kernel(const float* __restrict__ X,
        const float* __restrict__ G, const float* __restrict__ Bb,
        short* __restrict__ Y)
{
    int row = blockIdx.x;
    int t = threadIdx.x;
    const float* xr = X + (size_t)row * D_;
    float4 v0 = *(const float4*)(xr + t * 4);
    float4 v1 = *(const float4*)(xr + 256 + t * 4);
    float sum = v0.x + v0.y + v0.z + v0.w + v1.x + v1.y + v1.z + v1.w;
    float ssq = v0.x*v0.x + v0.y*v0.y + v0.z*v0.z + v0.w*v0.w
              + v1.x*v1.x + v1.y*v1.y + v1.z*v1.z + v1.w*v1.w;
    #pragma unroll
    for (int off = 32; off > 0; off >>= 1) {
        sum += __shfl_down(sum, off);
        ssq += __shfl_down(ssq, off);
    }
    sum = __shfl(sum, 0);
    ssq = __shfl(ssq, 0);
    float mean = sum * (1.0f / D_);
    float var  = ssq * (1.0f / D_) - mean * mean;
    float rstd = rsqrtf(var + EPS_);

    float4 g0 = *(const float4*)(G + t * 4);
    float4 g1 = *(const float4*)(G + 256 + t * 4);
    float4 b0 = *(const float4*)(Bb + t * 4);
    float4 b1 = *(const float4*)(Bb + 256 + t * 4);
    short4 o0, o1;
    o0.x = f2bf((v0.x - mean) * rstd * g0.x + b0.x);
    o0.y = f2bf((v0.y - mean) * rstd * g0.y + b0.y);
    o0.z = f2bf((v0.z - mean) * rstd * g0.z + b0.z);
    o0.w = f2bf((v0.w - mean) * rstd * g0.w + b0.w);
    o1.x = f2bf((v1.x - mean) * rstd * g1.x + b1.x);
    o1.y = f2bf((v1.y - mean) * rstd * g1.y + b1.y);
    o1.z = f2bf((v1.z - mean) * rstd * g1.z + b1.z);
    o1.w = f2bf((v1.w - mean) * rstd * g1.w + b1.w);
    short* yr = Y + (size_t)row * D_;
    *(short4*)(yr + t * 4)       = o0;
    *(short4*)(yr + 256 + t * 4) = o1;
}

// ---------------------------------------------------------------------------
// Tiled transpose + bf16 cast: in f32 [R][C] -> out bf16 [C][R], batched
// block (32,8), grid (C/32, R/32, batch)
// ---------------------------------------------------------------------------
__global__ __launch_bounds__(256) void transpose_kernel(const float* __restrict__ in,
        short* __restrict__ out, int R, int C, int inBatchStride, int outBatchStride)
{
    __shared__ float tile[32][33];
    const float* ip = in + (size_t)blockIdx.z * inBatchStride;
    short* op = out + (size_t)blockIdx.z * outBatchStride;
    int tx = threadIdx.x, ty = threadIdx.y;
    int c = blockIdx.x * 32 + tx;
    #pragma unroll
    for (int i = 0; i < 32; i += 8) {
        int r = blockIdx.y * 32 + ty + i;
        tile[ty + i][tx] = ip[(size_t)r * C + c];
    }
    __syncthreads();
    int rr = blockIdx.y * 32 + tx;
    #pragma unroll
    for (int i = 0; i < 32; i += 8) {
        int cc = blockIdx.x * 32 + ty + i;
        op[(size_t)cc * R + rr] = f2bf(tile[tx][ty + i]);
    }
}

// ---------------------------------------------------------------------------
// bf16 MFMA GEMM (m97 pattern): C[M,N] = A[M,K] @ Bt[N,K]^T
// 128x128 tile, BK=32, 256 threads (4 waves, each 64x64), global_load_lds.
// Epilogue: +bias, +resid, relu, fp32 or bf16 out.
// ---------------------------------------------------------------------------
__global__ __launch_bounds__(256) void mm_kernel(const short* __restrict__ A,
        const short* __restrict__ Bt, void* __restrict__ C,
        const float* __restrict__ bias, const float* __restrict__ resid,
        int M, int N, int K, int relu, int out_bf16)
{
    __shared__ short As[128 * 32];
    __shared__ short Bs[128 * 32];
    const int tid = threadIdx.x;
    const int wave = tid >> 6, lane = tid & 63;
    const int quad = lane >> 4, l15 = lane & 15;
    const int m0 = blockIdx.y * 128, n0 = blockIdx.x * 128;
    const int mw = (wave & 1) * 64, nw = (wave >> 1) * 64;

    f32x4 acc[4][4];
    #pragma unroll
    for (int i = 0; i < 4; ++i)
        #pragma unroll
        for (int j = 0; j < 4; ++j)
            acc[i][j] = (f32x4){0.f, 0.f, 0.f, 0.f};

    for (int k0 = 0; k0 < K; k0 += 32) {
        __syncthreads();
        #pragma unroll
        for (int r = 0; r < 2; ++r) {
            int c = r * 256 + tid;
            int row = c >> 2, seg = c & 3;
            GLL16(A + (size_t)(m0 + row) * K + k0 + seg * 8,
                  As + (size_t)(r * 256 + wave * 64) * 8);
            GLL16(Bt + (size_t)(n0 + row) * K + k0 + seg * 8,
                  Bs + (size_t)(r * 256 + wave * 64) * 8);
        }
        __syncthreads();
        b16x8 af[4], bf[4];
        #pragma unroll
        for (int i = 0; i < 4; ++i)
            af[i] = *(const b16x8*)(As + (mw + i * 16 + l15) * 32 + quad * 8);
        #pragma unroll
        for (int j = 0; j < 4; ++j)
            bf[j] = *(const b16x8*)(Bs + (nw + j * 16 + l15) * 32 + quad * 8);
        #pragma unroll
        for (int i = 0; i < 4; ++i)
            #pragma unroll
            for (int j = 0; j < 4; ++j)
                acc[i][j] = MFMA16(af[i], bf[j], acc[i][j]);
    }

    // epilogue: C-layout row = quad*4+reg, col = l15
    #pragma unroll
    for (int i = 0; i < 4; ++i) {
        #pragma unroll
        for (int r = 0; r < 4; ++r) {
            size_t row = (size_t)(m0 + mw + i * 16 + quad * 4 + r);
            #pragma unroll
            for (int j = 0; j < 4; ++j) {
                int col = n0 + nw + j * 16 + l15;
                float v = acc[i][j][r];
                if (bias)  v += bias[col];
                if (resid) v += resid[row * N + col];
                if (relu)  v = fmaxf(v, 0.0f);
                if (out_bf16) ((short*)C)[row * N + col] = f2bf(v);
                else          ((float*)C)[row * N + col] = v;
            }
        }
    }
}

// ---------------------------------------------------------------------------
// Flash attention, bf16 MFMA. qkv: [BT][1536] bf16 (q|k|v, each h*64+e).
// Out: [BT][512] bf16. grid (16, B*H); block handles q-tiles {x, 31-x}.
// Q/K staged via swizzled global_load_lds; V transposed via registers;
// P LDS round-trip (C-layout -> A-layout).
// ---------------------------------------------------------------------------
__global__ __launch_bounds__(256) void attn_kernel(const short* __restrict__ qkv,
        short* __restrict__ Ob)
{
    __shared__ short Qs[64 * 64];   // swizzled 16B chunks
    __shared__ short Ks[64 * 64];   // swizzled 16B chunks
    __shared__ short Vt[64 * 72];   // [dh][token], stride 72
    __shared__ short Ps[64 * 72];   // [qrow][token], stride 72

    const int tid = threadIdx.x;
    const int wave = tid >> 6, lane = tid & 63;
    const int quad = lane >> 4, l15 = lane & 15;
    const int bh = blockIdx.y;
    const int b = bh >> 3, h = bh & 7;
    const size_t tok0 = (size_t)b * T_;

    for (int rep = 0; rep < 2; ++rep) {
        const int qi = (rep == 0) ? (int)blockIdx.x : 31 - (int)blockIdx.x;
        __syncthreads();   // protect LDS from previous rep's readers
        // stage Q tile (swizzled chunks: slot = tok*8 + (seg ^ (tok&7)))
        #pragma unroll
        for (int r = 0; r < 2; ++r) {
            int c = r * 256 + tid;
            int tk = c >> 3;
            int seg = (c & 7) ^ (tk & 7);
            GLL16(qkv + (tok0 + qi * 64 + tk) * 1536 + h * 64 + seg * 8,
                  Qs + (size_t)(r * 256 + wave * 64) * 8);
        }

        float mrow[4], lrow[4];
        f32x4 oacc[4];
        #pragma unroll
        for (int r = 0; r < 4; ++r) { mrow[r] = NEGINF_; lrow[r] = 0.0f; }
        #pragma unroll
        for (int nt = 0; nt < 4; ++nt) oacc[nt] = (f32x4){0.f, 0.f, 0.f, 0.f};

        for (int kj = 0; kj <= qi; ++kj) {
            __syncthreads();
            // stage K tile (swizzled)
            #pragma unroll
            for (int r = 0; r < 2; ++r) {
                int c = r * 256 + tid;
                int tk = c >> 3;
                int seg = (c & 7) ^ (tk & 7);
                GLL16(qkv + (tok0 + kj * 64 + tk) * 1536 + 512 + h * 64 + seg * 8,
                      Ks + (size_t)(r * 256 + wave * 64) * 8);
            }
            // stage V transposed: thread = (seg s 0..7, token-pair tp 0..31)
            {
                int s = tid >> 5, tp = tid & 31;
                const short* g0 = qkv + (tok0 + kj * 64 + tp * 2) * 1536 + 1024 + h * 64 + s * 8;
                b16x8 v0 = *(const b16x8*)g0;
                b16x8 v1 = *(const b16x8*)(g0 + 1536);
                int* vo = (int*)Vt;
                #pragma unroll
                for (int e = 0; e < 8; ++e) {
                    unsigned int pk = (unsigned int)(unsigned short)v0[e]
                                    | ((unsigned int)(unsigned short)v1[e] << 16);
                    vo[(s * 8 + e) * 36 + tp] = pk;
                }
            }
            __syncthreads();

            // S = Q K^T  (16x16x32 MFMA, K-dim 64 = 2 steps)
            f32x4 sacc[4];
            #pragma unroll
            for (int nt = 0; nt < 4; ++nt) sacc[nt] = (f32x4){0.f, 0.f, 0.f, 0.f};
            b16x8 aq[2];
            #pragma unroll
            for (int kb = 0; kb < 2; ++kb) {
                int row = wave * 16 + l15;
                aq[kb] = *(const b16x8*)(Qs + (row * 8 + ((kb * 4 + quad) ^ (row & 7))) * 8);
            }
            #pragma unroll
            for (int nt = 0; nt < 4; ++nt) {
                int trow = nt * 16 + l15;
                #pragma unroll
                for (int kb = 0; kb < 2; ++kb) {
                    b16x8 bk = *(const b16x8*)(Ks + (trow * 8 + ((kb * 4 + quad) ^ (trow & 7))) * 8);
                    sacc[nt] = MFMA16(aq[kb], bk, sacc[nt]);
                }
            }

            // scale + causal mask; C-layout: row = wave*16+quad*4+r, col = nt*16+l15
            float p[4][4], mx[4];
            #pragma unroll
            for (int r = 0; r < 4; ++r) mx[r] = NEGINF_;
            #pragma unroll
            for (int nt = 0; nt < 4; ++nt)
                #pragma unroll
                for (int r = 0; r < 4; ++r) {
                    float s = sacc[nt][r] * SCALE_;
                    if (kj == qi && (nt * 16 + l15) > (wave * 16 + quad * 4 + r)) s = NEGINF_;
                    p[nt][r] = s;
                    mx[r] = fmaxf(mx[r], s);
                }
            // row max across the 16 lanes holding this row
            #pragma unroll
            for (int r = 0; r < 4; ++r) {
                mx[r] = fmaxf(mx[r], __shfl_xor(mx[r], 1));
                mx[r] = fmaxf(mx[r], __shfl_xor(mx[r], 2));
                mx[r] = fmaxf(mx[r], __shfl_xor(mx[r], 4));
                mx[r] = fmaxf(mx[r], __shfl_xor(mx[r], 8));
            }
            float alpha[4], rs[4];
            #pragma unroll
            for (int r = 0; r < 4; ++r) {
                float mn = fmaxf(mrow[r], mx[r]);
                alpha[r] = __expf(mrow[r] - mn);
                mrow[r] = mn;
                rs[r] = 0.0f;
            }
            #pragma unroll
            for (int nt = 0; nt < 4; ++nt)
                #pragma unroll
                for (int r = 0; r < 4; ++r) {
                    float e = __expf(p[nt][r] - mrow[r]);
                    p[nt][r] = e;
                    rs[r] += e;
                }
            #pragma unroll
            for (int r = 0; r < 4; ++r) {
                rs[r] += __shfl_xor(rs[r], 1);
                rs[r] += __shfl_xor(rs[r], 2);
                rs[r] += __shfl_xor(rs[r], 4);
                rs[r] += __shfl_xor(rs[r], 8);
                lrow[r] = lrow[r] * alpha[r] + rs[r];
            }
            // write P (bf16) to per-wave LDS strip; same-wave readback (DS in-order)
            #pragma unroll
            for (int nt = 0; nt < 4; ++nt)
                #pragma unroll
                for (int r = 0; r < 4; ++r)
                    Ps[(wave * 16 + quad * 4 + r) * 72 + nt * 16 + l15] = f2bf(p[nt][r]);
            // rescale O
            #pragma unroll
            for (int nt = 0; nt < 4; ++nt)
                #pragma unroll
                for (int r = 0; r < 4; ++r)
                    oacc[nt][r] *= alpha[r];
            // O += P @ V
            b16x8 ap[2];
            #pragma unroll
            for (int kb = 0; kb < 2; ++kb)
                ap[kb] = *(const b16x8*)(Ps + (wave * 16 + l15) * 72 + kb * 32 + quad * 8);
            #pragma unroll
            for (int nt = 0; nt < 4; ++nt)
                #pragma unroll
                for (int kb = 0; kb < 2; ++kb) {
                    b16x8 bv = *(const b16x8*)(Vt + (nt * 16 + l15) * 72 + kb * 32 + quad * 8);
                    oacc[nt] = MFMA16(ap[kb], bv, oacc[nt]);
                }
        }

        // epilogue: normalize and store bf16
        #pragma unroll
        for (int r = 0; r < 4; ++r) {
            float inv = 1.0f / lrow[r];
            size_t row = tok0 + (size_t)qi * 64 + wave * 16 + quad * 4 + r;
            #pragma unroll
            for (int nt = 0; nt < 4; ++nt)
                Ob[row * 512 + h * 64 + nt * 16 + l15] = f2bf(oacc[nt][r] * inv);
        }
    }
}

// ---------------------------------------------------------------------------
extern "C" void kernel_launch(void* const* d_in, const int* in_sizes, int n_in,
                              void* d_out, int out_size, void* d_ws, size_t ws_size,
                              hipStream_t stream) {
    (void)in_sizes; (void)n_in; (void)out_size; (void)ws_size;
    const float* x     = (const float*)d_in[0];
    const float* ln_g  = (const float*)d_in[1];
    const float* ln_b  = (const float*)d_in[2];
    const float* Wq    = (const float*)d_in[3];
    const float* Wk    = (const float*)d_in[4];
    const float* Wv    = (const float*)d_in[5];
    const float* Wproj = (const float*)d_in[6];
    const float* bproj = (const float*)d_in[7];
    const float* W1    = (const float*)d_in[8];
    const float* b1    = (const float*)d_in[9];
    const float* W2    = (const float*)d_in[10];
    const float* b2    = (const float*)d_in[11];
    float* out = (float*)d_out;

    char* W = (char*)d_ws;
    short* hbuf  = (short*)(W + 0);                    // 8 MB  (LN out, bf16)
    short* qkvb  = (short*)(W + ((size_t)8  << 20));   // 24 MB [BT][1536]
    short* attno = (short*)(W + ((size_t)32 << 20));   // 8 MB  [BT][512]
    float* x1    = (float*)(W + ((size_t)40 << 20));   // 16 MB
    short* ff1   = (short*)(W + ((size_t)56 << 20));   // 32 MB [BT][2048]
    short* wqkv  = (short*)(W + ((size_t)88 << 20));   // 1.5 MB [1536][512]
    short* wpt   = (short*)(W + ((size_t)90 << 20));   // 0.5 MB [512][512]
    short* w1t   = (short*)(W + ((size_t)91 << 20));   // 2 MB  [2048][512]
    short* w2t   = (short*)(W + ((size_t)93 << 20));   // 2 MB  [512][2048]

    dim3 tb(32, 8);
    // weight transposes (bf16, B^T layout)
    transpose_kernel<<<dim3(2, 16, 8), tb, 0, stream>>>(Wq, wqkv,             D_, DH_, D_ * DH_, DH_ * D_);
    transpose_kernel<<<dim3(2, 16, 8), tb, 0, stream>>>(Wk, wqkv + 512 * 512, D_, DH_, D_ * DH_, DH_ * D_);
    transpose_kernel<<<dim3(2, 16, 8), tb, 0, stream>>>(Wv, wqkv + 1024 * 512, D_, DH_, D_ * DH_, DH_ * D_);
    transpose_kernel<<<dim3(16, 16, 1), tb, 0, stream>>>(Wproj, wpt, D_, D_, 0, 0);
    transpose_kernel<<<dim3(64, 16, 1), tb, 0, stream>>>(W1, w1t, D_, FF_, 0, 0);
    transpose_kernel<<<dim3(16, 64, 1), tb, 0, stream>>>(W2, w2t, FF_, D_, 0, 0);

    // 1. h = LN(x) -> bf16
    ln_kernel<<<dim3(BT_), dim3(64), 0, stream>>>(x, ln_g, ln_b, hbuf);
    // 2. qkv = h @ Wqkv  [8192,1536] bf16
    mm_kernel<<<dim3(12, 64), dim3(256), 0, stream>>>(hbuf, wqkv, qkvb,
        nullptr, nullptr, BT_, 1536, D_, 0, 1);
    // 3. attention -> attno bf16
    attn_kernel<<<dim3(16, B_ * H_), dim3(256), 0, stream>>>(qkvb, attno);
    // 4. x1 = x + attno @ Wproj + bproj  (fp32)
    mm_kernel<<<dim3(4, 64), dim3(256), 0, stream>>>(attno, wpt, x1,
        bproj, x, BT_, D_, D_, 0, 0);
    // 5. h2 = LN(x1) -> bf16 (reuse hbuf)
    ln_kernel<<<dim3(BT_), dim3(64), 0, stream>>>(x1, ln_g, ln_b, hbuf);
    // 6. ff1 = relu(h2 @ W1 + b1)  bf16
    mm_kernel<<<dim3(16, 64), dim3(256), 0, stream>>>(hbuf, w1t, ff1,
        b1, nullptr, BT_, FF_, D_, 1, 1);
    // 7. out = x1 + ff1 @ W2 + b2  (fp32)
    mm_kernel<<<dim3(4, 64), dim3(256), 0, stream>>>(ff1, w2t, out,
        b2, x1, BT_, D_, FF_, 0, 0);
}

// Round 3
// 354.135 us; speedup vs baseline: 3.7307x; 1.0790x over previous
//
#include <hip/hip_runtime.h>
#include <math.h>

#define B_ 4
#define T_ 2048
#define D_ 512
#define H_ 8
#define DH_ 64
#define BT_ 8192
#define FF_ 2048
#define EPS_ 1e-5f
#define SCALE_ 0.04419417382415922f   // 512^-0.5
#define NEGINF_ -1e30f

typedef short b16x8 __attribute__((ext_vector_type(8)));
typedef float f32x4 __attribute__((ext_vector_type(4)));

#define MFMA16(a, b, c) __builtin_amdgcn_mfma_f32_16x16x32_bf16(a, b, c, 0, 0, 0)

#define GLL16(gp, lp) \
    __builtin_amdgcn_global_load_lds((const __attribute__((address_space(1))) void*)(gp), \
                                     (__attribute__((address_space(3))) void*)(lp), 16, 0, 0)

// fp32 -> bf16 RNE (finite inputs)
static __device__ inline short f2bf(float f) {
    unsigned int u = __builtin_bit_cast(unsigned int, f);
    unsigned int r = (u + 0x7fffu + ((u >> 16) & 1u)) >> 16;
    return (short)r;
}

// ---------------------------------------------------------------------------
// LayerNorm: one wave per row of 512, fp32 in -> bf16 out
// ---------------------------------------------------------------------------
__global__ __launch_bounds__(64) void ln_kernel(const float* __restrict__ X,
        const float* __restrict__ G, const float* __restrict__ Bb,
        short* __restrict__ Y)
{
    int row = blockIdx.x;
    int t = threadIdx.x;
    const float* xr = X + (size_t)row * D_;
    float4 v0 = *(const float4*)(xr + t * 4);
    float4 v1 = *(const float4*)(xr + 256 + t * 4);
    float sum = v0.x + v0.y + v0.z + v0.w + v1.x + v1.y + v1.z + v1.w;
    float ssq = v0.x*v0.x + v0.y*v0.y + v0.z*v0.z + v0.w*v0.w
              + v1.x*v1.x + v1.y*v1.y + v1.z*v1.z + v1.w*v1.w;
    #pragma unroll
    for (int off = 32; off > 0; off >>= 1) {
        sum += __shfl_down(sum, off);
        ssq += __shfl_down(ssq, off);
    }
    sum = __shfl(sum, 0);
    ssq = __shfl(ssq, 0);
    float mean = sum * (1.0f / D_);
    float var  = ssq * (1.0f / D_) - mean * mean;
    float rstd = rsqrtf(var + EPS_);

    float4 g0 = *(const float4*)(G + t * 4);
    float4 g1 = *(const float4*)(G + 256 + t * 4);
    float4 b0 = *(const float4*)(Bb + t * 4);
    float4 b1 = *(const float4*)(Bb + 256 + t * 4);
    short4 o0, o1;
    o0.x = f2bf((v0.x - mean) * rstd * g0.x + b0.x);
    o0.y = f2bf((v0.y - mean) * rstd * g0.y + b0.y);
    o0.z = f2bf((v0.z - mean) * rstd * g0.z + b0.z);
    o0.w = f2bf((v0.w - mean) * rstd * g0.w + b0.w);
    o1.x = f2bf((v1.x - mean) * rstd * g1.x + b1.x);
    o1.y = f2bf((v1.y - mean) * rstd * g1.y + b1.y);
    o1.z = f2bf((v1.z - mean) * rstd * g1.z + b1.z);
    o1.w = f2bf((v1.w - mean) * rstd * g1.w + b1.w);
    short* yr = Y + (size_t)row * D_;
    *(short4*)(yr + t * 4)       = o0;
    *(short4*)(yr + 256 + t * 4) = o1;
}

// ---------------------------------------------------------------------------
// Tiled transpose + bf16 cast: in f32 [R][C] -> out bf16 [C][R], batched
// block (32,8), grid (C/32, R/32, batch)
// ---------------------------------------------------------------------------
__global__ __launch_bounds__(256) void transpose_kernel(const float* __restrict__ in,
        short* __restrict__ out, int R, int C, int inBatchStride, int outBatchStride)
{
    __shared__ float tile[32][33];
    const float* ip = in + (size_t)blockIdx.z * inBatchStride;
    short* op = out + (size_t)blockIdx.z * outBatchStride;
    int tx = threadIdx.x, ty = threadIdx.y;
    int c = blockIdx.x * 32 + tx;
    #pragma unroll
    for (int i = 0; i < 32; i += 8) {
        int r = blockIdx.y * 32 + ty + i;
        tile[ty + i][tx] = ip[(size_t)r * C + c];
    }
    __syncthreads();
    int rr = blockIdx.y * 32 + tx;
    #pragma unroll
    for (int i = 0; i < 32; i += 8) {
        int cc = blockIdx.x * 32 + ty + i;
        op[(size_t)cc * R + rr] = f2bf(tile[tx][ty + i]);
    }
}

// ---------------------------------------------------------------------------
// bf16 MFMA GEMM (m97 pattern): C[M,N] = A[M,K] @ Bt[N,K]^T
// 128x128 tile, BK=32, 256 threads (4 waves, each 64x64), global_load_lds.
// ---------------------------------------------------------------------------
__global__ __launch_bounds__(256) void mm_kernel(const short* __restrict__ A,
        const short* __restrict__ Bt, void* __restrict__ C,
        const float* __restrict__ bias, const float* __restrict__ resid,
        int M, int N, int K, int relu, int out_bf16)
{
    __shared__ short As[128 * 32];
    __shared__ short Bs[128 * 32];
    const int tid = threadIdx.x;
    const int wave = tid >> 6, lane = tid & 63;
    const int quad = lane >> 4, l15 = lane & 15;
    const int m0 = blockIdx.y * 128, n0 = blockIdx.x * 128;
    const int mw = (wave & 1) * 64, nw = (wave >> 1) * 64;

    f32x4 acc[4][4];
    #pragma unroll
    for (int i = 0; i < 4; ++i)
        #pragma unroll
        for (int j = 0; j < 4; ++j)
            acc[i][j] = (f32x4){0.f, 0.f, 0.f, 0.f};

    for (int k0 = 0; k0 < K; k0 += 32) {
        __syncthreads();
        #pragma unroll
        for (int r = 0; r < 2; ++r) {
            int c = r * 256 + tid;
            int row = c >> 2, seg = c & 3;
            GLL16(A + (size_t)(m0 + row) * K + k0 + seg * 8,
                  As + (size_t)(r * 256 + wave * 64) * 8);
            GLL16(Bt + (size_t)(n0 + row) * K + k0 + seg * 8,
                  Bs + (size_t)(r * 256 + wave * 64) * 8);
        }
        __syncthreads();
        b16x8 af[4], bf[4];
        #pragma unroll
        for (int i = 0; i < 4; ++i)
            af[i] = *(const b16x8*)(As + (mw + i * 16 + l15) * 32 + quad * 8);
        #pragma unroll
        for (int j = 0; j < 4; ++j)
            bf[j] = *(const b16x8*)(Bs + (nw + j * 16 + l15) * 32 + quad * 8);
        #pragma unroll
        for (int i = 0; i < 4; ++i)
            #pragma unroll
            for (int j = 0; j < 4; ++j)
                acc[i][j] = MFMA16(af[i], bf[j], acc[i][j]);
    }

    #pragma unroll
    for (int i = 0; i < 4; ++i) {
        #pragma unroll
        for (int r = 0; r < 4; ++r) {
            size_t row = (size_t)(m0 + mw + i * 16 + quad * 4 + r);
            #pragma unroll
            for (int j = 0; j < 4; ++j) {
                int col = n0 + nw + j * 16 + l15;
                float v = acc[i][j][r];
                if (bias)  v += bias[col];
                if (resid) v += resid[row * N + col];
                if (relu)  v = fmaxf(v, 0.0f);
                if (out_bf16) ((short*)C)[row * N + col] = f2bf(v);
                else          ((float*)C)[row * N + col] = v;
            }
        }
    }
}

// ---------------------------------------------------------------------------
// bf16 MFMA GEMM, 128(M)x64(N) tile for narrow-N outputs (proj, FFN2).
// 4 waves, each 64x32 (acc 4x2). grid = (N/64, M/128).
// ---------------------------------------------------------------------------
__global__ __launch_bounds__(256) void mm64_kernel(const short* __restrict__ A,
        const short* __restrict__ Bt, void* __restrict__ C,
        const float* __restrict__ bias, const float* __restrict__ resid,
        int M, int N, int K, int relu, int out_bf16)
{
    __shared__ short As[128 * 32];
    __shared__ short Bs[64 * 32];
    const int tid = threadIdx.x;
    const int wave = tid >> 6, lane = tid & 63;
    const int quad = lane >> 4, l15 = lane & 15;
    const int m0 = blockIdx.y * 128, n0 = blockIdx.x * 64;
    const int mw = (wave & 1) * 64, nw = (wave >> 1) * 32;

    f32x4 acc[4][2];
    #pragma unroll
    for (int i = 0; i < 4; ++i)
        #pragma unroll
        for (int j = 0; j < 2; ++j)
            acc[i][j] = (f32x4){0.f, 0.f, 0.f, 0.f};

    for (int k0 = 0; k0 < K; k0 += 32) {
        __syncthreads();
        #pragma unroll
        for (int r = 0; r < 2; ++r) {
            int c = r * 256 + tid;
            int row = c >> 2, seg = c & 3;
            GLL16(A + (size_t)(m0 + row) * K + k0 + seg * 8,
                  As + (size_t)(r * 256 + wave * 64) * 8);
        }
        {
            int row = tid >> 2, seg = tid & 3;
            GLL16(Bt + (size_t)(n0 + row) * K + k0 + seg * 8,
                  Bs + (size_t)(wave * 64) * 8);
        }
        __syncthreads();
        b16x8 af[4], bf[2];
        #pragma unroll
        for (int i = 0; i < 4; ++i)
            af[i] = *(const b16x8*)(As + (mw + i * 16 + l15) * 32 + quad * 8);
        #pragma unroll
        for (int j = 0; j < 2; ++j)
            bf[j] = *(const b16x8*)(Bs + (nw + j * 16 + l15) * 32 + quad * 8);
        #pragma unroll
        for (int i = 0; i < 4; ++i)
            #pragma unroll
            for (int j = 0; j < 2; ++j)
                acc[i][j] = MFMA16(af[i], bf[j], acc[i][j]);
    }

    #pragma unroll
    for (int i = 0; i < 4; ++i) {
        #pragma unroll
        for (int r = 0; r < 4; ++r) {
            size_t row = (size_t)(m0 + mw + i * 16 + quad * 4 + r);
            #pragma unroll
            for (int j = 0; j < 2; ++j) {
                int col = n0 + nw + j * 16 + l15;
                float v = acc[i][j][r];
                if (bias)  v += bias[col];
                if (resid) v += resid[row * N + col];
                if (relu)  v = fmaxf(v, 0.0f);
                if (out_bf16) ((short*)C)[row * N + col] = f2bf(v);
                else          ((float*)C)[row * N + col] = v;
            }
        }
    }
}

// ---------------------------------------------------------------------------
// Flash attention, bf16 MFMA. qkv: [BT][1536] bf16 (q|k|v, each h*64+e).
// grid (32 bh, 32 qtile): bh on x pins a head's blocks to one XCD (L2 reuse);
// qi = 31 - blockIdx.y -> longest blocks dispatch first (LPT scheduling).
// 4 blocks/CU (34.8 KB LDS). Q fragments hoisted out of the kj loop.
// ---------------------------------------------------------------------------
__global__ __launch_bounds__(256) void attn_kernel(const short* __restrict__ qkv,
        short* __restrict__ Ob)
{
    __shared__ short Qs[64 * 64];   // swizzled 16B chunks
    __shared__ short Ks[64 * 64];   // swizzled 16B chunks
    __shared__ short Vt[64 * 72];   // [dh][token], stride 72
    __shared__ short Ps[64 * 72];   // [qrow][token], stride 72

    const int tid = threadIdx.x;
    const int wave = tid >> 6, lane = tid & 63;
    const int quad = lane >> 4, l15 = lane & 15;
    const int bh = blockIdx.x;
    const int qi = 31 - (int)blockIdx.y;
    const int b = bh >> 3, h = bh & 7;
    const size_t tok0 = (size_t)b * T_;

    // stage Q tile (swizzled chunks: slot = tok*8 + (seg ^ (tok&7)))
    #pragma unroll
    for (int r = 0; r < 2; ++r) {
        int c = r * 256 + tid;
        int tk = c >> 3;
        int seg = (c & 7) ^ (tk & 7);
        GLL16(qkv + (tok0 + qi * 64 + tk) * 1536 + h * 64 + seg * 8,
              Qs + (size_t)(r * 256 + wave * 64) * 8);
    }

    float mrow[4], lrow[4];
    f32x4 oacc[4];
    #pragma unroll
    for (int r = 0; r < 4; ++r) { mrow[r] = NEGINF_; lrow[r] = 0.0f; }
    #pragma unroll
    for (int nt = 0; nt < 4; ++nt) oacc[nt] = (f32x4){0.f, 0.f, 0.f, 0.f};

    b16x8 aq[2];

    for (int kj = 0; kj <= qi; ++kj) {
        __syncthreads();   // prev-iter LDS reads done (and Q GLL drained on kj=0)
        // stage K tile (swizzled)
        #pragma unroll
        for (int r = 0; r < 2; ++r) {
            int c = r * 256 + tid;
            int tk = c >> 3;
            int seg = (c & 7) ^ (tk & 7);
            GLL16(qkv + (tok0 + kj * 64 + tk) * 1536 + 512 + h * 64 + seg * 8,
                  Ks + (size_t)(r * 256 + wave * 64) * 8);
        }
        // stage V transposed: thread = (seg s 0..7, token-pair tp 0..31)
        {
            int s = tid >> 5, tp = tid & 31;
            const short* g0 = qkv + (tok0 + kj * 64 + tp * 2) * 1536 + 1024 + h * 64 + s * 8;
            b16x8 v0 = *(const b16x8*)g0;
            b16x8 v1 = *(const b16x8*)(g0 + 1536);
            int* vo = (int*)Vt;
            #pragma unroll
            for (int e = 0; e < 8; ++e) {
                unsigned int pk = (unsigned int)(unsigned short)v0[e]
                                | ((unsigned int)(unsigned short)v1[e] << 16);
                vo[(s * 8 + e) * 36 + tp] = pk;
            }
        }
        __syncthreads();

        if (kj == 0) {   // wave-uniform; Qs is ready after the barrier above
            #pragma unroll
            for (int kb = 0; kb < 2; ++kb) {
                int row = wave * 16 + l15;
                aq[kb] = *(const b16x8*)(Qs + (row * 8 + ((kb * 4 + quad) ^ (row & 7))) * 8);
            }
        }

        // S = Q K^T  (16x16x32 MFMA, K-dim 64 = 2 steps)
        f32x4 sacc[4];
        #pragma unroll
        for (int nt = 0; nt < 4; ++nt) sacc[nt] = (f32x4){0.f, 0.f, 0.f, 0.f};
        #pragma unroll
        for (int nt = 0; nt < 4; ++nt) {
            int trow = nt * 16 + l15;
            #pragma unroll
            for (int kb = 0; kb < 2; ++kb) {
                b16x8 bk = *(const b16x8*)(Ks + (trow * 8 + ((kb * 4 + quad) ^ (trow & 7))) * 8);
                sacc[nt] = MFMA16(aq[kb], bk, sacc[nt]);
            }
        }

        // scale + causal mask; C-layout: row = wave*16+quad*4+r, col = nt*16+l15
        float p[4][4], mx[4];
        #pragma unroll
        for (int r = 0; r < 4; ++r) mx[r] = NEGINF_;
        #pragma unroll
        for (int nt = 0; nt < 4; ++nt)
            #pragma unroll
            for (int r = 0; r < 4; ++r) {
                float s = sacc[nt][r] * SCALE_;
                if (kj == qi && (nt * 16 + l15) > (wave * 16 + quad * 4 + r)) s = NEGINF_;
                p[nt][r] = s;
                mx[r] = fmaxf(mx[r], s);
            }
        #pragma unroll
        for (int r = 0; r < 4; ++r) {
            mx[r] = fmaxf(mx[r], __shfl_xor(mx[r], 1));
            mx[r] = fmaxf(mx[r], __shfl_xor(mx[r], 2));
            mx[r] = fmaxf(mx[r], __shfl_xor(mx[r], 4));
            mx[r] = fmaxf(mx[r], __shfl_xor(mx[r], 8));
        }
        float alpha[4], rs[4];
        #pragma unroll
        for (int r = 0; r < 4; ++r) {
            float mn = fmaxf(mrow[r], mx[r]);
            alpha[r] = __expf(mrow[r] - mn);
            mrow[r] = mn;
            rs[r] = 0.0f;
        }
        #pragma unroll
        for (int nt = 0; nt < 4; ++nt)
            #pragma unroll
            for (int r = 0; r < 4; ++r) {
                float e = __expf(p[nt][r] - mrow[r]);
                p[nt][r] = e;
                rs[r] += e;
            }
        #pragma unroll
        for (int r = 0; r < 4; ++r) {
            rs[r] += __shfl_xor(rs[r], 1);
            rs[r] += __shfl_xor(rs[r], 2);
            rs[r] += __shfl_xor(rs[r], 4);
            rs[r] += __shfl_xor(rs[r], 8);
            lrow[r] = lrow[r] * alpha[r] + rs[r];
        }
        // write P (bf16) to per-wave LDS strip; same-wave readback (DS in-order)
        #pragma unroll
        for (int nt = 0; nt < 4; ++nt)
            #pragma unroll
            for (int r = 0; r < 4; ++r)
                Ps[(wave * 16 + quad * 4 + r) * 72 + nt * 16 + l15] = f2bf(p[nt][r]);
        // rescale O
        #pragma unroll
        for (int nt = 0; nt < 4; ++nt)
            #pragma unroll
            for (int r = 0; r < 4; ++r)
                oacc[nt][r] *= alpha[r];
        // O += P @ V
        b16x8 ap[2];
        #pragma unroll
        for (int kb = 0; kb < 2; ++kb)
            ap[kb] = *(const b16x8*)(Ps + (wave * 16 + l15) * 72 + kb * 32 + quad * 8);
        #pragma unroll
        for (int nt = 0; nt < 4; ++nt)
            #pragma unroll
            for (int kb = 0; kb < 2; ++kb) {
                b16x8 bv = *(const b16x8*)(Vt + (nt * 16 + l15) * 72 + kb * 32 + quad * 8);
                oacc[nt] = MFMA16(ap[kb], bv, oacc[nt]);
            }
    }

    // epilogue: normalize and store bf16
    #pragma unroll
    for (int r = 0; r < 4; ++r) {
        float inv = 1.0f / lrow[r];
        size_t row = tok0 + (size_t)qi * 64 + wave * 16 + quad * 4 + r;
        #pragma unroll
        for (int nt = 0; nt < 4; ++nt)
            Ob[row * 512 + h * 64 + nt * 16 + l15] = f2bf(oacc[nt][r] * inv);
    }
}

// ---------------------------------------------------------------------------
extern "C" void kernel_launch(void* const* d_in, const int* in_sizes, int n_in,
                              void* d_out, int out_size, void* d_ws, size_t ws_size,
                              hipStream_t stream) {
    (void)in_sizes; (void)n_in; (void)out_size; (void)ws_size;
    const float* x     = (const float*)d_in[0];
    const float* ln_g  = (const float*)d_in[1];
    const float* ln_b  = (const float*)d_in[2];
    const float* Wq    = (const float*)d_in[3];
    const float* Wk    = (const float*)d_in[4];
    const float* Wv    = (const float*)d_in[5];
    const float* Wproj = (const float*)d_in[6];
    const float* bproj = (const float*)d_in[7];
    const float* W1    = (const float*)d_in[8];
    const float* b1    = (const float*)d_in[9];
    const float* W2    = (const float*)d_in[10];
    const float* b2    = (const float*)d_in[11];
    float* out = (float*)d_out;

    char* W = (char*)d_ws;
    short* hbuf  = (short*)(W + 0);                    // 8 MB  (LN out, bf16)
    short* qkvb  = (short*)(W + ((size_t)8  << 20));   // 24 MB [BT][1536]
    short* attno = (short*)(W + ((size_t)32 << 20));   // 8 MB  [BT][512]
    float* x1    = (float*)(W + ((size_t)40 << 20));   // 16 MB
    short* ff1   = (short*)(W + ((size_t)56 << 20));   // 32 MB [BT][2048]
    short* wqkv  = (short*)(W + ((size_t)88 << 20));   // 1.5 MB [1536][512]
    short* wpt   = (short*)(W + ((size_t)90 << 20));   // 0.5 MB [512][512]
    short* w1t   = (short*)(W + ((size_t)91 << 20));   // 2 MB  [2048][512]
    short* w2t   = (short*)(W + ((size_t)93 << 20));   // 2 MB  [512][2048]

    dim3 tb(32, 8);
    // weight transposes (bf16, B^T layout)
    transpose_kernel<<<dim3(2, 16, 8), tb, 0, stream>>>(Wq, wqkv,              D_, DH_, D_ * DH_, DH_ * D_);
    transpose_kernel<<<dim3(2, 16, 8), tb, 0, stream>>>(Wk, wqkv + 512 * 512,  D_, DH_, D_ * DH_, DH_ * D_);
    transpose_kernel<<<dim3(2, 16, 8), tb, 0, stream>>>(Wv, wqkv + 1024 * 512, D_, DH_, D_ * DH_, DH_ * D_);
    transpose_kernel<<<dim3(16, 16, 1), tb, 0, stream>>>(Wproj, wpt, D_, D_, 0, 0);
    transpose_kernel<<<dim3(64, 16, 1), tb, 0, stream>>>(W1, w1t, D_, FF_, 0, 0);
    transpose_kernel<<<dim3(16, 64, 1), tb, 0, stream>>>(W2, w2t, FF_, D_, 0, 0);

    // 1. h = LN(x) -> bf16
    ln_kernel<<<dim3(BT_), dim3(64), 0, stream>>>(x, ln_g, ln_b, hbuf);
    // 2. qkv = h @ Wqkv  [8192,1536] bf16
    mm_kernel<<<dim3(12, 64), dim3(256), 0, stream>>>(hbuf, wqkv, qkvb,
        nullptr, nullptr, BT_, 1536, D_, 0, 1);
    // 3. attention -> attno bf16
    attn_kernel<<<dim3(32, 32), dim3(256), 0, stream>>>(qkvb, attno);
    // 4. x1 = x + attno @ Wproj + bproj  (fp32)
    mm64_kernel<<<dim3(8, 64), dim3(256), 0, stream>>>(attno, wpt, x1,
        bproj, x, BT_, D_, D_, 0, 0);
    // 5. h2 = LN(x1) -> bf16 (reuse hbuf)
    ln_kernel<<<dim3(BT_), dim3(64), 0, stream>>>(x1, ln_g, ln_b, hbuf);
    // 6. ff1 = relu(h2 @ W1 + b1)  bf16
    mm_kernel<<<dim3(16, 64), dim3(256), 0, stream>>>(hbuf, w1t, ff1,
        b1, nullptr, BT_, FF_, D_, 1, 1);
    // 7. out = x1 + ff1 @ W2 + b2  (fp32)
    mm64_kernel<<<dim3(8, 64), dim3(256), 0, stream>>>(ff1, w2t, out,
        b2, x1, BT_, D_, FF_, 0, 0);
}

// Round 4
// 350.331 us; speedup vs baseline: 3.7712x; 1.0109x over previous
//
#include <hip/hip_runtime.h>
#include <math.h>

#define B_ 4
#define T_ 2048
#define D_ 512
#define H_ 8
#define DH_ 64
#define BT_ 8192
#define FF_ 2048
#define EPS_ 1e-5f
#define SCALE_ 0.04419417382415922f   // 512^-0.5
#define SC2_ 0.06375861151f           // SCALE_ * log2(e)
#define NEGINF_ -1e30f

typedef short b16x8 __attribute__((ext_vector_type(8)));
typedef float f32x4 __attribute__((ext_vector_type(4)));

#define MFMA16(a, b, c) __builtin_amdgcn_mfma_f32_16x16x32_bf16(a, b, c, 0, 0, 0)

#define GLL16(gp, lp) \
    __builtin_amdgcn_global_load_lds((const __attribute__((address_space(1))) void*)(gp), \
                                     (__attribute__((address_space(3))) void*)(lp), 16, 0, 0)

#if __has_builtin(__builtin_amdgcn_exp2f)
#define EXP2F(x) __builtin_amdgcn_exp2f(x)
#else
#define EXP2F(x) exp2f(x)
#endif

// DPP row_ror within 16-lane rows (VALU pipe, replaces ds_swizzle shuffles)
#define DPP_F(x, ctrl) __builtin_bit_cast(float, __builtin_amdgcn_update_dpp( \
    __builtin_bit_cast(int, x), __builtin_bit_cast(int, x), ctrl, 0xf, 0xf, false))

static __device__ inline float rowmax16(float x) {
    x = fmaxf(x, DPP_F(x, 0x121));   // row_ror:1
    x = fmaxf(x, DPP_F(x, 0x122));   // row_ror:2
    x = fmaxf(x, DPP_F(x, 0x124));   // row_ror:4
    x = fmaxf(x, DPP_F(x, 0x128));   // row_ror:8
    return x;
}
static __device__ inline float rowsum16(float x) {
    x += DPP_F(x, 0x121);
    x += DPP_F(x, 0x122);
    x += DPP_F(x, 0x124);
    x += DPP_F(x, 0x128);
    return x;
}

// fp32 -> bf16 RNE (finite inputs)
static __device__ inline short f2bf(float f) {
    unsigned int u = __builtin_bit_cast(unsigned int, f);
    unsigned int r = (u + 0x7fffu + ((u >> 16) & 1u)) >> 16;
    return (short)r;
}

// ---------------------------------------------------------------------------
// LayerNorm: one wave per row of 512, fp32 in -> bf16 out
// ---------------------------------------------------------------------------
__global__ __launch_bounds__(64) void ln_kernel(const float* __restrict__ X,
        const float* __restrict__ G, const float* __restrict__ Bb,
        short* __restrict__ Y)
{
    int row = blockIdx.x;
    int t = threadIdx.x;
    const float* xr = X + (size_t)row * D_;
    float4 v0 = *(const float4*)(xr + t * 4);
    float4 v1 = *(const float4*)(xr + 256 + t * 4);
    float sum = v0.x + v0.y + v0.z + v0.w + v1.x + v1.y + v1.z + v1.w;
    float ssq = v0.x*v0.x + v0.y*v0.y + v0.z*v0.z + v0.w*v0.w
              + v1.x*v1.x + v1.y*v1.y + v1.z*v1.z + v1.w*v1.w;
    #pragma unroll
    for (int off = 32; off > 0; off >>= 1) {
        sum += __shfl_down(sum, off);
        ssq += __shfl_down(ssq, off);
    }
    sum = __shfl(sum, 0);
    ssq = __shfl(ssq, 0);
    float mean = sum * (1.0f / D_);
    float var  = ssq * (1.0f / D_) - mean * mean;
    float rstd = rsqrtf(var + EPS_);

    float4 g0 = *(const float4*)(G + t * 4);
    float4 g1 = *(const float4*)(G + 256 + t * 4);
    float4 b0 = *(const float4*)(Bb + t * 4);
    float4 b1 = *(const float4*)(Bb + 256 + t * 4);
    short4 o0, o1;
    o0.x = f2bf((v0.x - mean) * rstd * g0.x + b0.x);
    o0.y = f2bf((v0.y - mean) * rstd * g0.y + b0.y);
    o0.z = f2bf((v0.z - mean) * rstd * g0.z + b0.z);
    o0.w = f2bf((v0.w - mean) * rstd * g0.w + b0.w);
    o1.x = f2bf((v1.x - mean) * rstd * g1.x + b1.x);
    o1.y = f2bf((v1.y - mean) * rstd * g1.y + b1.y);
    o1.z = f2bf((v1.z - mean) * rstd * g1.z + b1.z);
    o1.w = f2bf((v1.w - mean) * rstd * g1.w + b1.w);
    short* yr = Y + (size_t)row * D_;
    *(short4*)(yr + t * 4)       = o0;
    *(short4*)(yr + 256 + t * 4) = o1;
}

// ---------------------------------------------------------------------------
// All weight transposes fused into one launch. 3072 tiles of 32x32.
// block (32,8).
// ---------------------------------------------------------------------------
__global__ __launch_bounds__(256) void prep_kernel(
        const float* __restrict__ Wq, const float* __restrict__ Wk,
        const float* __restrict__ Wv, const float* __restrict__ Wp,
        const float* __restrict__ W1, const float* __restrict__ W2,
        short* __restrict__ wqkv, short* __restrict__ wpt,
        short* __restrict__ w1t, short* __restrict__ w2t)
{
    __shared__ float tile[32][33];
    int idx = blockIdx.x;
    const float* src; short* dst; int R, C, tx0, ty0;
    if (idx < 768) {            // Wq/Wk/Wv: per head [512][64] -> [64][512]
        int w = idx >> 8, rem = idx & 255;
        int hh = rem >> 5, t = rem & 31;
        const float* base = (w == 0) ? Wq : ((w == 1) ? Wk : Wv);
        src = base + hh * (D_ * DH_);
        dst = wqkv + w * (512 * 512) + hh * (DH_ * D_);
        R = 512; C = 64; tx0 = (t & 1) * 32; ty0 = (t >> 1) * 32;
    } else if (idx < 1024) {    // Wproj [512][512]
        int t = idx - 768;
        src = Wp; dst = wpt; R = 512; C = 512;
        tx0 = (t & 15) * 32; ty0 = (t >> 4) * 32;
    } else if (idx < 2048) {    // W1 [512][2048] -> [2048][512]
        int t = idx - 1024;
        src = W1; dst = w1t; R = 512; C = 2048;
        tx0 = (t & 63) * 32; ty0 = (t >> 6) * 32;
    } else {                    // W2 [2048][512] -> [512][2048]
        int t = idx - 2048;
        src = W2; dst = w2t; R = 2048; C = 512;
        tx0 = (t & 15) * 32; ty0 = (t >> 4) * 32;
    }
    int tx = threadIdx.x, ty = threadIdx.y;
    #pragma unroll
    for (int i = 0; i < 32; i += 8)
        tile[ty + i][tx] = src[(size_t)(ty0 + ty + i) * C + tx0 + tx];
    __syncthreads();
    #pragma unroll
    for (int i = 0; i < 32; i += 8)
        dst[(size_t)(tx0 + ty + i) * R + ty0 + tx] = f2bf(tile[tx][ty + i]);
}

// ---------------------------------------------------------------------------
// bf16 MFMA GEMM: C[M,N] = A[M,K] @ Bt[N,K]^T.  128x128 tile, BK=64,
// 256 threads (4 waves x 64x64), global_load_lds with XOR-swizzled chunks
// (chunk slot sp holds global seg sp^(row&7); fragment reads land 2-way).
// ---------------------------------------------------------------------------
__global__ __launch_bounds__(256) void mm_kernel(const short* __restrict__ A,
        const short* __restrict__ Bt, void* __restrict__ C,
        const float* __restrict__ bias, const float* __restrict__ resid,
        int M, int N, int K, int relu, int out_bf16)
{
    __shared__ short As[128 * 64];
    __shared__ short Bs[128 * 64];
    const int tid = threadIdx.x;
    const int wave = tid >> 6, lane = tid & 63;
    const int quad = lane >> 4, l15 = lane & 15;
    const int m0 = blockIdx.y * 128, n0 = blockIdx.x * 128;
    const int mw = (wave & 1) * 64, nw = (wave >> 1) * 64;

    f32x4 acc[4][4];
    #pragma unroll
    for (int i = 0; i < 4; ++i)
        #pragma unroll
        for (int j = 0; j < 4; ++j)
            acc[i][j] = (f32x4){0.f, 0.f, 0.f, 0.f};

    for (int k0 = 0; k0 < K; k0 += 64) {
        __syncthreads();
        #pragma unroll
        for (int r = 0; r < 4; ++r) {
            int c = r * 256 + tid;
            int row = c >> 3, seg = (c & 7) ^ (row & 7);
            GLL16(A + (size_t)(m0 + row) * K + k0 + seg * 8,
                  As + (size_t)(r * 256 + wave * 64) * 8);
            GLL16(Bt + (size_t)(n0 + row) * K + k0 + seg * 8,
                  Bs + (size_t)(r * 256 + wave * 64) * 8);
        }
        __syncthreads();
        b16x8 af[4][2], bf[4][2];
        #pragma unroll
        for (int i = 0; i < 4; ++i)
            #pragma unroll
            for (int kb = 0; kb < 2; ++kb) {
                int row = mw + i * 16 + l15;
                af[i][kb] = *(const b16x8*)(As + row * 64 + (((kb * 4 + quad) ^ (row & 7)) * 8));
            }
        #pragma unroll
        for (int j = 0; j < 4; ++j)
            #pragma unroll
            for (int kb = 0; kb < 2; ++kb) {
                int row = nw + j * 16 + l15;
                bf[j][kb] = *(const b16x8*)(Bs + row * 64 + (((kb * 4 + quad) ^ (row & 7)) * 8));
            }
        #pragma unroll
        for (int kb = 0; kb < 2; ++kb)
            #pragma unroll
            for (int i = 0; i < 4; ++i)
                #pragma unroll
                for (int j = 0; j < 4; ++j)
                    acc[i][j] = MFMA16(af[i][kb], bf[j][kb], acc[i][j]);
    }

    #pragma unroll
    for (int i = 0; i < 4; ++i) {
        #pragma unroll
        for (int r = 0; r < 4; ++r) {
            size_t row = (size_t)(m0 + mw + i * 16 + quad * 4 + r);
            #pragma unroll
            for (int j = 0; j < 4; ++j) {
                int col = n0 + nw + j * 16 + l15;
                float v = acc[i][j][r];
                if (bias)  v += bias[col];
                if (resid) v += resid[row * N + col];
                if (relu)  v = fmaxf(v, 0.0f);
                if (out_bf16) ((short*)C)[row * N + col] = f2bf(v);
                else          ((float*)C)[row * N + col] = v;
            }
        }
    }
}

// ---------------------------------------------------------------------------
// bf16 MFMA GEMM, 128(M)x64(N) tile, BK=64, for narrow-N outputs.
// 4 waves, each 64x32 (acc 4x2). grid = (N/64, M/128).
// ---------------------------------------------------------------------------
__global__ __launch_bounds__(256) void mm64_kernel(const short* __restrict__ A,
        const short* __restrict__ Bt, void* __restrict__ C,
        const float* __restrict__ bias, const float* __restrict__ resid,
        int M, int N, int K, int relu, int out_bf16)
{
    __shared__ short As[128 * 64];
    __shared__ short Bs[64 * 64];
    const int tid = threadIdx.x;
    const int wave = tid >> 6, lane = tid & 63;
    const int quad = lane >> 4, l15 = lane & 15;
    const int m0 = blockIdx.y * 128, n0 = blockIdx.x * 64;
    const int mw = (wave & 1) * 64, nw = (wave >> 1) * 32;

    f32x4 acc[4][2];
    #pragma unroll
    for (int i = 0; i < 4; ++i)
        #pragma unroll
        for (int j = 0; j < 2; ++j)
            acc[i][j] = (f32x4){0.f, 0.f, 0.f, 0.f};

    for (int k0 = 0; k0 < K; k0 += 64) {
        __syncthreads();
        #pragma unroll
        for (int r = 0; r < 4; ++r) {
            int c = r * 256 + tid;
            int row = c >> 3, seg = (c & 7) ^ (row & 7);
            GLL16(A + (size_t)(m0 + row) * K + k0 + seg * 8,
                  As + (size_t)(r * 256 + wave * 64) * 8);
        }
        #pragma unroll
        for (int r = 0; r < 2; ++r) {
            int c = r * 256 + tid;
            int row = c >> 3, seg = (c & 7) ^ (row & 7);
            GLL16(Bt + (size_t)(n0 + row) * K + k0 + seg * 8,
                  Bs + (size_t)(r * 256 + wave * 64) * 8);
        }
        __syncthreads();
        b16x8 af[4][2], bf[2][2];
        #pragma unroll
        for (int i = 0; i < 4; ++i)
            #pragma unroll
            for (int kb = 0; kb < 2; ++kb) {
                int row = mw + i * 16 + l15;
                af[i][kb] = *(const b16x8*)(As + row * 64 + (((kb * 4 + quad) ^ (row & 7)) * 8));
            }
        #pragma unroll
        for (int j = 0; j < 2; ++j)
            #pragma unroll
            for (int kb = 0; kb < 2; ++kb) {
                int row = nw + j * 16 + l15;
                bf[j][kb] = *(const b16x8*)(Bs + row * 64 + (((kb * 4 + quad) ^ (row & 7)) * 8));
            }
        #pragma unroll
        for (int kb = 0; kb < 2; ++kb)
            #pragma unroll
            for (int i = 0; i < 4; ++i)
                #pragma unroll
                for (int j = 0; j < 2; ++j)
                    acc[i][j] = MFMA16(af[i][kb], bf[j][kb], acc[i][j]);
    }

    #pragma unroll
    for (int i = 0; i < 4; ++i) {
        #pragma unroll
        for (int r = 0; r < 4; ++r) {
            size_t row = (size_t)(m0 + mw + i * 16 + quad * 4 + r);
            #pragma unroll
            for (int j = 0; j < 2; ++j) {
                int col = n0 + nw + j * 16 + l15;
                float v = acc[i][j][r];
                if (bias)  v += bias[col];
                if (resid) v += resid[row * N + col];
                if (relu)  v = fmaxf(v, 0.0f);
                if (out_bf16) ((short*)C)[row * N + col] = f2bf(v);
                else          ((float*)C)[row * N + col] = v;
            }
        }
    }
}

// ---------------------------------------------------------------------------
// Flash attention, bf16 MFMA. qkv: [BT][1536] bf16 (q|k|v, each h*64+e).
// Q-tile 128 x K-tile 64. grid (32 bh, 16 qt); qi = 15 - blockIdx.y (LPT).
// Each wave owns 32 q-rows (2 m-tiles). Softmax reductions via DPP row_ror
// (VALU pipe); exp via native exp2 with log2(e) folded into scale.
// ---------------------------------------------------------------------------
__global__ __launch_bounds__(256) void attn_kernel(const short* __restrict__ qkv,
        short* __restrict__ Ob)
{
    __shared__ short Qs[128 * 64];  // swizzled 16B chunks: slot = row*8 + (seg^(row&7))
    __shared__ short Ks[64 * 64];   // swizzled
    __shared__ short Vt[64 * 72];   // [dh][token], stride 72
    __shared__ short Ps[128 * 72];  // [qrow][token], stride 72 (per-wave strips)

    const int tid = threadIdx.x;
    const int wave = tid >> 6, lane = tid & 63;
    const int quad = lane >> 4, l15 = lane & 15;
    const int bh = blockIdx.x;
    const int qi = 15 - (int)blockIdx.y;
    const int b = bh >> 3, h = bh & 7;
    const size_t tok0 = (size_t)b * T_;

    // stage Q tile (128 rows)
    #pragma unroll
    for (int r = 0; r < 4; ++r) {
        int c = r * 256 + tid;
        int tk = c >> 3;
        int seg = (c & 7) ^ (tk & 7);
        GLL16(qkv + (tok0 + qi * 128 + tk) * 1536 + h * 64 + seg * 8,
              Qs + (size_t)(r * 256 + wave * 64) * 8);
    }

    float mrow[2][4], lrow[2][4];
    f32x4 oacc[2][4];
    #pragma unroll
    for (int mi = 0; mi < 2; ++mi) {
        #pragma unroll
        for (int r = 0; r < 4; ++r) { mrow[mi][r] = NEGINF_; lrow[mi][r] = 0.0f; }
        #pragma unroll
        for (int nt = 0; nt < 4; ++nt) oacc[mi][nt] = (f32x4){0.f, 0.f, 0.f, 0.f};
    }
    b16x8 aq[2][2];

    const int kjmax = 2 * qi + 1;
    for (int kj = 0; kj <= kjmax; ++kj) {
        __syncthreads();   // prev-iter Ks/Vt reads done (and Q GLL drained on kj=0)
        // stage K tile (swizzled)
        #pragma unroll
        for (int r = 0; r < 2; ++r) {
            int c = r * 256 + tid;
            int tk = c >> 3;
            int seg = (c & 7) ^ (tk & 7);
            GLL16(qkv + (tok0 + kj * 64 + tk) * 1536 + 512 + h * 64 + seg * 8,
                  Ks + (size_t)(r * 256 + wave * 64) * 8);
        }
        // stage V transposed: thread = (seg s 0..7, token-pair tp 0..31)
        {
            int s = tid >> 5, tp = tid & 31;
            const short* g0 = qkv + (tok0 + kj * 64 + tp * 2) * 1536 + 1024 + h * 64 + s * 8;
            b16x8 v0 = *(const b16x8*)g0;
            b16x8 v1 = *(const b16x8*)(g0 + 1536);
            int* vo = (int*)Vt;
            #pragma unroll
            for (int e = 0; e < 8; ++e) {
                unsigned int pk = (unsigned int)(unsigned short)v0[e]
                                | ((unsigned int)(unsigned short)v1[e] << 16);
                vo[(s * 8 + e) * 36 + tp] = pk;
            }
        }
        __syncthreads();

        if (kj == 0) {   // Qs ready after the barrier above; hoisted for all kj
            #pragma unroll
            for (int mi = 0; mi < 2; ++mi)
                #pragma unroll
                for (int kb = 0; kb < 2; ++kb) {
                    int row = wave * 32 + mi * 16 + l15;
                    aq[mi][kb] = *(const b16x8*)(Qs + row * 64 + (((kb * 4 + quad) ^ (row & 7)) * 8));
                }
        }

        // S = Q K^T  (bk shared across both m-tiles)
        f32x4 sacc[2][4];
        #pragma unroll
        for (int mi = 0; mi < 2; ++mi)
            #pragma unroll
            for (int nt = 0; nt < 4; ++nt) sacc[mi][nt] = (f32x4){0.f, 0.f, 0.f, 0.f};
        #pragma unroll
        for (int nt = 0; nt < 4; ++nt) {
            int trow = nt * 16 + l15;
            #pragma unroll
            for (int kb = 0; kb < 2; ++kb) {
                b16x8 bk = *(const b16x8*)(Ks + trow * 64 + (((kb * 4 + quad) ^ (trow & 7)) * 8));
                #pragma unroll
                for (int mi = 0; mi < 2; ++mi)
                    sacc[mi][nt] = MFMA16(aq[mi][kb], bk, sacc[mi][nt]);
            }
        }

        // scale (exp2 domain) + causal mask
        float p[2][4][4], mx[2][4];
        const bool diag = (kj >= 2 * qi);
        #pragma unroll
        for (int mi = 0; mi < 2; ++mi)
            #pragma unroll
            for (int r = 0; r < 4; ++r) mx[mi][r] = NEGINF_;
        #pragma unroll
        for (int mi = 0; mi < 2; ++mi)
            #pragma unroll
            for (int nt = 0; nt < 4; ++nt)
                #pragma unroll
                for (int r = 0; r < 4; ++r) {
                    float s = sacc[mi][nt][r] * SC2_;
                    if (diag && (kj * 64 + nt * 16 + l15) >
                                (qi * 128 + wave * 32 + mi * 16 + quad * 4 + r))
                        s = NEGINF_;
                    p[mi][nt][r] = s;
                    mx[mi][r] = fmaxf(mx[mi][r], s);
                }
        float alpha[2][4], rs[2][4];
        #pragma unroll
        for (int mi = 0; mi < 2; ++mi)
            #pragma unroll
            for (int r = 0; r < 4; ++r) {
                float m16 = rowmax16(mx[mi][r]);
                float mn = fmaxf(mrow[mi][r], m16);
                alpha[mi][r] = EXP2F(mrow[mi][r] - mn);
                mrow[mi][r] = mn;
                rs[mi][r] = 0.0f;
            }
        #pragma unroll
        for (int mi = 0; mi < 2; ++mi)
            #pragma unroll
            for (int nt = 0; nt < 4; ++nt)
                #pragma unroll
                for (int r = 0; r < 4; ++r) {
                    float e = EXP2F(p[mi][nt][r] - mrow[mi][r]);
                    p[mi][nt][r] = e;
                    rs[mi][r] += e;
                }
        #pragma unroll
        for (int mi = 0; mi < 2; ++mi)
            #pragma unroll
            for (int r = 0; r < 4; ++r)
                lrow[mi][r] = lrow[mi][r] * alpha[mi][r] + rowsum16(rs[mi][r]);

        // write P (bf16) to per-wave LDS strip; same-wave readback (DS in-order)
        #pragma unroll
        for (int mi = 0; mi < 2; ++mi)
            #pragma unroll
            for (int nt = 0; nt < 4; ++nt)
                #pragma unroll
                for (int r = 0; r < 4; ++r)
                    Ps[(wave * 32 + mi * 16 + quad * 4 + r) * 72 + nt * 16 + l15]
                        = f2bf(p[mi][nt][r]);
        // rescale O
        #pragma unroll
        for (int mi = 0; mi < 2; ++mi)
            #pragma unroll
            for (int nt = 0; nt < 4; ++nt)
                #pragma unroll
                for (int r = 0; r < 4; ++r)
                    oacc[mi][nt][r] *= alpha[mi][r];
        // O += P @ V  (bv shared across both m-tiles)
        b16x8 ap[2][2];
        #pragma unroll
        for (int mi = 0; mi < 2; ++mi)
            #pragma unroll
            for (int kb = 0; kb < 2; ++kb)
                ap[mi][kb] = *(const b16x8*)(Ps + (wave * 32 + mi * 16 + l15) * 72
                                                + kb * 32 + quad * 8);
        #pragma unroll
        for (int nt = 0; nt < 4; ++nt)
            #pragma unroll
            for (int kb = 0; kb < 2; ++kb) {
                b16x8 bv = *(const b16x8*)(Vt + (nt * 16 + l15) * 72 + kb * 32 + quad * 8);
                #pragma unroll
                for (int mi = 0; mi < 2; ++mi)
                    oacc[mi][nt] = MFMA16(ap[mi][kb], bv, oacc[mi][nt]);
            }
    }

    // epilogue: normalize and store bf16
    #pragma unroll
    for (int mi = 0; mi < 2; ++mi)
        #pragma unroll
        for (int r = 0; r < 4; ++r) {
            float inv = 1.0f / lrow[mi][r];
            size_t row = tok0 + (size_t)qi * 128 + wave * 32 + mi * 16 + quad * 4 + r;
            #pragma unroll
            for (int nt = 0; nt < 4; ++nt)
                Ob[row * 512 + h * 64 + nt * 16 + l15] = f2bf(oacc[mi][nt][r] * inv);
        }
}

// ---------------------------------------------------------------------------
extern "C" void kernel_launch(void* const* d_in, const int* in_sizes, int n_in,
                              void* d_out, int out_size, void* d_ws, size_t ws_size,
                              hipStream_t stream) {
    (void)in_sizes; (void)n_in; (void)out_size; (void)ws_size;
    const float* x     = (const float*)d_in[0];
    const float* ln_g  = (const float*)d_in[1];
    const float* ln_b  = (const float*)d_in[2];
    const float* Wq    = (const float*)d_in[3];
    const float* Wk    = (const float*)d_in[4];
    const float* Wv    = (const float*)d_in[5];
    const float* Wproj = (const float*)d_in[6];
    const float* bproj = (const float*)d_in[7];
    const float* W1    = (const float*)d_in[8];
    const float* b1    = (const float*)d_in[9];
    const float* W2    = (const float*)d_in[10];
    const float* b2    = (const float*)d_in[11];
    float* out = (float*)d_out;

    char* W = (char*)d_ws;
    short* hbuf  = (short*)(W + 0);                    // 8 MB  (LN out, bf16)
    short* qkvb  = (short*)(W + ((size_t)8  << 20));   // 24 MB [BT][1536]
    short* attno = (short*)(W + ((size_t)32 << 20));   // 8 MB  [BT][512]
    float* x1    = (float*)(W + ((size_t)40 << 20));   // 16 MB
    short* ff1   = (short*)(W + ((size_t)56 << 20));   // 32 MB [BT][2048]
    short* wqkv  = (short*)(W + ((size_t)88 << 20));   // 1.5 MB [1536][512]
    short* wpt   = (short*)(W + ((size_t)90 << 20));   // 0.5 MB [512][512]
    short* w1t   = (short*)(W + ((size_t)91 << 20));   // 2 MB  [2048][512]
    short* w2t   = (short*)(W + ((size_t)93 << 20));   // 2 MB  [512][2048]

    // 0. all weight transposes in one launch
    prep_kernel<<<dim3(3072), dim3(32, 8), 0, stream>>>(
        Wq, Wk, Wv, Wproj, W1, W2, wqkv, wpt, w1t, w2t);
    // 1. h = LN(x) -> bf16
    ln_kernel<<<dim3(BT_), dim3(64), 0, stream>>>(x, ln_g, ln_b, hbuf);
    // 2. qkv = h @ Wqkv  [8192,1536] bf16
    mm_kernel<<<dim3(12, 64), dim3(256), 0, stream>>>(hbuf, wqkv, qkvb,
        nullptr, nullptr, BT_, 1536, D_, 0, 1);
    // 3. attention -> attno bf16
    attn_kernel<<<dim3(32, 16), dim3(256), 0, stream>>>(qkvb, attno);
    // 4. x1 = x + attno @ Wproj + bproj  (fp32)
    mm64_kernel<<<dim3(8, 64), dim3(256), 0, stream>>>(attno, wpt, x1,
        bproj, x, BT_, D_, D_, 0, 0);
    // 5. h2 = LN(x1) -> bf16 (reuse hbuf)
    ln_kernel<<<dim3(BT_), dim3(64), 0, stream>>>(x1, ln_g, ln_b, hbuf);
    // 6. ff1 = relu(h2 @ W1 + b1)  bf16
    mm_kernel<<<dim3(16, 64), dim3(256), 0, stream>>>(hbuf, w1t, ff1,
        b1, nullptr, BT_, FF_, D_, 1, 1);
    // 7. out = x1 + ff1 @ W2 + b2  (fp32)
    mm64_kernel<<<dim3(8, 64), dim3(256), 0, stream>>>(ff1, w2t, out,
        b2, x1, BT_, D_, FF_, 0, 0);
}

// Round 5
// 317.624 us; speedup vs baseline: 4.1595x; 1.1030x over previous
//
#include <hip/hip_runtime.h>
#include <math.h>

#define B_ 4
#define T_ 2048
#define D_ 512
#define H_ 8
#define DH_ 64
#define BT_ 8192
#define FF_ 2048
#define EPS_ 1e-5f
#define SCALE_ 0.04419417382415922f   // 512^-0.5
#define SC2_ 0.06375861151f           // SCALE_ * log2(e)
#define NEGINF_ -1e30f

typedef short b16x8 __attribute__((ext_vector_type(8)));
typedef float f32x4 __attribute__((ext_vector_type(4)));

#define MFMA16(a, b, c) __builtin_amdgcn_mfma_f32_16x16x32_bf16(a, b, c, 0, 0, 0)

#define GLL16(gp, lp) \
    __builtin_amdgcn_global_load_lds((const __attribute__((address_space(1))) void*)(gp), \
                                     (__attribute__((address_space(3))) void*)(lp), 16, 0, 0)

#if __has_builtin(__builtin_amdgcn_exp2f)
#define EXP2F(x) __builtin_amdgcn_exp2f(x)
#else
#define EXP2F(x) exp2f(x)
#endif

// DPP row_ror within 16-lane rows (VALU pipe, replaces ds_swizzle shuffles)
#define DPP_F(x, ctrl) __builtin_bit_cast(float, __builtin_amdgcn_update_dpp( \
    __builtin_bit_cast(int, x), __builtin_bit_cast(int, x), ctrl, 0xf, 0xf, false))

static __device__ inline float rowmax16(float x) {
    x = fmaxf(x, DPP_F(x, 0x121));   // row_ror:1
    x = fmaxf(x, DPP_F(x, 0x122));   // row_ror:2
    x = fmaxf(x, DPP_F(x, 0x124));   // row_ror:4
    x = fmaxf(x, DPP_F(x, 0x128));   // row_ror:8
    return x;
}
static __device__ inline float rowsum16(float x) {
    x += DPP_F(x, 0x121);
    x += DPP_F(x, 0x122);
    x += DPP_F(x, 0x124);
    x += DPP_F(x, 0x128);
    return x;
}

// fp32 -> bf16 RNE (finite inputs)
static __device__ inline short f2bf(float f) {
    unsigned int u = __builtin_bit_cast(unsigned int, f);
    unsigned int r = (u + 0x7fffu + ((u >> 16) & 1u)) >> 16;
    return (short)r;
}
// fp32 -> bf16 truncation (1 VALU op; used for P where bias is negligible)
static __device__ inline short f2bf_trunc(float f) {
    return (short)(__builtin_bit_cast(unsigned int, f) >> 16);
}

// ---------------------------------------------------------------------------
// LayerNorm: one wave per row of 512, fp32 in -> bf16 out
// ---------------------------------------------------------------------------
__global__ __launch_bounds__(64) void ln_kernel(const float* __restrict__ X,
        const float* __restrict__ G, const float* __restrict__ Bb,
        short* __restrict__ Y)
{
    int row = blockIdx.x;
    int t = threadIdx.x;
    const float* xr = X + (size_t)row * D_;
    float4 v0 = *(const float4*)(xr + t * 4);
    float4 v1 = *(const float4*)(xr + 256 + t * 4);
    float sum = v0.x + v0.y + v0.z + v0.w + v1.x + v1.y + v1.z + v1.w;
    float ssq = v0.x*v0.x + v0.y*v0.y + v0.z*v0.z + v0.w*v0.w
              + v1.x*v1.x + v1.y*v1.y + v1.z*v1.z + v1.w*v1.w;
    #pragma unroll
    for (int off = 32; off > 0; off >>= 1) {
        sum += __shfl_down(sum, off);
        ssq += __shfl_down(ssq, off);
    }
    sum = __shfl(sum, 0);
    ssq = __shfl(ssq, 0);
    float mean = sum * (1.0f / D_);
    float var  = ssq * (1.0f / D_) - mean * mean;
    float rstd = rsqrtf(var + EPS_);

    float4 g0 = *(const float4*)(G + t * 4);
    float4 g1 = *(const float4*)(G + 256 + t * 4);
    float4 b0 = *(const float4*)(Bb + t * 4);
    float4 b1 = *(const float4*)(Bb + 256 + t * 4);
    short4 o0, o1;
    o0.x = f2bf((v0.x - mean) * rstd * g0.x + b0.x);
    o0.y = f2bf((v0.y - mean) * rstd * g0.y + b0.y);
    o0.z = f2bf((v0.z - mean) * rstd * g0.z + b0.z);
    o0.w = f2bf((v0.w - mean) * rstd * g0.w + b0.w);
    o1.x = f2bf((v1.x - mean) * rstd * g1.x + b1.x);
    o1.y = f2bf((v1.y - mean) * rstd * g1.y + b1.y);
    o1.z = f2bf((v1.z - mean) * rstd * g1.z + b1.z);
    o1.w = f2bf((v1.w - mean) * rstd * g1.w + b1.w);
    short* yr = Y + (size_t)row * D_;
    *(short4*)(yr + t * 4)       = o0;
    *(short4*)(yr + 256 + t * 4) = o1;
}

// ---------------------------------------------------------------------------
// All weight transposes fused into one launch. 3072 tiles of 32x32.
// block (32,8).
// ---------------------------------------------------------------------------
__global__ __launch_bounds__(256) void prep_kernel(
        const float* __restrict__ Wq, const float* __restrict__ Wk,
        const float* __restrict__ Wv, const float* __restrict__ Wp,
        const float* __restrict__ W1, const float* __restrict__ W2,
        short* __restrict__ wqkv, short* __restrict__ wpt,
        short* __restrict__ w1t, short* __restrict__ w2t)
{
    __shared__ float tile[32][33];
    int idx = blockIdx.x;
    const float* src; short* dst; int R, C, tx0, ty0;
    if (idx < 768) {            // Wq/Wk/Wv: per head [512][64] -> [64][512]
        int w = idx >> 8, rem = idx & 255;
        int hh = rem >> 5, t = rem & 31;
        const float* base = (w == 0) ? Wq : ((w == 1) ? Wk : Wv);
        src = base + hh * (D_ * DH_);
        dst = wqkv + w * (512 * 512) + hh * (DH_ * D_);
        R = 512; C = 64; tx0 = (t & 1) * 32; ty0 = (t >> 1) * 32;
    } else if (idx < 1024) {    // Wproj [512][512]
        int t = idx - 768;
        src = Wp; dst = wpt; R = 512; C = 512;
        tx0 = (t & 15) * 32; ty0 = (t >> 4) * 32;
    } else if (idx < 2048) {    // W1 [512][2048] -> [2048][512]
        int t = idx - 1024;
        src = W1; dst = w1t; R = 512; C = 2048;
        tx0 = (t & 63) * 32; ty0 = (t >> 6) * 32;
    } else {                    // W2 [2048][512] -> [512][2048]
        int t = idx - 2048;
        src = W2; dst = w2t; R = 2048; C = 512;
        tx0 = (t & 15) * 32; ty0 = (t >> 4) * 32;
    }
    int tx = threadIdx.x, ty = threadIdx.y;
    #pragma unroll
    for (int i = 0; i < 32; i += 8)
        tile[ty + i][tx] = src[(size_t)(ty0 + ty + i) * C + tx0 + tx];
    __syncthreads();
    #pragma unroll
    for (int i = 0; i < 32; i += 8)
        dst[(size_t)(tx0 + ty + i) * R + ty0 + tx] = f2bf(tile[tx][ty + i]);
}

// ---------------------------------------------------------------------------
// bf16 MFMA GEMM: C[M,N] = A[M,K] @ Bt[N,K]^T.  128x128 tile, BK=64,
// 256 threads (4 waves x 64x64), global_load_lds with XOR-swizzled chunks.
// ---------------------------------------------------------------------------
__global__ __launch_bounds__(256) void mm_kernel(const short* __restrict__ A,
        const short* __restrict__ Bt, void* __restrict__ C,
        const float* __restrict__ bias, const float* __restrict__ resid,
        int M, int N, int K, int relu, int out_bf16)
{
    __shared__ short As[128 * 64];
    __shared__ short Bs[128 * 64];
    const int tid = threadIdx.x;
    const int wave = tid >> 6, lane = tid & 63;
    const int quad = lane >> 4, l15 = lane & 15;
    const int m0 = blockIdx.y * 128, n0 = blockIdx.x * 128;
    const int mw = (wave & 1) * 64, nw = (wave >> 1) * 64;

    f32x4 acc[4][4];
    #pragma unroll
    for (int i = 0; i < 4; ++i)
        #pragma unroll
        for (int j = 0; j < 4; ++j)
            acc[i][j] = (f32x4){0.f, 0.f, 0.f, 0.f};

    for (int k0 = 0; k0 < K; k0 += 64) {
        __syncthreads();
        #pragma unroll
        for (int r = 0; r < 4; ++r) {
            int c = r * 256 + tid;
            int row = c >> 3, seg = (c & 7) ^ (row & 7);
            GLL16(A + (size_t)(m0 + row) * K + k0 + seg * 8,
                  As + (size_t)(r * 256 + wave * 64) * 8);
            GLL16(Bt + (size_t)(n0 + row) * K + k0 + seg * 8,
                  Bs + (size_t)(r * 256 + wave * 64) * 8);
        }
        __syncthreads();
        b16x8 af[4][2], bf[4][2];
        #pragma unroll
        for (int i = 0; i < 4; ++i)
            #pragma unroll
            for (int kb = 0; kb < 2; ++kb) {
                int row = mw + i * 16 + l15;
                af[i][kb] = *(const b16x8*)(As + row * 64 + (((kb * 4 + quad) ^ (row & 7)) * 8));
            }
        #pragma unroll
        for (int j = 0; j < 4; ++j)
            #pragma unroll
            for (int kb = 0; kb < 2; ++kb) {
                int row = nw + j * 16 + l15;
                bf[j][kb] = *(const b16x8*)(Bs + row * 64 + (((kb * 4 + quad) ^ (row & 7)) * 8));
            }
        #pragma unroll
        for (int kb = 0; kb < 2; ++kb)
            #pragma unroll
            for (int i = 0; i < 4; ++i)
                #pragma unroll
                for (int j = 0; j < 4; ++j)
                    acc[i][j] = MFMA16(af[i][kb], bf[j][kb], acc[i][j]);
    }

    #pragma unroll
    for (int i = 0; i < 4; ++i) {
        #pragma unroll
        for (int r = 0; r < 4; ++r) {
            size_t row = (size_t)(m0 + mw + i * 16 + quad * 4 + r);
            #pragma unroll
            for (int j = 0; j < 4; ++j) {
                int col = n0 + nw + j * 16 + l15;
                float v = acc[i][j][r];
                if (bias)  v += bias[col];
                if (resid) v += resid[row * N + col];
                if (relu)  v = fmaxf(v, 0.0f);
                if (out_bf16) ((short*)C)[row * N + col] = f2bf(v);
                else          ((float*)C)[row * N + col] = v;
            }
        }
    }
}

// ---------------------------------------------------------------------------
// bf16 MFMA GEMM, 128(M)x64(N) tile, BK=64 (FFN2: long-K, throughput regime).
// ---------------------------------------------------------------------------
__global__ __launch_bounds__(256) void mm64_kernel(const short* __restrict__ A,
        const short* __restrict__ Bt, void* __restrict__ C,
        const float* __restrict__ bias, const float* __restrict__ resid,
        int M, int N, int K, int relu, int out_bf16)
{
    __shared__ short As[128 * 64];
    __shared__ short Bs[64 * 64];
    const int tid = threadIdx.x;
    const int wave = tid >> 6, lane = tid & 63;
    const int quad = lane >> 4, l15 = lane & 15;
    const int m0 = blockIdx.y * 128, n0 = blockIdx.x * 64;
    const int mw = (wave & 1) * 64, nw = (wave >> 1) * 32;

    f32x4 acc[4][2];
    #pragma unroll
    for (int i = 0; i < 4; ++i)
        #pragma unroll
        for (int j = 0; j < 2; ++j)
            acc[i][j] = (f32x4){0.f, 0.f, 0.f, 0.f};

    for (int k0 = 0; k0 < K; k0 += 64) {
        __syncthreads();
        #pragma unroll
        for (int r = 0; r < 4; ++r) {
            int c = r * 256 + tid;
            int row = c >> 3, seg = (c & 7) ^ (row & 7);
            GLL16(A + (size_t)(m0 + row) * K + k0 + seg * 8,
                  As + (size_t)(r * 256 + wave * 64) * 8);
        }
        #pragma unroll
        for (int r = 0; r < 2; ++r) {
            int c = r * 256 + tid;
            int row = c >> 3, seg = (c & 7) ^ (row & 7);
            GLL16(Bt + (size_t)(n0 + row) * K + k0 + seg * 8,
                  Bs + (size_t)(r * 256 + wave * 64) * 8);
        }
        __syncthreads();
        b16x8 af[4][2], bf[2][2];
        #pragma unroll
        for (int i = 0; i < 4; ++i)
            #pragma unroll
            for (int kb = 0; kb < 2; ++kb) {
                int row = mw + i * 16 + l15;
                af[i][kb] = *(const b16x8*)(As + row * 64 + (((kb * 4 + quad) ^ (row & 7)) * 8));
            }
        #pragma unroll
        for (int j = 0; j < 2; ++j)
            #pragma unroll
            for (int kb = 0; kb < 2; ++kb) {
                int row = nw + j * 16 + l15;
                bf[j][kb] = *(const b16x8*)(Bs + row * 64 + (((kb * 4 + quad) ^ (row & 7)) * 8));
            }
        #pragma unroll
        for (int kb = 0; kb < 2; ++kb)
            #pragma unroll
            for (int i = 0; i < 4; ++i)
                #pragma unroll
                for (int j = 0; j < 2; ++j)
                    acc[i][j] = MFMA16(af[i][kb], bf[j][kb], acc[i][j]);
    }

    #pragma unroll
    for (int i = 0; i < 4; ++i) {
        #pragma unroll
        for (int r = 0; r < 4; ++r) {
            size_t row = (size_t)(m0 + mw + i * 16 + quad * 4 + r);
            #pragma unroll
            for (int j = 0; j < 2; ++j) {
                int col = n0 + nw + j * 16 + l15;
                float v = acc[i][j][r];
                if (bias)  v += bias[col];
                if (resid) v += resid[row * N + col];
                if (relu)  v = fmaxf(v, 0.0f);
                if (out_bf16) ((short*)C)[row * N + col] = f2bf(v);
                else          ((float*)C)[row * N + col] = v;
            }
        }
    }
}

// ---------------------------------------------------------------------------
// bf16 MFMA GEMM, 64x64 tile, BK=64 (proj: short-K latency regime -> max TLP).
// 4 waves; wave owns 16-col strip of all 64 rows. grid = (N/64, M/64).
// ---------------------------------------------------------------------------
__global__ __launch_bounds__(256) void mm6464_kernel(const short* __restrict__ A,
        const short* __restrict__ Bt, void* __restrict__ C,
        const float* __restrict__ bias, const float* __restrict__ resid,
        int M, int N, int K, int relu, int out_bf16)
{
    __shared__ short As[64 * 64];
    __shared__ short Bs[64 * 64];
    const int tid = threadIdx.x;
    const int wave = tid >> 6, lane = tid & 63;
    const int quad = lane >> 4, l15 = lane & 15;
    const int m0 = blockIdx.y * 64, n0 = blockIdx.x * 64;
    const int nw = wave * 16;

    f32x4 acc[4];
    #pragma unroll
    for (int i = 0; i < 4; ++i) acc[i] = (f32x4){0.f, 0.f, 0.f, 0.f};

    for (int k0 = 0; k0 < K; k0 += 64) {
        __syncthreads();
        #pragma unroll
        for (int r = 0; r < 2; ++r) {
            int c = r * 256 + tid;
            int row = c >> 3, seg = (c & 7) ^ (row & 7);
            GLL16(A + (size_t)(m0 + row) * K + k0 + seg * 8,
                  As + (size_t)(r * 256 + wave * 64) * 8);
            GLL16(Bt + (size_t)(n0 + row) * K + k0 + seg * 8,
                  Bs + (size_t)(r * 256 + wave * 64) * 8);
        }
        __syncthreads();
        b16x8 af[4][2], bf[2];
        #pragma unroll
        for (int i = 0; i < 4; ++i)
            #pragma unroll
            for (int kb = 0; kb < 2; ++kb) {
                int row = i * 16 + l15;
                af[i][kb] = *(const b16x8*)(As + row * 64 + (((kb * 4 + quad) ^ (row & 7)) * 8));
            }
        #pragma unroll
        for (int kb = 0; kb < 2; ++kb) {
            int row = nw + l15;
            bf[kb] = *(const b16x8*)(Bs + row * 64 + (((kb * 4 + quad) ^ (row & 7)) * 8));
        }
        #pragma unroll
        for (int kb = 0; kb < 2; ++kb)
            #pragma unroll
            for (int i = 0; i < 4; ++i)
                acc[i] = MFMA16(af[i][kb], bf[kb], acc[i]);
    }

    #pragma unroll
    for (int i = 0; i < 4; ++i) {
        #pragma unroll
        for (int r = 0; r < 4; ++r) {
            size_t row = (size_t)(m0 + i * 16 + quad * 4 + r);
            int col = n0 + nw + l15;
            float v = acc[i][r];
            if (bias)  v += bias[col];
            if (resid) v += resid[row * N + col];
            if (relu)  v = fmaxf(v, 0.0f);
            if (out_bf16) ((short*)C)[row * N + col] = f2bf(v);
            else          ((float*)C)[row * N + col] = v;
        }
    }
}

// ---------------------------------------------------------------------------
// Flash attention, bf16 MFMA. qkv: [BT][1536] bf16 (q|k|v, each h*64+e).
// Q-tile 64, K-tile 64. grid (32 bh, 32 qt); qi = 31 - blockIdx.y (LPT).
// 34.8 KB LDS -> 4 blocks/CU. Softmax: DPP row reductions, raw-domain max,
// scale folded into exp2 via FMA, truncating P->bf16 stores.
// ---------------------------------------------------------------------------
__global__ __launch_bounds__(256) void attn_kernel(const short* __restrict__ qkv,
        short* __restrict__ Ob)
{
    __shared__ short Qs[64 * 64];   // swizzled 16B chunks: slot = row*8 + (seg^(row&7))
    __shared__ short Ks[64 * 64];   // swizzled
    __shared__ short Vt[64 * 72];   // [dh][token], stride 72
    __shared__ short Ps[64 * 72];   // [qrow][token], stride 72 (per-wave strips)

    const int tid = threadIdx.x;
    const int wave = tid >> 6, lane = tid & 63;
    const int quad = lane >> 4, l15 = lane & 15;
    const int bh = blockIdx.x;
    const int qi = 31 - (int)blockIdx.y;
    const int b = bh >> 3, h = bh & 7;
    const size_t tok0 = (size_t)b * T_;

    // stage Q tile (swizzled)
    #pragma unroll
    for (int r = 0; r < 2; ++r) {
        int c = r * 256 + tid;
        int tk = c >> 3;
        int seg = (c & 7) ^ (tk & 7);
        GLL16(qkv + (tok0 + qi * 64 + tk) * 1536 + h * 64 + seg * 8,
              Qs + (size_t)(r * 256 + wave * 64) * 8);
    }

    float mrow[4], lrow[4];
    f32x4 oacc[4];
    #pragma unroll
    for (int r = 0; r < 4; ++r) { mrow[r] = NEGINF_; lrow[r] = 0.0f; }
    #pragma unroll
    for (int nt = 0; nt < 4; ++nt) oacc[nt] = (f32x4){0.f, 0.f, 0.f, 0.f};

    b16x8 aq[2];

    for (int kj = 0; kj <= qi; ++kj) {
        __syncthreads();   // prev-iter LDS reads done (and Q GLL drained on kj=0)
        // stage K tile (swizzled)
        #pragma unroll
        for (int r = 0; r < 2; ++r) {
            int c = r * 256 + tid;
            int tk = c >> 3;
            int seg = (c & 7) ^ (tk & 7);
            GLL16(qkv + (tok0 + kj * 64 + tk) * 1536 + 512 + h * 64 + seg * 8,
                  Ks + (size_t)(r * 256 + wave * 64) * 8);
        }
        // stage V transposed: thread = (seg s 0..7, token-pair tp 0..31)
        {
            int s = tid >> 5, tp = tid & 31;
            const short* g0 = qkv + (tok0 + kj * 64 + tp * 2) * 1536 + 1024 + h * 64 + s * 8;
            b16x8 v0 = *(const b16x8*)g0;
            b16x8 v1 = *(const b16x8*)(g0 + 1536);
            int* vo = (int*)Vt;
            #pragma unroll
            for (int e = 0; e < 8; ++e) {
                unsigned int pk = (unsigned int)(unsigned short)v0[e]
                                | ((unsigned int)(unsigned short)v1[e] << 16);
                vo[(s * 8 + e) * 36 + tp] = pk;
            }
        }
        __syncthreads();

        if (kj == 0) {   // Qs ready after the barrier above; hoisted for all kj
            #pragma unroll
            for (int kb = 0; kb < 2; ++kb) {
                int row = wave * 16 + l15;
                aq[kb] = *(const b16x8*)(Qs + row * 64 + (((kb * 4 + quad) ^ (row & 7)) * 8));
            }
        }

        // S = Q K^T (raw domain)
        f32x4 sacc[4];
        #pragma unroll
        for (int nt = 0; nt < 4; ++nt) sacc[nt] = (f32x4){0.f, 0.f, 0.f, 0.f};
        #pragma unroll
        for (int nt = 0; nt < 4; ++nt) {
            int trow = nt * 16 + l15;
            #pragma unroll
            for (int kb = 0; kb < 2; ++kb) {
                b16x8 bk = *(const b16x8*)(Ks + trow * 64 + (((kb * 4 + quad) ^ (trow & 7)) * 8));
                sacc[nt] = MFMA16(aq[kb], bk, sacc[nt]);
            }
        }

        // causal mask (raw) + row max (raw domain)
        float mx[4];
        #pragma unroll
        for (int r = 0; r < 4; ++r) mx[r] = NEGINF_;
        const bool diag = (kj == qi);
        #pragma unroll
        for (int nt = 0; nt < 4; ++nt)
            #pragma unroll
            for (int r = 0; r < 4; ++r) {
                if (diag && (nt * 16 + l15) > (wave * 16 + quad * 4 + r))
                    sacc[nt][r] = NEGINF_;
                mx[r] = fmaxf(mx[r], sacc[nt][r]);
            }
        float alpha[4], mnsc[4], rs[4];
        #pragma unroll
        for (int r = 0; r < 4; ++r) {
            float m16 = rowmax16(mx[r]);
            float mn = fmaxf(mrow[r], m16);
            alpha[r] = EXP2F((mrow[r] - mn) * SC2_);
            mrow[r] = mn;
            mnsc[r] = mn * SC2_;
            rs[r] = 0.0f;
        }
        // P = exp2(S*SC2 - m*SC2); truncating bf16 store to LDS strip
        #pragma unroll
        for (int nt = 0; nt < 4; ++nt)
            #pragma unroll
            for (int r = 0; r < 4; ++r) {
                float e = EXP2F(fmaf(sacc[nt][r], SC2_, -mnsc[r]));
                rs[r] += e;
                Ps[(wave * 16 + quad * 4 + r) * 72 + nt * 16 + l15] = f2bf_trunc(e);
            }
        #pragma unroll
        for (int r = 0; r < 4; ++r)
            lrow[r] = lrow[r] * alpha[r] + rowsum16(rs[r]);
        // rescale O
        #pragma unroll
        for (int nt = 0; nt < 4; ++nt)
            #pragma unroll
            for (int r = 0; r < 4; ++r)
                oacc[nt][r] *= alpha[r];
        // O += P @ V  (same-wave LDS readback; DS ops in-order within a wave)
        b16x8 ap[2];
        #pragma unroll
        for (int kb = 0; kb < 2; ++kb)
            ap[kb] = *(const b16x8*)(Ps + (wave * 16 + l15) * 72 + kb * 32 + quad * 8);
        #pragma unroll
        for (int nt = 0; nt < 4; ++nt)
            #pragma unroll
            for (int kb = 0; kb < 2; ++kb) {
                b16x8 bv = *(const b16x8*)(Vt + (nt * 16 + l15) * 72 + kb * 32 + quad * 8);
                oacc[nt] = MFMA16(ap[kb], bv, oacc[nt]);
            }
    }

    // epilogue: normalize and store bf16
    #pragma unroll
    for (int r = 0; r < 4; ++r) {
        float inv = 1.0f / lrow[r];
        size_t row = tok0 + (size_t)qi * 64 + wave * 16 + quad * 4 + r;
        #pragma unroll
        for (int nt = 0; nt < 4; ++nt)
            Ob[row * 512 + h * 64 + nt * 16 + l15] = f2bf(oacc[nt][r] * inv);
    }
}

// ---------------------------------------------------------------------------
extern "C" void kernel_launch(void* const* d_in, const int* in_sizes, int n_in,
                              void* d_out, int out_size, void* d_ws, size_t ws_size,
                              hipStream_t stream) {
    (void)in_sizes; (void)n_in; (void)out_size; (void)ws_size;
    const float* x     = (const float*)d_in[0];
    const float* ln_g  = (const float*)d_in[1];
    const float* ln_b  = (const float*)d_in[2];
    const float* Wq    = (const float*)d_in[3];
    const float* Wk    = (const float*)d_in[4];
    const float* Wv    = (const float*)d_in[5];
    const float* Wproj = (const float*)d_in[6];
    const float* bproj = (const float*)d_in[7];
    const float* W1    = (const float*)d_in[8];
    const float* b1    = (const float*)d_in[9];
    const float* W2    = (const float*)d_in[10];
    const float* b2    = (const float*)d_in[11];
    float* out = (float*)d_out;

    char* W = (char*)d_ws;
    short* hbuf  = (short*)(W + 0);                    // 8 MB  (LN out, bf16)
    short* qkvb  = (short*)(W + ((size_t)8  << 20));   // 24 MB [BT][1536]
    short* attno = (short*)(W + ((size_t)32 << 20));   // 8 MB  [BT][512]
    float* x1    = (float*)(W + ((size_t)40 << 20));   // 16 MB
    short* ff1   = (short*)(W + ((size_t)56 << 20));   // 32 MB [BT][2048]
    short* wqkv  = (short*)(W + ((size_t)88 << 20));   // 1.5 MB [1536][512]
    short* wpt   = (short*)(W + ((size_t)90 << 20));   // 0.5 MB [512][512]
    short* w1t   = (short*)(W + ((size_t)91 << 20));   // 2 MB  [2048][512]
    short* w2t   = (short*)(W + ((size_t)93 << 20));   // 2 MB  [512][2048]

    // 0. all weight transposes in one launch
    prep_kernel<<<dim3(3072), dim3(32, 8), 0, stream>>>(
        Wq, Wk, Wv, Wproj, W1, W2, wqkv, wpt, w1t, w2t);
    // 1. h = LN(x) -> bf16
    ln_kernel<<<dim3(BT_), dim3(64), 0, stream>>>(x, ln_g, ln_b, hbuf);
    // 2. qkv = h @ Wqkv  [8192,1536] bf16
    mm_kernel<<<dim3(12, 64), dim3(256), 0, stream>>>(hbuf, wqkv, qkvb,
        nullptr, nullptr, BT_, 1536, D_, 0, 1);
    // 3. attention -> attno bf16
    attn_kernel<<<dim3(32, 32), dim3(256), 0, stream>>>(qkvb, attno);
    // 4. x1 = x + attno @ Wproj + bproj  (fp32), 64x64 tile -> 1024 blocks
    mm6464_kernel<<<dim3(8, 128), dim3(256), 0, stream>>>(attno, wpt, x1,
        bproj, x, BT_, D_, D_, 0, 0);
    // 5. h2 = LN(x1) -> bf16 (reuse hbuf)
    ln_kernel<<<dim3(BT_), dim3(64), 0, stream>>>(x1, ln_g, ln_b, hbuf);
    // 6. ff1 = relu(h2 @ W1 + b1)  bf16
    mm_kernel<<<dim3(16, 64), dim3(256), 0, stream>>>(hbuf, w1t, ff1,
        b1, nullptr, BT_, FF_, D_, 1, 1);
    // 7. out = x1 + ff1 @ W2 + b2  (fp32)
    mm64_kernel<<<dim3(8, 64), dim3(256), 0, stream>>>(ff1, w2t, out,
        b2, x1, BT_, D_, FF_, 0, 0);
}

// Round 6
// 310.010 us; speedup vs baseline: 4.2617x; 1.0246x over previous
//
#include <hip/hip_runtime.h>
#include <math.h>

#define B_ 4
#define T_ 2048
#define D_ 512
#define H_ 8
#define DH_ 64
#define BT_ 8192
#define FF_ 2048
#define EPS_ 1e-5f
#define SCALE_ 0.04419417382415922f   // 512^-0.5
#define SC2_ 0.06375861151f           // SCALE_ * log2(e)
#define NEGINF_ -1e30f

typedef short b16x8 __attribute__((ext_vector_type(8)));
typedef short b16x4 __attribute__((ext_vector_type(4)));
typedef float f32x4 __attribute__((ext_vector_type(4)));

#define MFMA16(a, b, c) __builtin_amdgcn_mfma_f32_16x16x32_bf16(a, b, c, 0, 0, 0)
#define MFMA16K16(a, b, c) __builtin_amdgcn_mfma_f32_16x16x16bf16_1k(a, b, c, 0, 0, 0)

#define GLL16(gp, lp) \
    __builtin_amdgcn_global_load_lds((const __attribute__((address_space(1))) void*)(gp), \
                                     (__attribute__((address_space(3))) void*)(lp), 16, 0, 0)

#if __has_builtin(__builtin_amdgcn_exp2f)
#define EXP2F(x) __builtin_amdgcn_exp2f(x)
#else
#define EXP2F(x) exp2f(x)
#endif

// fp32 -> bf16 RNE (finite inputs)
static __device__ inline short f2bf(float f) {
    unsigned int u = __builtin_bit_cast(unsigned int, f);
    unsigned int r = (u + 0x7fffu + ((u >> 16) & 1u)) >> 16;
    return (short)r;
}
// fp32 -> bf16 truncation (1 VALU op; used for P where bias is negligible)
static __device__ inline short f2bf_trunc(float f) {
    return (short)(__builtin_bit_cast(unsigned int, f) >> 16);
}

// ---------------------------------------------------------------------------
// LayerNorm: one wave per row of 512, fp32 in -> bf16 out
// ---------------------------------------------------------------------------
__global__ __launch_bounds__(64) void ln_kernel(const float* __restrict__ X,
        const float* __restrict__ G, const float* __restrict__ Bb,
        short* __restrict__ Y)
{
    int row = blockIdx.x;
    int t = threadIdx.x;
    const float* xr = X + (size_t)row * D_;
    float4 v0 = *(const float4*)(xr + t * 4);
    float4 v1 = *(const float4*)(xr + 256 + t * 4);
    float sum = v0.x + v0.y + v0.z + v0.w + v1.x + v1.y + v1.z + v1.w;
    float ssq = v0.x*v0.x + v0.y*v0.y + v0.z*v0.z + v0.w*v0.w
              + v1.x*v1.x + v1.y*v1.y + v1.z*v1.z + v1.w*v1.w;
    #pragma unroll
    for (int off = 32; off > 0; off >>= 1) {
        sum += __shfl_down(sum, off);
        ssq += __shfl_down(ssq, off);
    }
    sum = __shfl(sum, 0);
    ssq = __shfl(ssq, 0);
    float mean = sum * (1.0f / D_);
    float var  = ssq * (1.0f / D_) - mean * mean;
    float rstd = rsqrtf(var + EPS_);

    float4 g0 = *(const float4*)(G + t * 4);
    float4 g1 = *(const float4*)(G + 256 + t * 4);
    float4 b0 = *(const float4*)(Bb + t * 4);
    float4 b1 = *(const float4*)(Bb + 256 + t * 4);
    short4 o0, o1;
    o0.x = f2bf((v0.x - mean) * rstd * g0.x + b0.x);
    o0.y = f2bf((v0.y - mean) * rstd * g0.y + b0.y);
    o0.z = f2bf((v0.z - mean) * rstd * g0.z + b0.z);
    o0.w = f2bf((v0.w - mean) * rstd * g0.w + b0.w);
    o1.x = f2bf((v1.x - mean) * rstd * g1.x + b1.x);
    o1.y = f2bf((v1.y - mean) * rstd * g1.y + b1.y);
    o1.z = f2bf((v1.z - mean) * rstd * g1.z + b1.z);
    o1.w = f2bf((v1.w - mean) * rstd * g1.w + b1.w);
    short* yr = Y + (size_t)row * D_;
    *(short4*)(yr + t * 4)       = o0;
    *(short4*)(yr + 256 + t * 4) = o1;
}

// ---------------------------------------------------------------------------
// All weight transposes fused into one launch. 3072 tiles of 32x32.
// block (32,8).
// ---------------------------------------------------------------------------
__global__ __launch_bounds__(256) void prep_kernel(
        const float* __restrict__ Wq, const float* __restrict__ Wk,
        const float* __restrict__ Wv, const float* __restrict__ Wp,
        const float* __restrict__ W1, const float* __restrict__ W2,
        short* __restrict__ wqkv, short* __restrict__ wpt,
        short* __restrict__ w1t, short* __restrict__ w2t)
{
    __shared__ float tile[32][33];
    int idx = blockIdx.x;
    const float* src; short* dst; int R, C, tx0, ty0;
    if (idx < 768) {            // Wq/Wk/Wv: per head [512][64] -> [64][512]
        int w = idx >> 8, rem = idx & 255;
        int hh = rem >> 5, t = rem & 31;
        const float* base = (w == 0) ? Wq : ((w == 1) ? Wk : Wv);
        src = base + hh * (D_ * DH_);
        dst = wqkv + w * (512 * 512) + hh * (DH_ * D_);
        R = 512; C = 64; tx0 = (t & 1) * 32; ty0 = (t >> 1) * 32;
    } else if (idx < 1024) {    // Wproj [512][512]
        int t = idx - 768;
        src = Wp; dst = wpt; R = 512; C = 512;
        tx0 = (t & 15) * 32; ty0 = (t >> 4) * 32;
    } else if (idx < 2048) {    // W1 [512][2048] -> [2048][512]
        int t = idx - 1024;
        src = W1; dst = w1t; R = 512; C = 2048;
        tx0 = (t & 63) * 32; ty0 = (t >> 6) * 32;
    } else {                    // W2 [2048][512] -> [512][2048]
        int t = idx - 2048;
        src = W2; dst = w2t; R = 2048; C = 512;
        tx0 = (t & 15) * 32; ty0 = (t >> 4) * 32;
    }
    int tx = threadIdx.x, ty = threadIdx.y;
    #pragma unroll
    for (int i = 0; i < 32; i += 8)
        tile[ty + i][tx] = src[(size_t)(ty0 + ty + i) * C + tx0 + tx];
    __syncthreads();
    #pragma unroll
    for (int i = 0; i < 32; i += 8)
        dst[(size_t)(tx0 + ty + i) * R + ty0 + tx] = f2bf(tile[tx][ty + i]);
}

// ---------------------------------------------------------------------------
// bf16 MFMA GEMM: C[M,N] = A[M,K] @ Bt[N,K]^T.  128x128 tile, BK=64,
// 256 threads (4 waves x 64x64), global_load_lds with XOR-swizzled chunks.
// ---------------------------------------------------------------------------
__global__ __launch_bounds__(256) void mm_kernel(const short* __restrict__ A,
        const short* __restrict__ Bt, void* __restrict__ C,
        const float* __restrict__ bias, const float* __restrict__ resid,
        int M, int N, int K, int relu, int out_bf16)
{
    __shared__ short As[128 * 64];
    __shared__ short Bs[128 * 64];
    const int tid = threadIdx.x;
    const int wave = tid >> 6, lane = tid & 63;
    const int quad = lane >> 4, l15 = lane & 15;
    const int m0 = blockIdx.y * 128, n0 = blockIdx.x * 128;
    const int mw = (wave & 1) * 64, nw = (wave >> 1) * 64;

    f32x4 acc[4][4];
    #pragma unroll
    for (int i = 0; i < 4; ++i)
        #pragma unroll
        for (int j = 0; j < 4; ++j)
            acc[i][j] = (f32x4){0.f, 0.f, 0.f, 0.f};

    for (int k0 = 0; k0 < K; k0 += 64) {
        __syncthreads();
        #pragma unroll
        for (int r = 0; r < 4; ++r) {
            int c = r * 256 + tid;
            int row = c >> 3, seg = (c & 7) ^ (row & 7);
            GLL16(A + (size_t)(m0 + row) * K + k0 + seg * 8,
                  As + (size_t)(r * 256 + wave * 64) * 8);
            GLL16(Bt + (size_t)(n0 + row) * K + k0 + seg * 8,
                  Bs + (size_t)(r * 256 + wave * 64) * 8);
        }
        __syncthreads();
        b16x8 af[4][2], bf[4][2];
        #pragma unroll
        for (int i = 0; i < 4; ++i)
            #pragma unroll
            for (int kb = 0; kb < 2; ++kb) {
                int row = mw + i * 16 + l15;
                af[i][kb] = *(const b16x8*)(As + row * 64 + (((kb * 4 + quad) ^ (row & 7)) * 8));
            }
        #pragma unroll
        for (int j = 0; j < 4; ++j)
            #pragma unroll
            for (int kb = 0; kb < 2; ++kb) {
                int row = nw + j * 16 + l15;
                bf[j][kb] = *(const b16x8*)(Bs + row * 64 + (((kb * 4 + quad) ^ (row & 7)) * 8));
            }
        #pragma unroll
        for (int kb = 0; kb < 2; ++kb)
            #pragma unroll
            for (int i = 0; i < 4; ++i)
                #pragma unroll
                for (int j = 0; j < 4; ++j)
                    acc[i][j] = MFMA16(af[i][kb], bf[j][kb], acc[i][j]);
    }

    #pragma unroll
    for (int i = 0; i < 4; ++i) {
        #pragma unroll
        for (int r = 0; r < 4; ++r) {
            size_t row = (size_t)(m0 + mw + i * 16 + quad * 4 + r);
            #pragma unroll
            for (int j = 0; j < 4; ++j) {
                int col = n0 + nw + j * 16 + l15;
                float v = acc[i][j][r];
                if (bias)  v += bias[col];
                if (resid) v += resid[row * N + col];
                if (relu)  v = fmaxf(v, 0.0f);
                if (out_bf16) ((short*)C)[row * N + col] = f2bf(v);
                else          ((float*)C)[row * N + col] = v;
            }
        }
    }
}

// ---------------------------------------------------------------------------
// bf16 MFMA GEMM, 128(M)x64(N) tile, BK=64 (FFN2: long-K, throughput regime).
// ---------------------------------------------------------------------------
__global__ __launch_bounds__(256) void mm64_kernel(const short* __restrict__ A,
        const short* __restrict__ Bt, void* __restrict__ C,
        const float* __restrict__ bias, const float* __restrict__ resid,
        int M, int N, int K, int relu, int out_bf16)
{
    __shared__ short As[128 * 64];
    __shared__ short Bs[64 * 64];
    const int tid = threadIdx.x;
    const int wave = tid >> 6, lane = tid & 63;
    const int quad = lane >> 4, l15 = lane & 15;
    const int m0 = blockIdx.y * 128, n0 = blockIdx.x * 64;
    const int mw = (wave & 1) * 64, nw = (wave >> 1) * 32;

    f32x4 acc[4][2];
    #pragma unroll
    for (int i = 0; i < 4; ++i)
        #pragma unroll
        for (int j = 0; j < 2; ++j)
            acc[i][j] = (f32x4){0.f, 0.f, 0.f, 0.f};

    for (int k0 = 0; k0 < K; k0 += 64) {
        __syncthreads();
        #pragma unroll
        for (int r = 0; r < 4; ++r) {
            int c = r * 256 + tid;
            int row = c >> 3, seg = (c & 7) ^ (row & 7);
            GLL16(A + (size_t)(m0 + row) * K + k0 + seg * 8,
                  As + (size_t)(r * 256 + wave * 64) * 8);
        }
        #pragma unroll
        for (int r = 0; r < 2; ++r) {
            int c = r * 256 + tid;
            int row = c >> 3, seg = (c & 7) ^ (row & 7);
            GLL16(Bt + (size_t)(n0 + row) * K + k0 + seg * 8,
                  Bs + (size_t)(r * 256 + wave * 64) * 8);
        }
        __syncthreads();
        b16x8 af[4][2], bf[2][2];
        #pragma unroll
        for (int i = 0; i < 4; ++i)
            #pragma unroll
            for (int kb = 0; kb < 2; ++kb) {
                int row = mw + i * 16 + l15;
                af[i][kb] = *(const b16x8*)(As + row * 64 + (((kb * 4 + quad) ^ (row & 7)) * 8));
            }
        #pragma unroll
        for (int j = 0; j < 2; ++j)
            #pragma unroll
            for (int kb = 0; kb < 2; ++kb) {
                int row = nw + j * 16 + l15;
                bf[j][kb] = *(const b16x8*)(Bs + row * 64 + (((kb * 4 + quad) ^ (row & 7)) * 8));
            }
        #pragma unroll
        for (int kb = 0; kb < 2; ++kb)
            #pragma unroll
            for (int i = 0; i < 4; ++i)
                #pragma unroll
                for (int j = 0; j < 2; ++j)
                    acc[i][j] = MFMA16(af[i][kb], bf[j][kb], acc[i][j]);
    }

    #pragma unroll
    for (int i = 0; i < 4; ++i) {
        #pragma unroll
        for (int r = 0; r < 4; ++r) {
            size_t row = (size_t)(m0 + mw + i * 16 + quad * 4 + r);
            #pragma unroll
            for (int j = 0; j < 2; ++j) {
                int col = n0 + nw + j * 16 + l15;
                float v = acc[i][j][r];
                if (bias)  v += bias[col];
                if (resid) v += resid[row * N + col];
                if (relu)  v = fmaxf(v, 0.0f);
                if (out_bf16) ((short*)C)[row * N + col] = f2bf(v);
                else          ((float*)C)[row * N + col] = v;
            }
        }
    }
}

// ---------------------------------------------------------------------------
// bf16 MFMA GEMM, 64x64 tile, BK=64 (proj: short-K latency regime -> max TLP).
// ---------------------------------------------------------------------------
__global__ __launch_bounds__(256) void mm6464_kernel(const short* __restrict__ A,
        const short* __restrict__ Bt, void* __restrict__ C,
        const float* __restrict__ bias, const float* __restrict__ resid,
        int M, int N, int K, int relu, int out_bf16)
{
    __shared__ short As[64 * 64];
    __shared__ short Bs[64 * 64];
    const int tid = threadIdx.x;
    const int wave = tid >> 6, lane = tid & 63;
    const int quad = lane >> 4, l15 = lane & 15;
    const int m0 = blockIdx.y * 64, n0 = blockIdx.x * 64;
    const int nw = wave * 16;

    f32x4 acc[4];
    #pragma unroll
    for (int i = 0; i < 4; ++i) acc[i] = (f32x4){0.f, 0.f, 0.f, 0.f};

    for (int k0 = 0; k0 < K; k0 += 64) {
        __syncthreads();
        #pragma unroll
        for (int r = 0; r < 2; ++r) {
            int c = r * 256 + tid;
            int row = c >> 3, seg = (c & 7) ^ (row & 7);
            GLL16(A + (size_t)(m0 + row) * K + k0 + seg * 8,
                  As + (size_t)(r * 256 + wave * 64) * 8);
            GLL16(Bt + (size_t)(n0 + row) * K + k0 + seg * 8,
                  Bs + (size_t)(r * 256 + wave * 64) * 8);
        }
        __syncthreads();
        b16x8 af[4][2], bf[2];
        #pragma unroll
        for (int i = 0; i < 4; ++i)
            #pragma unroll
            for (int kb = 0; kb < 2; ++kb) {
                int row = i * 16 + l15;
                af[i][kb] = *(const b16x8*)(As + row * 64 + (((kb * 4 + quad) ^ (row & 7)) * 8));
            }
        #pragma unroll
        for (int kb = 0; kb < 2; ++kb) {
            int row = nw + l15;
            bf[kb] = *(const b16x8*)(Bs + row * 64 + (((kb * 4 + quad) ^ (row & 7)) * 8));
        }
        #pragma unroll
        for (int kb = 0; kb < 2; ++kb)
            #pragma unroll
            for (int i = 0; i < 4; ++i)
                acc[i] = MFMA16(af[i][kb], bf[kb], acc[i]);
    }

    #pragma unroll
    for (int i = 0; i < 4; ++i) {
        #pragma unroll
        for (int r = 0; r < 4; ++r) {
            size_t row = (size_t)(m0 + i * 16 + quad * 4 + r);
            int col = n0 + nw + l15;
            float v = acc[i][r];
            if (bias)  v += bias[col];
            if (resid) v += resid[row * N + col];
            if (relu)  v = fmaxf(v, 0.0f);
            if (out_bf16) ((short*)C)[row * N + col] = f2bf(v);
            else          ((float*)C)[row * N + col] = v;
        }
    }
}

// ---------------------------------------------------------------------------
// Flash attention, S^T formulation. qkv: [BT][1536] bf16 (q|k|v, each h*64+e).
// grid (32 bh, 32 qt); qi = 31 - blockIdx.y (LPT).
// S^T = K·Q^T via 16x16x32 (C-layout: token=quad*4+r, qrow=l15) -- which IS
// the B-operand layout of 16x16x16 MFMA, so P stays in registers and
// O^T += V^T·P^T needs no P LDS round-trip. Softmax state per-lane scalar.
// Epilogue: same-wave LDS repack -> coalesced b16x8 stores.
// ---------------------------------------------------------------------------
__global__ __launch_bounds__(256) void attn_kernel(const short* __restrict__ qkv,
        short* __restrict__ Ob)
{
    __shared__ short Qs[64 * 64];   // [qrow][dh], swizzled 16B chunks
    __shared__ short Ks[64 * 64];   // [tok][dh], swizzled
    __shared__ short Vt[64 * 72];   // [dh][tok], stride 72
    __shared__ short Osh[64 * 72];  // [qrow][dh] repack, stride 72

    const int tid = threadIdx.x;
    const int wave = tid >> 6, lane = tid & 63;
    const int quad = lane >> 4, l15 = lane & 15;
    const int bh = blockIdx.x;
    const int qi = 31 - (int)blockIdx.y;
    const int b = bh >> 3, h = bh & 7;
    const size_t tok0 = (size_t)b * T_;
    const int qrow_rel = wave * 16 + l15;   // this lane's q-row within the tile

    // stage Q tile (swizzled)
    #pragma unroll
    for (int r = 0; r < 2; ++r) {
        int c = r * 256 + tid;
        int tk = c >> 3;
        int seg = (c & 7) ^ (tk & 7);
        GLL16(qkv + (tok0 + qi * 64 + tk) * 1536 + h * 64 + seg * 8,
              Qs + (size_t)(r * 256 + wave * 64) * 8);
    }

    float mrow = NEGINF_, lrow = 0.0f;
    f32x4 ot[4];   // O^T: row=dh=dt*16+quad*4+rr, col=qrow=l15
    #pragma unroll
    for (int dt = 0; dt < 4; ++dt) ot[dt] = (f32x4){0.f, 0.f, 0.f, 0.f};

    b16x8 qf[2];

    for (int kj = 0; kj <= qi; ++kj) {
        __syncthreads();   // prev-iter LDS reads done (and Q GLL drained on kj=0)
        // stage K tile (swizzled)
        #pragma unroll
        for (int r = 0; r < 2; ++r) {
            int c = r * 256 + tid;
            int tk = c >> 3;
            int seg = (c & 7) ^ (tk & 7);
            GLL16(qkv + (tok0 + kj * 64 + tk) * 1536 + 512 + h * 64 + seg * 8,
                  Ks + (size_t)(r * 256 + wave * 64) * 8);
        }
        // stage V transposed: thread = (seg s 0..7, token-pair tp 0..31)
        {
            int s = tid >> 5, tp = tid & 31;
            const short* g0 = qkv + (tok0 + kj * 64 + tp * 2) * 1536 + 1024 + h * 64 + s * 8;
            b16x8 v0 = *(const b16x8*)g0;
            b16x8 v1 = *(const b16x8*)(g0 + 1536);
            int* vo = (int*)Vt;
            #pragma unroll
            for (int e = 0; e < 8; ++e) {
                unsigned int pk = (unsigned int)(unsigned short)v0[e]
                                | ((unsigned int)(unsigned short)v1[e] << 16);
                vo[(s * 8 + e) * 36 + tp] = pk;
            }
        }
        __syncthreads();

        if (kj == 0) {   // Q fragment (B-operand: n=l15=qrow, k=quad*8+j), hoisted
            #pragma unroll
            for (int kb = 0; kb < 2; ++kb) {
                int row = wave * 16 + l15;
                qf[kb] = *(const b16x8*)(Qs + row * 64 + (((kb * 4 + quad) ^ (row & 7)) * 8));
            }
        }

        // S^T = K Q^T  (A=K-frag, B=Q-frag)
        f32x4 st[4];   // mt token-tiles: token = mt*16+quad*4+r, qrow = l15
        #pragma unroll
        for (int mt = 0; mt < 4; ++mt) st[mt] = (f32x4){0.f, 0.f, 0.f, 0.f};
        #pragma unroll
        for (int mt = 0; mt < 4; ++mt) {
            int trow = mt * 16 + l15;
            #pragma unroll
            for (int kb = 0; kb < 2; ++kb) {
                b16x8 kf = *(const b16x8*)(Ks + trow * 64 + (((kb * 4 + quad) ^ (trow & 7)) * 8));
                st[mt] = MFMA16(kf, qf[kb], st[mt]);
            }
        }

        // causal mask + token-max (in-lane 16 + cross-quad 2 shuffles)
        const bool diag = (kj == qi);
        float mx = NEGINF_;
        #pragma unroll
        for (int mt = 0; mt < 4; ++mt)
            #pragma unroll
            for (int r = 0; r < 4; ++r) {
                if (diag && (mt * 16 + quad * 4 + r) > qrow_rel) st[mt][r] = NEGINF_;
                mx = fmaxf(mx, st[mt][r]);
            }
        mx = fmaxf(mx, __shfl_xor(mx, 16));
        mx = fmaxf(mx, __shfl_xor(mx, 32));
        float mn = fmaxf(mrow, mx);
        float alpha = EXP2F((mrow - mn) * SC2_);
        float mnsc = mn * SC2_;
        mrow = mn;
        float rs = 0.0f;
        b16x4 pf[4];   // P^T fragments: directly in 16x16x16 B-operand layout
        #pragma unroll
        for (int mt = 0; mt < 4; ++mt)
            #pragma unroll
            for (int r = 0; r < 4; ++r) {
                float e = EXP2F(fmaf(st[mt][r], SC2_, -mnsc));
                rs += e;
                pf[mt][r] = f2bf_trunc(e);
            }
        rs += __shfl_xor(rs, 16);
        rs += __shfl_xor(rs, 32);
        lrow = lrow * alpha + rs;
        #pragma unroll
        for (int dt = 0; dt < 4; ++dt) {
            ot[dt][0] *= alpha; ot[dt][1] *= alpha;
            ot[dt][2] *= alpha; ot[dt][3] *= alpha;
        }
        // O^T += V^T P^T  (16x16x16; A=V^T-frag from Vt, B=P^T in registers)
        #pragma unroll
        for (int dt = 0; dt < 4; ++dt) {
            const short* vrow = Vt + (dt * 16 + l15) * 72;
            #pragma unroll
            for (int kt = 0; kt < 4; ++kt) {
                b16x4 vf = *(const b16x4*)(vrow + kt * 16 + quad * 4);
                ot[dt] = MFMA16K16(vf, pf[kt], ot[dt]);
            }
        }
    }

    // epilogue: normalize, repack via same-wave LDS strip, coalesced store
    float inv = 1.0f / lrow;
    #pragma unroll
    for (int dt = 0; dt < 4; ++dt) {
        b16x4 o4;
        o4[0] = f2bf(ot[dt][0] * inv);
        o4[1] = f2bf(ot[dt][1] * inv);
        o4[2] = f2bf(ot[dt][2] * inv);
        o4[3] = f2bf(ot[dt][3] * inv);
        *(b16x4*)(Osh + (size_t)qrow_rel * 72 + dt * 16 + quad * 4) = o4;
    }
    // rows tid>>2 land inside this wave's own strip -> DS in-order, no barrier
    {
        int row = tid >> 2, ch = tid & 3;
        b16x8 lo = *(const b16x8*)(Osh + (size_t)row * 72 + ch * 16);
        b16x8 hi = *(const b16x8*)(Osh + (size_t)row * 72 + ch * 16 + 8);
        short* dst = Ob + (tok0 + (size_t)qi * 64 + row) * 512 + h * 64 + ch * 16;
        *(b16x8*)dst = lo;
        *(b16x8*)(dst + 8) = hi;
    }
}

// ---------------------------------------------------------------------------
extern "C" void kernel_launch(void* const* d_in, const int* in_sizes, int n_in,
                              void* d_out, int out_size, void* d_ws, size_t ws_size,
                              hipStream_t stream) {
    (void)in_sizes; (void)n_in; (void)out_size; (void)ws_size;
    const float* x     = (const float*)d_in[0];
    const float* ln_g  = (const float*)d_in[1];
    const float* ln_b  = (const float*)d_in[2];
    const float* Wq    = (const float*)d_in[3];
    const float* Wk    = (const float*)d_in[4];
    const float* Wv    = (const float*)d_in[5];
    const float* Wproj = (const float*)d_in[6];
    const float* bproj = (const float*)d_in[7];
    const float* W1    = (const float*)d_in[8];
    const float* b1    = (const float*)d_in[9];
    const float* W2    = (const float*)d_in[10];
    const float* b2    = (const float*)d_in[11];
    float* out = (float*)d_out;

    char* W = (char*)d_ws;
    short* hbuf  = (short*)(W + 0);                    // 8 MB  (LN out, bf16)
    short* qkvb  = (short*)(W + ((size_t)8  << 20));   // 24 MB [BT][1536]
    short* attno = (short*)(W + ((size_t)32 << 20));   // 8 MB  [BT][512]
    float* x1    = (float*)(W + ((size_t)40 << 20));   // 16 MB
    short* ff1   = (short*)(W + ((size_t)56 << 20));   // 32 MB [BT][2048]
    short* wqkv  = (short*)(W + ((size_t)88 << 20));   // 1.5 MB [1536][512]
    short* wpt   = (short*)(W + ((size_t)90 << 20));   // 0.5 MB [512][512]
    short* w1t   = (short*)(W + ((size_t)91 << 20));   // 2 MB  [2048][512]
    short* w2t   = (short*)(W + ((size_t)93 << 20));   // 2 MB  [512][2048]

    // 0. all weight transposes in one launch
    prep_kernel<<<dim3(3072), dim3(32, 8), 0, stream>>>(
        Wq, Wk, Wv, Wproj, W1, W2, wqkv, wpt, w1t, w2t);
    // 1. h = LN(x) -> bf16
    ln_kernel<<<dim3(BT_), dim3(64), 0, stream>>>(x, ln_g, ln_b, hbuf);
    // 2. qkv = h @ Wqkv  [8192,1536] bf16
    mm_kernel<<<dim3(12, 64), dim3(256), 0, stream>>>(hbuf, wqkv, qkvb,
        nullptr, nullptr, BT_, 1536, D_, 0, 1);
    // 3. attention -> attno bf16
    attn_kernel<<<dim3(32, 32), dim3(256), 0, stream>>>(qkvb, attno);
    // 4. x1 = x + attno @ Wproj + bproj  (fp32), 64x64 tile -> 1024 blocks
    mm6464_kernel<<<dim3(8, 128), dim3(256), 0, stream>>>(attno, wpt, x1,
        bproj, x, BT_, D_, D_, 0, 0);
    // 5. h2 = LN(x1) -> bf16 (reuse hbuf)
    ln_kernel<<<dim3(BT_), dim3(64), 0, stream>>>(x1, ln_g, ln_b, hbuf);
    // 6. ff1 = relu(h2 @ W1 + b1)  bf16
    mm_kernel<<<dim3(16, 64), dim3(256), 0, stream>>>(hbuf, w1t, ff1,
        b1, nullptr, BT_, FF_, D_, 1, 1);
    // 7. out = x1 + ff1 @ W2 + b2  (fp32)
    mm64_kernel<<<dim3(8, 64), dim3(256), 0, stream>>>(ff1, w2t, out,
        b2, x1, BT_, D_, FF_, 0, 0);
}

// Round 7
// 298.708 us; speedup vs baseline: 4.4229x; 1.0378x over previous
//
#include <hip/hip_runtime.h>
#include <math.h>

#define B_ 4
#define T_ 2048
#define D_ 512
#define H_ 8
#define DH_ 64
#define BT_ 8192
#define FF_ 2048
#define EPS_ 1e-5f
#define SCALE_ 0.04419417382415922f   // 512^-0.5
#define SC2_ 0.06375861151f           // SCALE_ * log2(e)
#define NEGINF_ -1e30f

typedef short b16x8 __attribute__((ext_vector_type(8)));
typedef short b16x4 __attribute__((ext_vector_type(4)));
typedef float f32x4 __attribute__((ext_vector_type(4)));

#define MFMA16(a, b, c) __builtin_amdgcn_mfma_f32_16x16x32_bf16(a, b, c, 0, 0, 0)
#define MFMA16K16(a, b, c) __builtin_amdgcn_mfma_f32_16x16x16bf16_1k(a, b, c, 0, 0, 0)

#define GLL16(gp, lp) \
    __builtin_amdgcn_global_load_lds((const __attribute__((address_space(1))) void*)(gp), \
                                     (__attribute__((address_space(3))) void*)(lp), 16, 0, 0)

#if __has_builtin(__builtin_amdgcn_exp2f)
#define EXP2F(x) __builtin_amdgcn_exp2f(x)
#else
#define EXP2F(x) exp2f(x)
#endif

// fp32 -> bf16 RNE (finite inputs)
static __device__ inline short f2bf(float f) {
    unsigned int u = __builtin_bit_cast(unsigned int, f);
    unsigned int r = (u + 0x7fffu + ((u >> 16) & 1u)) >> 16;
    return (short)r;
}
// fp32 -> bf16 truncation (1 VALU op; used for P where bias is negligible)
static __device__ inline short f2bf_trunc(float f) {
    return (short)(__builtin_bit_cast(unsigned int, f) >> 16);
}

// ---------------------------------------------------------------------------
// LayerNorm: one wave per row of 512, fp32 in -> bf16 out
// ---------------------------------------------------------------------------
__global__ __launch_bounds__(64) void ln_kernel(const float* __restrict__ X,
        const float* __restrict__ G, const float* __restrict__ Bb,
        short* __restrict__ Y)
{
    int row = blockIdx.x;
    int t = threadIdx.x;
    const float* xr = X + (size_t)row * D_;
    float4 v0 = *(const float4*)(xr + t * 4);
    float4 v1 = *(const float4*)(xr + 256 + t * 4);
    float sum = v0.x + v0.y + v0.z + v0.w + v1.x + v1.y + v1.z + v1.w;
    float ssq = v0.x*v0.x + v0.y*v0.y + v0.z*v0.z + v0.w*v0.w
              + v1.x*v1.x + v1.y*v1.y + v1.z*v1.z + v1.w*v1.w;
    #pragma unroll
    for (int off = 32; off > 0; off >>= 1) {
        sum += __shfl_down(sum, off);
        ssq += __shfl_down(ssq, off);
    }
    sum = __shfl(sum, 0);
    ssq = __shfl(ssq, 0);
    float mean = sum * (1.0f / D_);
    float var  = ssq * (1.0f / D_) - mean * mean;
    float rstd = rsqrtf(var + EPS_);

    float4 g0 = *(const float4*)(G + t * 4);
    float4 g1 = *(const float4*)(G + 256 + t * 4);
    float4 b0 = *(const float4*)(Bb + t * 4);
    float4 b1 = *(const float4*)(Bb + 256 + t * 4);
    short4 o0, o1;
    o0.x = f2bf((v0.x - mean) * rstd * g0.x + b0.x);
    o0.y = f2bf((v0.y - mean) * rstd * g0.y + b0.y);
    o0.z = f2bf((v0.z - mean) * rstd * g0.z + b0.z);
    o0.w = f2bf((v0.w - mean) * rstd * g0.w + b0.w);
    o1.x = f2bf((v1.x - mean) * rstd * g1.x + b1.x);
    o1.y = f2bf((v1.y - mean) * rstd * g1.y + b1.y);
    o1.z = f2bf((v1.z - mean) * rstd * g1.z + b1.z);
    o1.w = f2bf((v1.w - mean) * rstd * g1.w + b1.w);
    short* yr = Y + (size_t)row * D_;
    *(short4*)(yr + t * 4)       = o0;
    *(short4*)(yr + 256 + t * 4) = o1;
}

// ---------------------------------------------------------------------------
// All weight transposes fused into one launch. 3072 tiles of 32x32.
// block (32,8).
// ---------------------------------------------------------------------------
__global__ __launch_bounds__(256) void prep_kernel(
        const float* __restrict__ Wq, const float* __restrict__ Wk,
        const float* __restrict__ Wv, const float* __restrict__ Wp,
        const float* __restrict__ W1, const float* __restrict__ W2,
        short* __restrict__ wqkv, short* __restrict__ wpt,
        short* __restrict__ w1t, short* __restrict__ w2t)
{
    __shared__ float tile[32][33];
    int idx = blockIdx.x;
    const float* src; short* dst; int R, C, tx0, ty0;
    if (idx < 768) {            // Wq/Wk/Wv: per head [512][64] -> [64][512]
        int w = idx >> 8, rem = idx & 255;
        int hh = rem >> 5, t = rem & 31;
        const float* base = (w == 0) ? Wq : ((w == 1) ? Wk : Wv);
        src = base + hh * (D_ * DH_);
        dst = wqkv + w * (512 * 512) + hh * (DH_ * D_);
        R = 512; C = 64; tx0 = (t & 1) * 32; ty0 = (t >> 1) * 32;
    } else if (idx < 1024) {    // Wproj [512][512]
        int t = idx - 768;
        src = Wp; dst = wpt; R = 512; C = 512;
        tx0 = (t & 15) * 32; ty0 = (t >> 4) * 32;
    } else if (idx < 2048) {    // W1 [512][2048] -> [2048][512]
        int t = idx - 1024;
        src = W1; dst = w1t; R = 512; C = 2048;
        tx0 = (t & 63) * 32; ty0 = (t >> 6) * 32;
    } else {                    // W2 [2048][512] -> [512][2048]
        int t = idx - 2048;
        src = W2; dst = w2t; R = 2048; C = 512;
        tx0 = (t & 15) * 32; ty0 = (t >> 4) * 32;
    }
    int tx = threadIdx.x, ty = threadIdx.y;
    #pragma unroll
    for (int i = 0; i < 32; i += 8)
        tile[ty + i][tx] = src[(size_t)(ty0 + ty + i) * C + tx0 + tx];
    __syncthreads();
    #pragma unroll
    for (int i = 0; i < 32; i += 8)
        dst[(size_t)(tx0 + ty + i) * R + ty0 + tx] = f2bf(tile[tx][ty + i]);
}

// ---------------------------------------------------------------------------
// bf16 MFMA GEMM: C[M,N] = A[M,K] @ Bt[N,K]^T.  128x128 tile, BK=64.
// grid = (M/128, N/128): blockIdx.x = M-row-block so all N-blocks sharing the
// same A rows land on the same XCD (linear%8 = x%8) -> A fetched once, L2-hot.
// ---------------------------------------------------------------------------
__global__ __launch_bounds__(256) void mm_kernel(const short* __restrict__ A,
        const short* __restrict__ Bt, void* __restrict__ C,
        const float* __restrict__ bias, const float* __restrict__ resid,
        int M, int N, int K, int relu, int out_bf16)
{
    __shared__ short As[128 * 64];
    __shared__ short Bs[128 * 64];
    const int tid = threadIdx.x;
    const int wave = tid >> 6, lane = tid & 63;
    const int quad = lane >> 4, l15 = lane & 15;
    const int m0 = blockIdx.x * 128, n0 = blockIdx.y * 128;
    const int mw = (wave & 1) * 64, nw = (wave >> 1) * 64;

    f32x4 acc[4][4];
    #pragma unroll
    for (int i = 0; i < 4; ++i)
        #pragma unroll
        for (int j = 0; j < 4; ++j)
            acc[i][j] = (f32x4){0.f, 0.f, 0.f, 0.f};

    for (int k0 = 0; k0 < K; k0 += 64) {
        __syncthreads();
        #pragma unroll
        for (int r = 0; r < 4; ++r) {
            int c = r * 256 + tid;
            int row = c >> 3, seg = (c & 7) ^ (row & 7);
            GLL16(A + (size_t)(m0 + row) * K + k0 + seg * 8,
                  As + (size_t)(r * 256 + wave * 64) * 8);
            GLL16(Bt + (size_t)(n0 + row) * K + k0 + seg * 8,
                  Bs + (size_t)(r * 256 + wave * 64) * 8);
        }
        __syncthreads();
        b16x8 af[4][2], bf[4][2];
        #pragma unroll
        for (int i = 0; i < 4; ++i)
            #pragma unroll
            for (int kb = 0; kb < 2; ++kb) {
                int row = mw + i * 16 + l15;
                af[i][kb] = *(const b16x8*)(As + row * 64 + (((kb * 4 + quad) ^ (row & 7)) * 8));
            }
        #pragma unroll
        for (int j = 0; j < 4; ++j)
            #pragma unroll
            for (int kb = 0; kb < 2; ++kb) {
                int row = nw + j * 16 + l15;
                bf[j][kb] = *(const b16x8*)(Bs + row * 64 + (((kb * 4 + quad) ^ (row & 7)) * 8));
            }
        #pragma unroll
        for (int kb = 0; kb < 2; ++kb)
            #pragma unroll
            for (int i = 0; i < 4; ++i)
                #pragma unroll
                for (int j = 0; j < 4; ++j)
                    acc[i][j] = MFMA16(af[i][kb], bf[j][kb], acc[i][j]);
    }

    #pragma unroll
    for (int i = 0; i < 4; ++i) {
        #pragma unroll
        for (int r = 0; r < 4; ++r) {
            size_t row = (size_t)(m0 + mw + i * 16 + quad * 4 + r);
            #pragma unroll
            for (int j = 0; j < 4; ++j) {
                int col = n0 + nw + j * 16 + l15;
                float v = acc[i][j][r];
                if (bias)  v += bias[col];
                if (resid) v += resid[row * N + col];
                if (relu)  v = fmaxf(v, 0.0f);
                if (out_bf16) ((short*)C)[row * N + col] = f2bf(v);
                else          ((float*)C)[row * N + col] = v;
            }
        }
    }
}

// ---------------------------------------------------------------------------
// bf16 MFMA GEMM, 128(M)x64(N) tile, BK=64 (FFN2). grid = (M/128, N/64).
// ---------------------------------------------------------------------------
__global__ __launch_bounds__(256) void mm64_kernel(const short* __restrict__ A,
        const short* __restrict__ Bt, void* __restrict__ C,
        const float* __restrict__ bias, const float* __restrict__ resid,
        int M, int N, int K, int relu, int out_bf16)
{
    __shared__ short As[128 * 64];
    __shared__ short Bs[64 * 64];
    const int tid = threadIdx.x;
    const int wave = tid >> 6, lane = tid & 63;
    const int quad = lane >> 4, l15 = lane & 15;
    const int m0 = blockIdx.x * 128, n0 = blockIdx.y * 64;
    const int mw = (wave & 1) * 64, nw = (wave >> 1) * 32;

    f32x4 acc[4][2];
    #pragma unroll
    for (int i = 0; i < 4; ++i)
        #pragma unroll
        for (int j = 0; j < 2; ++j)
            acc[i][j] = (f32x4){0.f, 0.f, 0.f, 0.f};

    for (int k0 = 0; k0 < K; k0 += 64) {
        __syncthreads();
        #pragma unroll
        for (int r = 0; r < 4; ++r) {
            int c = r * 256 + tid;
            int row = c >> 3, seg = (c & 7) ^ (row & 7);
            GLL16(A + (size_t)(m0 + row) * K + k0 + seg * 8,
                  As + (size_t)(r * 256 + wave * 64) * 8);
        }
        #pragma unroll
        for (int r = 0; r < 2; ++r) {
            int c = r * 256 + tid;
            int row = c >> 3, seg = (c & 7) ^ (row & 7);
            GLL16(Bt + (size_t)(n0 + row) * K + k0 + seg * 8,
                  Bs + (size_t)(r * 256 + wave * 64) * 8);
        }
        __syncthreads();
        b16x8 af[4][2], bf[2][2];
        #pragma unroll
        for (int i = 0; i < 4; ++i)
            #pragma unroll
            for (int kb = 0; kb < 2; ++kb) {
                int row = mw + i * 16 + l15;
                af[i][kb] = *(const b16x8*)(As + row * 64 + (((kb * 4 + quad) ^ (row & 7)) * 8));
            }
        #pragma unroll
        for (int j = 0; j < 2; ++j)
            #pragma unroll
            for (int kb = 0; kb < 2; ++kb) {
                int row = nw + j * 16 + l15;
                bf[j][kb] = *(const b16x8*)(Bs + row * 64 + (((kb * 4 + quad) ^ (row & 7)) * 8));
            }
        #pragma unroll
        for (int kb = 0; kb < 2; ++kb)
            #pragma unroll
            for (int i = 0; i < 4; ++i)
                #pragma unroll
                for (int j = 0; j < 2; ++j)
                    acc[i][j] = MFMA16(af[i][kb], bf[j][kb], acc[i][j]);
    }

    #pragma unroll
    for (int i = 0; i < 4; ++i) {
        #pragma unroll
        for (int r = 0; r < 4; ++r) {
            size_t row = (size_t)(m0 + mw + i * 16 + quad * 4 + r);
            #pragma unroll
            for (int j = 0; j < 2; ++j) {
                int col = n0 + nw + j * 16 + l15;
                float v = acc[i][j][r];
                if (bias)  v += bias[col];
                if (resid) v += resid[row * N + col];
                if (relu)  v = fmaxf(v, 0.0f);
                if (out_bf16) ((short*)C)[row * N + col] = f2bf(v);
                else          ((float*)C)[row * N + col] = v;
            }
        }
    }
}

// ---------------------------------------------------------------------------
// bf16 MFMA GEMM, 64x64 tile, BK=64 (proj: short-K, max TLP).
// grid = (M/64, N/64).
// ---------------------------------------------------------------------------
__global__ __launch_bounds__(256) void mm6464_kernel(const short* __restrict__ A,
        const short* __restrict__ Bt, void* __restrict__ C,
        const float* __restrict__ bias, const float* __restrict__ resid,
        int M, int N, int K, int relu, int out_bf16)
{
    __shared__ short As[64 * 64];
    __shared__ short Bs[64 * 64];
    const int tid = threadIdx.x;
    const int wave = tid >> 6, lane = tid & 63;
    const int quad = lane >> 4, l15 = lane & 15;
    const int m0 = blockIdx.x * 64, n0 = blockIdx.y * 64;
    const int nw = wave * 16;

    f32x4 acc[4];
    #pragma unroll
    for (int i = 0; i < 4; ++i) acc[i] = (f32x4){0.f, 0.f, 0.f, 0.f};

    for (int k0 = 0; k0 < K; k0 += 64) {
        __syncthreads();
        #pragma unroll
        for (int r = 0; r < 2; ++r) {
            int c = r * 256 + tid;
            int row = c >> 3, seg = (c & 7) ^ (row & 7);
            GLL16(A + (size_t)(m0 + row) * K + k0 + seg * 8,
                  As + (size_t)(r * 256 + wave * 64) * 8);
            GLL16(Bt + (size_t)(n0 + row) * K + k0 + seg * 8,
                  Bs + (size_t)(r * 256 + wave * 64) * 8);
        }
        __syncthreads();
        b16x8 af[4][2], bf[2];
        #pragma unroll
        for (int i = 0; i < 4; ++i)
            #pragma unroll
            for (int kb = 0; kb < 2; ++kb) {
                int row = i * 16 + l15;
                af[i][kb] = *(const b16x8*)(As + row * 64 + (((kb * 4 + quad) ^ (row & 7)) * 8));
            }
        #pragma unroll
        for (int kb = 0; kb < 2; ++kb) {
            int row = nw + l15;
            bf[kb] = *(const b16x8*)(Bs + row * 64 + (((kb * 4 + quad) ^ (row & 7)) * 8));
        }
        #pragma unroll
        for (int kb = 0; kb < 2; ++kb)
            #pragma unroll
            for (int i = 0; i < 4; ++i)
                acc[i] = MFMA16(af[i][kb], bf[kb], acc[i]);
    }

    #pragma unroll
    for (int i = 0; i < 4; ++i) {
        #pragma unroll
        for (int r = 0; r < 4; ++r) {
            size_t row = (size_t)(m0 + i * 16 + quad * 4 + r);
            int col = n0 + nw + l15;
            float v = acc[i][r];
            if (bias)  v += bias[col];
            if (resid) v += resid[row * N + col];
            if (relu)  v = fmaxf(v, 0.0f);
            if (out_bf16) ((short*)C)[row * N + col] = f2bf(v);
            else          ((float*)C)[row * N + col] = v;
        }
    }
}

// ---------------------------------------------------------------------------
// Flash attention, S^T formulation. qkv: [BT][1536] bf16 (q|k|v, each h*64+e).
// grid (32 bh, 32 qt); qi = 31 - blockIdx.y (LPT).
// S^T = K·Q^T via 16x16x32 (C-layout: token=quad*4+r, qrow=l15) -- which IS
// the B-operand layout of 16x16x16 MFMA, so P stays in registers and
// O^T += V^T·P^T needs no P LDS round-trip. Softmax state per-lane scalar.
// ---------------------------------------------------------------------------
__global__ __launch_bounds__(256) void attn_kernel(const short* __restrict__ qkv,
        short* __restrict__ Ob)
{
    __shared__ short Qs[64 * 64];   // [qrow][dh], swizzled 16B chunks
    __shared__ short Ks[64 * 64];   // [tok][dh], swizzled
    __shared__ short Vt[64 * 72];   // [dh][tok], stride 72
    __shared__ short Osh[64 * 72];  // [qrow][dh] repack, stride 72

    const int tid = threadIdx.x;
    const int wave = tid >> 6, lane = tid & 63;
    const int quad = lane >> 4, l15 = lane & 15;
    const int bh = blockIdx.x;
    const int qi = 31 - (int)blockIdx.y;
    const int b = bh >> 3, h = bh & 7;
    const size_t tok0 = (size_t)b * T_;
    const int qrow_rel = wave * 16 + l15;   // this lane's q-row within the tile

    // stage Q tile (swizzled)
    #pragma unroll
    for (int r = 0; r < 2; ++r) {
        int c = r * 256 + tid;
        int tk = c >> 3;
        int seg = (c & 7) ^ (tk & 7);
        GLL16(qkv + (tok0 + qi * 64 + tk) * 1536 + h * 64 + seg * 8,
              Qs + (size_t)(r * 256 + wave * 64) * 8);
    }

    float mrow = NEGINF_, lrow = 0.0f;
    f32x4 ot[4];   // O^T: row=dh=dt*16+quad*4+rr, col=qrow=l15
    #pragma unroll
    for (int dt = 0; dt < 4; ++dt) ot[dt] = (f32x4){0.f, 0.f, 0.f, 0.f};

    b16x8 qf[2];

    for (int kj = 0; kj <= qi; ++kj) {
        __syncthreads();   // prev-iter LDS reads done (and Q GLL drained on kj=0)
        // stage K tile (swizzled)
        #pragma unroll
        for (int r = 0; r < 2; ++r) {
            int c = r * 256 + tid;
            int tk = c >> 3;
            int seg = (c & 7) ^ (tk & 7);
            GLL16(qkv + (tok0 + kj * 64 + tk) * 1536 + 512 + h * 64 + seg * 8,
                  Ks + (size_t)(r * 256 + wave * 64) * 8);
        }
        // stage V transposed: thread = (seg s 0..7, token-pair tp 0..31)
        {
            int s = tid >> 5, tp = tid & 31;
            const short* g0 = qkv + (tok0 + kj * 64 + tp * 2) * 1536 + 1024 + h * 64 + s * 8;
            b16x8 v0 = *(const b16x8*)g0;
            b16x8 v1 = *(const b16x8*)(g0 + 1536);
            int* vo = (int*)Vt;
            #pragma unroll
            for (int e = 0; e < 8; ++e) {
                unsigned int pk = (unsigned int)(unsigned short)v0[e]
                                | ((unsigned int)(unsigned short)v1[e] << 16);
                vo[(s * 8 + e) * 36 + tp] = pk;
            }
        }
        __syncthreads();

        if (kj == 0) {   // Q fragment (B-operand: n=l15=qrow, k=quad*8+j), hoisted
            #pragma unroll
            for (int kb = 0; kb < 2; ++kb) {
                int row = wave * 16 + l15;
                qf[kb] = *(const b16x8*)(Qs + row * 64 + (((kb * 4 + quad) ^ (row & 7)) * 8));
            }
        }

        // S^T = K Q^T  (A=K-frag, B=Q-frag)
        f32x4 st[4];   // mt token-tiles: token = mt*16+quad*4+r, qrow = l15
        #pragma unroll
        for (int mt = 0; mt < 4; ++mt) st[mt] = (f32x4){0.f, 0.f, 0.f, 0.f};
        #pragma unroll
        for (int mt = 0; mt < 4; ++mt) {
            int trow = mt * 16 + l15;
            #pragma unroll
            for (int kb = 0; kb < 2; ++kb) {
                b16x8 kf = *(const b16x8*)(Ks + trow * 64 + (((kb * 4 + quad) ^ (trow & 7)) * 8));
                st[mt] = MFMA16(kf, qf[kb], st[mt]);
            }
        }

        // causal mask + token-max (in-lane 16 + cross-quad 2 shuffles)
        const bool diag = (kj == qi);
        float mx = NEGINF_;
        #pragma unroll
        for (int mt = 0; mt < 4; ++mt)
            #pragma unroll
            for (int r = 0; r < 4; ++r) {
                if (diag && (mt * 16 + quad * 4 + r) > qrow_rel) st[mt][r] = NEGINF_;
                mx = fmaxf(mx, st[mt][r]);
            }
        mx = fmaxf(mx, __shfl_xor(mx, 16));
        mx = fmaxf(mx, __shfl_xor(mx, 32));
        float mn = fmaxf(mrow, mx);
        float alpha = EXP2F((mrow - mn) * SC2_);
        float mnsc = mn * SC2_;
        mrow = mn;
        float rs = 0.0f;
        b16x4 pf[4];   // P^T fragments: directly in 16x16x16 B-operand layout
        #pragma unroll
        for (int mt = 0; mt < 4; ++mt)
            #pragma unroll
            for (int r = 0; r < 4; ++r) {
                float e = EXP2F(fmaf(st[mt][r], SC2_, -mnsc));
                rs += e;
                pf[mt][r] = f2bf_trunc(e);
            }
        rs += __shfl_xor(rs, 16);
        rs += __shfl_xor(rs, 32);
        lrow = lrow * alpha + rs;
        #pragma unroll
        for (int dt = 0; dt < 4; ++dt) {
            ot[dt][0] *= alpha; ot[dt][1] *= alpha;
            ot[dt][2] *= alpha; ot[dt][3] *= alpha;
        }
        // O^T += V^T P^T  (16x16x16; A=V^T-frag from Vt, B=P^T in registers)
        #pragma unroll
        for (int dt = 0; dt < 4; ++dt) {
            const short* vrow = Vt + (dt * 16 + l15) * 72;
            #pragma unroll
            for (int kt = 0; kt < 4; ++kt) {
                b16x4 vf = *(const b16x4*)(vrow + kt * 16 + quad * 4);
                ot[dt] = MFMA16K16(vf, pf[kt], ot[dt]);
            }
        }
    }

    // epilogue: normalize, repack via same-wave LDS strip, coalesced store
    float inv = 1.0f / lrow;
    #pragma unroll
    for (int dt = 0; dt < 4; ++dt) {
        b16x4 o4;
        o4[0] = f2bf(ot[dt][0] * inv);
        o4[1] = f2bf(ot[dt][1] * inv);
        o4[2] = f2bf(ot[dt][2] * inv);
        o4[3] = f2bf(ot[dt][3] * inv);
        *(b16x4*)(Osh + (size_t)qrow_rel * 72 + dt * 16 + quad * 4) = o4;
    }
    // rows tid>>2 land inside this wave's own strip -> DS in-order, no barrier
    {
        int row = tid >> 2, ch = tid & 3;
        b16x8 lo = *(const b16x8*)(Osh + (size_t)row * 72 + ch * 16);
        b16x8 hi = *(const b16x8*)(Osh + (size_t)row * 72 + ch * 16 + 8);
        short* dst = Ob + (tok0 + (size_t)qi * 64 + row) * 512 + h * 64 + ch * 16;
        *(b16x8*)dst = lo;
        *(b16x8*)(dst + 8) = hi;
    }
}

// ---------------------------------------------------------------------------
extern "C" void kernel_launch(void* const* d_in, const int* in_sizes, int n_in,
                              void* d_out, int out_size, void* d_ws, size_t ws_size,
                              hipStream_t stream) {
    (void)in_sizes; (void)n_in; (void)out_size; (void)ws_size;
    const float* x     = (const float*)d_in[0];
    const float* ln_g  = (const float*)d_in[1];
    const float* ln_b  = (const float*)d_in[2];
    const float* Wq    = (const float*)d_in[3];
    const float* Wk    = (const float*)d_in[4];
    const float* Wv    = (const float*)d_in[5];
    const float* Wproj = (const float*)d_in[6];
    const float* bproj = (const float*)d_in[7];
    const float* W1    = (const float*)d_in[8];
    const float* b1    = (const float*)d_in[9];
    const float* W2    = (const float*)d_in[10];
    const float* b2    = (const float*)d_in[11];
    float* out = (float*)d_out;

    char* W = (char*)d_ws;
    short* hbuf  = (short*)(W + 0);                    // 8 MB  (LN out, bf16)
    short* qkvb  = (short*)(W + ((size_t)8  << 20));   // 24 MB [BT][1536]
    short* attno = (short*)(W + ((size_t)32 << 20));   // 8 MB  [BT][512]
    float* x1    = (float*)(W + ((size_t)40 << 20));   // 16 MB
    short* ff1   = (short*)(W + ((size_t)56 << 20));   // 32 MB [BT][2048]
    short* wqkv  = (short*)(W + ((size_t)88 << 20));   // 1.5 MB [1536][512]
    short* wpt   = (short*)(W + ((size_t)90 << 20));   // 0.5 MB [512][512]
    short* w1t   = (short*)(W + ((size_t)91 << 20));   // 2 MB  [2048][512]
    short* w2t   = (short*)(W + ((size_t)93 << 20));   // 2 MB  [512][2048]

    // 0. all weight transposes in one launch
    prep_kernel<<<dim3(3072), dim3(32, 8), 0, stream>>>(
        Wq, Wk, Wv, Wproj, W1, W2, wqkv, wpt, w1t, w2t);
    // 1. h = LN(x) -> bf16
    ln_kernel<<<dim3(BT_), dim3(64), 0, stream>>>(x, ln_g, ln_b, hbuf);
    // 2. qkv = h @ Wqkv  [8192,1536] bf16  (grid: M-blocks on x for XCD A-reuse)
    mm_kernel<<<dim3(64, 12), dim3(256), 0, stream>>>(hbuf, wqkv, qkvb,
        nullptr, nullptr, BT_, 1536, D_, 0, 1);
    // 3. attention -> attno bf16
    attn_kernel<<<dim3(32, 32), dim3(256), 0, stream>>>(qkvb, attno);
    // 4. x1 = x + attno @ Wproj + bproj  (fp32)
    mm6464_kernel<<<dim3(128, 8), dim3(256), 0, stream>>>(attno, wpt, x1,
        bproj, x, BT_, D_, D_, 0, 0);
    // 5. h2 = LN(x1) -> bf16 (reuse hbuf)
    ln_kernel<<<dim3(BT_), dim3(64), 0, stream>>>(x1, ln_g, ln_b, hbuf);
    // 6. ff1 = relu(h2 @ W1 + b1)  bf16
    mm_kernel<<<dim3(64, 16), dim3(256), 0, stream>>>(hbuf, w1t, ff1,
        b1, nullptr, BT_, FF_, D_, 1, 1);
    // 7. out = x1 + ff1 @ W2 + b2  (fp32)
    mm64_kernel<<<dim3(64, 8), dim3(256), 0, stream>>>(ff1, w2t, out,
        b2, x1, BT_, D_, FF_, 0, 0);
}

// Round 8
// 294.533 us; speedup vs baseline: 4.4856x; 1.0142x over previous
//
#include <hip/hip_runtime.h>
#include <math.h>

#define B_ 4
#define T_ 2048
#define D_ 512
#define H_ 8
#define DH_ 64
#define BT_ 8192
#define FF_ 2048
#define EPS_ 1e-5f
#define SCALE_ 0.04419417382415922f   // 512^-0.5
#define SC2_ 0.06375861151f           // SCALE_ * log2(e)
#define NEGINF_ -1e30f

typedef short b16x8 __attribute__((ext_vector_type(8)));
typedef short b16x4 __attribute__((ext_vector_type(4)));
typedef float f32x4 __attribute__((ext_vector_type(4)));

#define MFMA16(a, b, c) __builtin_amdgcn_mfma_f32_16x16x32_bf16(a, b, c, 0, 0, 0)
#define MFMA16K16(a, b, c) __builtin_amdgcn_mfma_f32_16x16x16bf16_1k(a, b, c, 0, 0, 0)

#define GLL16(gp, lp) \
    __builtin_amdgcn_global_load_lds((const __attribute__((address_space(1))) void*)(gp), \
                                     (__attribute__((address_space(3))) void*)(lp), 16, 0, 0)

#if __has_builtin(__builtin_amdgcn_exp2f)
#define EXP2F(x) __builtin_amdgcn_exp2f(x)
#else
#define EXP2F(x) exp2f(x)
#endif

// fp32 -> bf16 RNE (finite inputs)
static __device__ inline short f2bf(float f) {
    unsigned int u = __builtin_bit_cast(unsigned int, f);
    unsigned int r = (u + 0x7fffu + ((u >> 16) & 1u)) >> 16;
    return (short)r;
}
// fp32 -> bf16 truncation (1 VALU op; used for P where bias is negligible)
static __device__ inline short f2bf_trunc(float f) {
    return (short)(__builtin_bit_cast(unsigned int, f) >> 16);
}

// ---------------------------------------------------------------------------
// LayerNorm: one wave per row of 512, fp32 in -> bf16 out
// ---------------------------------------------------------------------------
__global__ __launch_bounds__(64) void ln_kernel(const float* __restrict__ X,
        const float* __restrict__ G, const float* __restrict__ Bb,
        short* __restrict__ Y)
{
    int row = blockIdx.x;
    int t = threadIdx.x;
    const float* xr = X + (size_t)row * D_;
    float4 v0 = *(const float4*)(xr + t * 4);
    float4 v1 = *(const float4*)(xr + 256 + t * 4);
    float sum = v0.x + v0.y + v0.z + v0.w + v1.x + v1.y + v1.z + v1.w;
    float ssq = v0.x*v0.x + v0.y*v0.y + v0.z*v0.z + v0.w*v0.w
              + v1.x*v1.x + v1.y*v1.y + v1.z*v1.z + v1.w*v1.w;
    #pragma unroll
    for (int off = 32; off > 0; off >>= 1) {
        sum += __shfl_down(sum, off);
        ssq += __shfl_down(ssq, off);
    }
    sum = __shfl(sum, 0);
    ssq = __shfl(ssq, 0);
    float mean = sum * (1.0f / D_);
    float var  = ssq * (1.0f / D_) - mean * mean;
    float rstd = rsqrtf(var + EPS_);

    float4 g0 = *(const float4*)(G + t * 4);
    float4 g1 = *(const float4*)(G + 256 + t * 4);
    float4 b0 = *(const float4*)(Bb + t * 4);
    float4 b1 = *(const float4*)(Bb + 256 + t * 4);
    short4 o0, o1;
    o0.x = f2bf((v0.x - mean) * rstd * g0.x + b0.x);
    o0.y = f2bf((v0.y - mean) * rstd * g0.y + b0.y);
    o0.z = f2bf((v0.z - mean) * rstd * g0.z + b0.z);
    o0.w = f2bf((v0.w - mean) * rstd * g0.w + b0.w);
    o1.x = f2bf((v1.x - mean) * rstd * g1.x + b1.x);
    o1.y = f2bf((v1.y - mean) * rstd * g1.y + b1.y);
    o1.z = f2bf((v1.z - mean) * rstd * g1.z + b1.z);
    o1.w = f2bf((v1.w - mean) * rstd * g1.w + b1.w);
    short* yr = Y + (size_t)row * D_;
    *(short4*)(yr + t * 4)       = o0;
    *(short4*)(yr + 256 + t * 4) = o1;
}

// ---------------------------------------------------------------------------
// All weight transposes fused into one launch. 3072 tiles of 32x32.
// block (32,8).
// ---------------------------------------------------------------------------
__global__ __launch_bounds__(256) void prep_kernel(
        const float* __restrict__ Wq, const float* __restrict__ Wk,
        const float* __restrict__ Wv, const float* __restrict__ Wp,
        const float* __restrict__ W1, const float* __restrict__ W2,
        short* __restrict__ wqkv, short* __restrict__ wpt,
        short* __restrict__ w1t, short* __restrict__ w2t)
{
    __shared__ float tile[32][33];
    int idx = blockIdx.x;
    const float* src; short* dst; int R, C, tx0, ty0;
    if (idx < 768) {            // Wq/Wk/Wv: per head [512][64] -> [64][512]
        int w = idx >> 8, rem = idx & 255;
        int hh = rem >> 5, t = rem & 31;
        const float* base = (w == 0) ? Wq : ((w == 1) ? Wk : Wv);
        src = base + hh * (D_ * DH_);
        dst = wqkv + w * (512 * 512) + hh * (DH_ * D_);
        R = 512; C = 64; tx0 = (t & 1) * 32; ty0 = (t >> 1) * 32;
    } else if (idx < 1024) {    // Wproj [512][512]
        int t = idx - 768;
        src = Wp; dst = wpt; R = 512; C = 512;
        tx0 = (t & 15) * 32; ty0 = (t >> 4) * 32;
    } else if (idx < 2048) {    // W1 [512][2048] -> [2048][512]
        int t = idx - 1024;
        src = W1; dst = w1t; R = 512; C = 2048;
        tx0 = (t & 63) * 32; ty0 = (t >> 6) * 32;
    } else {                    // W2 [2048][512] -> [512][2048]
        int t = idx - 2048;
        src = W2; dst = w2t; R = 2048; C = 512;
        tx0 = (t & 15) * 32; ty0 = (t >> 4) * 32;
    }
    int tx = threadIdx.x, ty = threadIdx.y;
    #pragma unroll
    for (int i = 0; i < 32; i += 8)
        tile[ty + i][tx] = src[(size_t)(ty0 + ty + i) * C + tx0 + tx];
    __syncthreads();
    #pragma unroll
    for (int i = 0; i < 32; i += 8)
        dst[(size_t)(tx0 + ty + i) * R + ty0 + tx] = f2bf(tile[tx][ty + i]);
}

// ---------------------------------------------------------------------------
// bf16 MFMA GEMM: C[M,N] = A[M,K] @ Bt[N,K]^T.  128x128 tile, BK=32 with
// single-barrier double-buffered global_load_lds pipeline:
//   barrier(drain prev prefetch) -> issue prefetch(next) -> compute(cur).
// The prefetch has a full compute phase in flight before any wave drains it.
// grid = (M/128, N/128): M-blocks on x -> XCD-pinned A rows (L2-hot).
// ---------------------------------------------------------------------------
__global__ __launch_bounds__(256) void mm_kernel(const short* __restrict__ A,
        const short* __restrict__ Bt, void* __restrict__ C,
        const float* __restrict__ bias, const float* __restrict__ resid,
        int M, int N, int K, int relu, int out_bf16)
{
    __shared__ short As[2][128 * 32];
    __shared__ short Bs[2][128 * 32];
    const int tid = threadIdx.x;
    const int wave = tid >> 6, lane = tid & 63;
    const int quad = lane >> 4, l15 = lane & 15;
    const int m0 = blockIdx.x * 128, n0 = blockIdx.y * 128;
    const int mw = (wave & 1) * 64, nw = (wave >> 1) * 64;

#define STAGE_MM(bufi, kk) \
    { \
        for (int r = 0; r < 2; ++r) { \
            int c = r * 256 + tid; \
            int row = c >> 2, seg = (c & 3) ^ (row & 3); \
            GLL16(A + (size_t)(m0 + row) * K + (kk) + seg * 8, \
                  As[bufi] + (size_t)(r * 256 + wave * 64) * 8); \
            GLL16(Bt + (size_t)(n0 + row) * K + (kk) + seg * 8, \
                  Bs[bufi] + (size_t)(r * 256 + wave * 64) * 8); \
        } \
    }

    f32x4 acc[4][4];
    #pragma unroll
    for (int i = 0; i < 4; ++i)
        #pragma unroll
        for (int j = 0; j < 4; ++j)
            acc[i][j] = (f32x4){0.f, 0.f, 0.f, 0.f};

    STAGE_MM(0, 0);
    int buf = 0;
    for (int k0 = 0; k0 < K; k0 += 32) {
        __syncthreads();                      // drains prefetch issued last iter
        if (k0 + 32 < K) STAGE_MM(buf ^ 1, k0 + 32);
        b16x8 af[4], bf[4];
        #pragma unroll
        for (int i = 0; i < 4; ++i) {
            int row = mw + i * 16 + l15;
            af[i] = *(const b16x8*)(As[buf] + row * 32 + ((quad ^ (row & 3)) * 8));
        }
        #pragma unroll
        for (int j = 0; j < 4; ++j) {
            int row = nw + j * 16 + l15;
            bf[j] = *(const b16x8*)(Bs[buf] + row * 32 + ((quad ^ (row & 3)) * 8));
        }
        #pragma unroll
        for (int i = 0; i < 4; ++i)
            #pragma unroll
            for (int j = 0; j < 4; ++j)
                acc[i][j] = MFMA16(af[i], bf[j], acc[i][j]);
        buf ^= 1;
    }
#undef STAGE_MM

    #pragma unroll
    for (int i = 0; i < 4; ++i) {
        #pragma unroll
        for (int r = 0; r < 4; ++r) {
            size_t row = (size_t)(m0 + mw + i * 16 + quad * 4 + r);
            #pragma unroll
            for (int j = 0; j < 4; ++j) {
                int col = n0 + nw + j * 16 + l15;
                float v = acc[i][j][r];
                if (bias)  v += bias[col];
                if (resid) v += resid[row * N + col];
                if (relu)  v = fmaxf(v, 0.0f);
                if (out_bf16) ((short*)C)[row * N + col] = f2bf(v);
                else          ((float*)C)[row * N + col] = v;
            }
        }
    }
}

// ---------------------------------------------------------------------------
// bf16 MFMA GEMM, 128(M)x64(N), BK=32 dbuf pipeline (FFN2). grid=(M/128,N/64).
// ---------------------------------------------------------------------------
__global__ __launch_bounds__(256) void mm64_kernel(const short* __restrict__ A,
        const short* __restrict__ Bt, void* __restrict__ C,
        const float* __restrict__ bias, const float* __restrict__ resid,
        int M, int N, int K, int relu, int out_bf16)
{
    __shared__ short As[2][128 * 32];
    __shared__ short Bs[2][64 * 32];
    const int tid = threadIdx.x;
    const int wave = tid >> 6, lane = tid & 63;
    const int quad = lane >> 4, l15 = lane & 15;
    const int m0 = blockIdx.x * 128, n0 = blockIdx.y * 64;
    const int mw = (wave & 1) * 64, nw = (wave >> 1) * 32;

#define STAGE_M64(bufi, kk) \
    { \
        for (int r = 0; r < 2; ++r) { \
            int c = r * 256 + tid; \
            int row = c >> 2, seg = (c & 3) ^ (row & 3); \
            GLL16(A + (size_t)(m0 + row) * K + (kk) + seg * 8, \
                  As[bufi] + (size_t)(r * 256 + wave * 64) * 8); \
        } \
        { \
            int row = tid >> 2, seg = (tid & 3) ^ (row & 3); \
            GLL16(Bt + (size_t)(n0 + row) * K + (kk) + seg * 8, \
                  Bs[bufi] + (size_t)(wave * 64) * 8); \
        } \
    }

    f32x4 acc[4][2];
    #pragma unroll
    for (int i = 0; i < 4; ++i)
        #pragma unroll
        for (int j = 0; j < 2; ++j)
            acc[i][j] = (f32x4){0.f, 0.f, 0.f, 0.f};

    STAGE_M64(0, 0);
    int buf = 0;
    for (int k0 = 0; k0 < K; k0 += 32) {
        __syncthreads();
        if (k0 + 32 < K) STAGE_M64(buf ^ 1, k0 + 32);
        b16x8 af[4], bf[2];
        #pragma unroll
        for (int i = 0; i < 4; ++i) {
            int row = mw + i * 16 + l15;
            af[i] = *(const b16x8*)(As[buf] + row * 32 + ((quad ^ (row & 3)) * 8));
        }
        #pragma unroll
        for (int j = 0; j < 2; ++j) {
            int row = nw + j * 16 + l15;
            bf[j] = *(const b16x8*)(Bs[buf] + row * 32 + ((quad ^ (row & 3)) * 8));
        }
        #pragma unroll
        for (int i = 0; i < 4; ++i)
            #pragma unroll
            for (int j = 0; j < 2; ++j)
                acc[i][j] = MFMA16(af[i], bf[j], acc[i][j]);
        buf ^= 1;
    }
#undef STAGE_M64

    #pragma unroll
    for (int i = 0; i < 4; ++i) {
        #pragma unroll
        for (int r = 0; r < 4; ++r) {
            size_t row = (size_t)(m0 + mw + i * 16 + quad * 4 + r);
            #pragma unroll
            for (int j = 0; j < 2; ++j) {
                int col = n0 + nw + j * 16 + l15;
                float v = acc[i][j][r];
                if (bias)  v += bias[col];
                if (resid) v += resid[row * N + col];
                if (relu)  v = fmaxf(v, 0.0f);
                if (out_bf16) ((short*)C)[row * N + col] = f2bf(v);
                else          ((float*)C)[row * N + col] = v;
            }
        }
    }
}

// ---------------------------------------------------------------------------
// bf16 MFMA GEMM, 64x64, BK=32 dbuf pipeline (proj). grid = (M/64, N/64).
// ---------------------------------------------------------------------------
__global__ __launch_bounds__(256) void mm6464_kernel(const short* __restrict__ A,
        const short* __restrict__ Bt, void* __restrict__ C,
        const float* __restrict__ bias, const float* __restrict__ resid,
        int M, int N, int K, int relu, int out_bf16)
{
    __shared__ short As[2][64 * 32];
    __shared__ short Bs[2][64 * 32];
    const int tid = threadIdx.x;
    const int wave = tid >> 6, lane = tid & 63;
    const int quad = lane >> 4, l15 = lane & 15;
    const int m0 = blockIdx.x * 64, n0 = blockIdx.y * 64;
    const int nw = wave * 16;

#define STAGE_M66(bufi, kk) \
    { \
        int row = tid >> 2, seg = (tid & 3) ^ (row & 3); \
        GLL16(A + (size_t)(m0 + row) * K + (kk) + seg * 8, \
              As[bufi] + (size_t)(wave * 64) * 8); \
        GLL16(Bt + (size_t)(n0 + row) * K + (kk) + seg * 8, \
              Bs[bufi] + (size_t)(wave * 64) * 8); \
    }

    f32x4 acc[4];
    #pragma unroll
    for (int i = 0; i < 4; ++i) acc[i] = (f32x4){0.f, 0.f, 0.f, 0.f};

    STAGE_M66(0, 0);
    int buf = 0;
    for (int k0 = 0; k0 < K; k0 += 32) {
        __syncthreads();
        if (k0 + 32 < K) STAGE_M66(buf ^ 1, k0 + 32);
        b16x8 af[4], bf;
        #pragma unroll
        for (int i = 0; i < 4; ++i) {
            int row = i * 16 + l15;
            af[i] = *(const b16x8*)(As[buf] + row * 32 + ((quad ^ (row & 3)) * 8));
        }
        {
            int row = nw + l15;
            bf = *(const b16x8*)(Bs[buf] + row * 32 + ((quad ^ (row & 3)) * 8));
        }
        #pragma unroll
        for (int i = 0; i < 4; ++i)
            acc[i] = MFMA16(af[i], bf, acc[i]);
        buf ^= 1;
    }
#undef STAGE_M66

    #pragma unroll
    for (int i = 0; i < 4; ++i) {
        #pragma unroll
        for (int r = 0; r < 4; ++r) {
            size_t row = (size_t)(m0 + i * 16 + quad * 4 + r);
            int col = n0 + nw + l15;
            float v = acc[i][r];
            if (bias)  v += bias[col];
            if (resid) v += resid[row * N + col];
            if (relu)  v = fmaxf(v, 0.0f);
            if (out_bf16) ((short*)C)[row * N + col] = f2bf(v);
            else          ((float*)C)[row * N + col] = v;
        }
    }
}

// ---------------------------------------------------------------------------
// Flash attention, S^T formulation. qkv: [BT][1536] bf16 (q|k|v, each h*64+e).
// grid (32 bh, 32 qt); qi = 31 - blockIdx.y (LPT).
// Vt now stride 64 with per-row granule XOR swizzle (slot = g ^ (row&15)):
// both packed writes and b16x4 fragment reads spread evenly over all 32 banks
// (2-way = free), killing the stride-72 even-bank hotspots.
// ---------------------------------------------------------------------------
__global__ __launch_bounds__(256) void attn_kernel(const short* __restrict__ qkv,
        short* __restrict__ Ob)
{
    __shared__ short Qs[64 * 64];   // [qrow][dh], swizzled 16B chunks
    __shared__ short Ks[64 * 64];   // [tok][dh], swizzled
    __shared__ short Vt[64 * 64];   // [dh][tok], granule-swizzled, stride 64
    __shared__ short Osh[64 * 72];  // [qrow][dh] repack, stride 72

    const int tid = threadIdx.x;
    const int wave = tid >> 6, lane = tid & 63;
    const int quad = lane >> 4, l15 = lane & 15;
    const int bh = blockIdx.x;
    const int qi = 31 - (int)blockIdx.y;
    const int b = bh >> 3, h = bh & 7;
    const size_t tok0 = (size_t)b * T_;
    const int qrow_rel = wave * 16 + l15;   // this lane's q-row within the tile

    // stage Q tile (swizzled)
    #pragma unroll
    for (int r = 0; r < 2; ++r) {
        int c = r * 256 + tid;
        int tk = c >> 3;
        int seg = (c & 7) ^ (tk & 7);
        GLL16(qkv + (tok0 + qi * 64 + tk) * 1536 + h * 64 + seg * 8,
              Qs + (size_t)(r * 256 + wave * 64) * 8);
    }

    float mrow = NEGINF_, lrow = 0.0f;
    f32x4 ot[4];   // O^T: row=dh=dt*16+quad*4+rr, col=qrow=l15
    #pragma unroll
    for (int dt = 0; dt < 4; ++dt) ot[dt] = (f32x4){0.f, 0.f, 0.f, 0.f};

    b16x8 qf[2];

    for (int kj = 0; kj <= qi; ++kj) {
        __syncthreads();   // prev-iter LDS reads done (and Q GLL drained on kj=0)
        // stage K tile (swizzled)
        #pragma unroll
        for (int r = 0; r < 2; ++r) {
            int c = r * 256 + tid;
            int tk = c >> 3;
            int seg = (c & 7) ^ (tk & 7);
            GLL16(qkv + (tok0 + kj * 64 + tk) * 1536 + 512 + h * 64 + seg * 8,
                  Ks + (size_t)(r * 256 + wave * 64) * 8);
        }
        // stage V transposed, granule-swizzled: thread = (s 0..7, tp 0..31)
        {
            int s = tid >> 5, tp = tid & 31;
            const short* g0 = qkv + (tok0 + kj * 64 + tp * 2) * 1536 + 1024 + h * 64 + s * 8;
            b16x8 v0 = *(const b16x8*)g0;
            b16x8 v1 = *(const b16x8*)(g0 + 1536);
            int* vo = (int*)Vt;
            int gg = tp >> 1, half = tp & 1;
            #pragma unroll
            for (int e = 0; e < 8; ++e) {
                int row = s * 8 + e;
                unsigned int pk = (unsigned int)(unsigned short)v0[e]
                                | ((unsigned int)(unsigned short)v1[e] << 16);
                vo[row * 32 + ((gg ^ (row & 15)) << 1) + half] = pk;
            }
        }
        __syncthreads();

        if (kj == 0) {   // Q fragment (B-operand: n=l15=qrow, k=quad*8+j), hoisted
            #pragma unroll
            for (int kb = 0; kb < 2; ++kb) {
                int row = wave * 16 + l15;
                qf[kb] = *(const b16x8*)(Qs + row * 64 + (((kb * 4 + quad) ^ (row & 7)) * 8));
            }
        }

        // S^T = K Q^T  (A=K-frag, B=Q-frag)
        f32x4 st[4];   // mt token-tiles: token = mt*16+quad*4+r, qrow = l15
        #pragma unroll
        for (int mt = 0; mt < 4; ++mt) st[mt] = (f32x4){0.f, 0.f, 0.f, 0.f};
        #pragma unroll
        for (int mt = 0; mt < 4; ++mt) {
            int trow = mt * 16 + l15;
            #pragma unroll
            for (int kb = 0; kb < 2; ++kb) {
                b16x8 kf = *(const b16x8*)(Ks + trow * 64 + (((kb * 4 + quad) ^ (trow & 7)) * 8));
                st[mt] = MFMA16(kf, qf[kb], st[mt]);
            }
        }

        // causal mask + token-max (in-lane 16 + cross-quad 2 shuffles)
        const bool diag = (kj == qi);
        float mx = NEGINF_;
        #pragma unroll
        for (int mt = 0; mt < 4; ++mt)
            #pragma unroll
            for (int r = 0; r < 4; ++r) {
                if (diag && (mt * 16 + quad * 4 + r) > qrow_rel) st[mt][r] = NEGINF_;
                mx = fmaxf(mx, st[mt][r]);
            }
        mx = fmaxf(mx, __shfl_xor(mx, 16));
        mx = fmaxf(mx, __shfl_xor(mx, 32));
        float mn = fmaxf(mrow, mx);
        float alpha = EXP2F((mrow - mn) * SC2_);
        float mnsc = mn * SC2_;
        mrow = mn;
        float rs = 0.0f;
        b16x4 pf[4];   // P^T fragments: directly in 16x16x16 B-operand layout
        #pragma unroll
        for (int mt = 0; mt < 4; ++mt)
            #pragma unroll
            for (int r = 0; r < 4; ++r) {
                float e = EXP2F(fmaf(st[mt][r], SC2_, -mnsc));
                rs += e;
                pf[mt][r] = f2bf_trunc(e);
            }
        rs += __shfl_xor(rs, 16);
        rs += __shfl_xor(rs, 32);
        lrow = lrow * alpha + rs;
        #pragma unroll
        for (int dt = 0; dt < 4; ++dt) {
            ot[dt][0] *= alpha; ot[dt][1] *= alpha;
            ot[dt][2] *= alpha; ot[dt][3] *= alpha;
        }
        // O^T += V^T P^T  (16x16x16; A=V^T-frag from swizzled Vt, B=P^T in regs)
        #pragma unroll
        for (int dt = 0; dt < 4; ++dt) {
            const short* vrow = Vt + (dt * 16 + l15) * 64;
            #pragma unroll
            for (int kt = 0; kt < 4; ++kt) {
                b16x4 vf = *(const b16x4*)(vrow + (((kt * 4 + quad) ^ l15) << 2));
                ot[dt] = MFMA16K16(vf, pf[kt], ot[dt]);
            }
        }
    }

    // epilogue: normalize, repack via same-wave LDS strip, coalesced store
    float inv = 1.0f / lrow;
    #pragma unroll
    for (int dt = 0; dt < 4; ++dt) {
        b16x4 o4;
        o4[0] = f2bf(ot[dt][0] * inv);
        o4[1] = f2bf(ot[dt][1] * inv);
        o4[2] = f2bf(ot[dt][2] * inv);
        o4[3] = f2bf(ot[dt][3] * inv);
        *(b16x4*)(Osh + (size_t)qrow_rel * 72 + dt * 16 + quad * 4) = o4;
    }
    // rows tid>>2 land inside this wave's own strip -> DS in-order, no barrier
    {
        int row = tid >> 2, ch = tid & 3;
        b16x8 lo = *(const b16x8*)(Osh + (size_t)row * 72 + ch * 16);
        b16x8 hi = *(const b16x8*)(Osh + (size_t)row * 72 + ch * 16 + 8);
        short* dst = Ob + (tok0 + (size_t)qi * 64 + row) * 512 + h * 64 + ch * 16;
        *(b16x8*)dst = lo;
        *(b16x8*)(dst + 8) = hi;
    }
}

// ---------------------------------------------------------------------------
extern "C" void kernel_launch(void* const* d_in, const int* in_sizes, int n_in,
                              void* d_out, int out_size, void* d_ws, size_t ws_size,
                              hipStream_t stream) {
    (void)in_sizes; (void)n_in; (void)out_size; (void)ws_size;
    const float* x     = (const float*)d_in[0];
    const float* ln_g  = (const float*)d_in[1];
    const float* ln_b  = (const float*)d_in[2];
    const float* Wq    = (const float*)d_in[3];
    const float* Wk    = (const float*)d_in[4];
    const float* Wv    = (const float*)d_in[5];
    const float* Wproj = (const float*)d_in[6];
    const float* bproj = (const float*)d_in[7];
    const float* W1    = (const float*)d_in[8];
    const float* b1    = (const float*)d_in[9];
    const float* W2    = (const float*)d_in[10];
    const float* b2    = (const float*)d_in[11];
    float* out = (float*)d_out;

    char* W = (char*)d_ws;
    short* hbuf  = (short*)(W + 0);                    // 8 MB  (LN out, bf16)
    short* qkvb  = (short*)(W + ((size_t)8  << 20));   // 24 MB [BT][1536]
    short* attno = (short*)(W + ((size_t)32 << 20));   // 8 MB  [BT][512]
    float* x1    = (float*)(W + ((size_t)40 << 20));   // 16 MB
    short* ff1   = (short*)(W + ((size_t)56 << 20));   // 32 MB [BT][2048]
    short* wqkv  = (short*)(W + ((size_t)88 << 20));   // 1.5 MB [1536][512]
    short* wpt   = (short*)(W + ((size_t)90 << 20));   // 0.5 MB [512][512]
    short* w1t   = (short*)(W + ((size_t)91 << 20));   // 2 MB  [2048][512]
    short* w2t   = (short*)(W + ((size_t)93 << 20));   // 2 MB  [512][2048]

    // 0. all weight transposes in one launch
    prep_kernel<<<dim3(3072), dim3(32, 8), 0, stream>>>(
        Wq, Wk, Wv, Wproj, W1, W2, wqkv, wpt, w1t, w2t);
    // 1. h = LN(x) -> bf16
    ln_kernel<<<dim3(BT_), dim3(64), 0, stream>>>(x, ln_g, ln_b, hbuf);
    // 2. qkv = h @ Wqkv  [8192,1536] bf16  (grid: M-blocks on x for XCD A-reuse)
    mm_kernel<<<dim3(64, 12), dim3(256), 0, stream>>>(hbuf, wqkv, qkvb,
        nullptr, nullptr, BT_, 1536, D_, 0, 1);
    // 3. attention -> attno bf16
    attn_kernel<<<dim3(32, 32), dim3(256), 0, stream>>>(qkvb, attno);
    // 4. x1 = x + attno @ Wproj + bproj  (fp32)
    mm6464_kernel<<<dim3(128, 8), dim3(256), 0, stream>>>(attno, wpt, x1,
        bproj, x, BT_, D_, D_, 0, 0);
    // 5. h2 = LN(x1) -> bf16 (reuse hbuf)
    ln_kernel<<<dim3(BT_), dim3(64), 0, stream>>>(x1, ln_g, ln_b, hbuf);
    // 6. ff1 = relu(h2 @ W1 + b1)  bf16
    mm_kernel<<<dim3(64, 16), dim3(256), 0, stream>>>(hbuf, w1t, ff1,
        b1, nullptr, BT_, FF_, D_, 1, 1);
    // 7. out = x1 + ff1 @ W2 + b2  (fp32)
    mm64_kernel<<<dim3(64, 8), dim3(256), 0, stream>>>(ff1, w2t, out,
        b2, x1, BT_, D_, FF_, 0, 0);
}

// Round 9
// 289.626 us; speedup vs baseline: 4.5616x; 1.0169x over previous
//
#include <hip/hip_runtime.h>
#include <math.h>

#define B_ 4
#define T_ 2048
#define D_ 512
#define H_ 8
#define DH_ 64
#define BT_ 8192
#define FF_ 2048
#define EPS_ 1e-5f
#define SCALE_ 0.04419417382415922f   // 512^-0.5
#define SC2_ 0.06375861151f           // SCALE_ * log2(e)
#define NEGINF_ -1e30f

typedef short b16x8 __attribute__((ext_vector_type(8)));
typedef short b16x4 __attribute__((ext_vector_type(4)));
typedef float f32x4 __attribute__((ext_vector_type(4)));

#define MFMA16(a, b, c) __builtin_amdgcn_mfma_f32_16x16x32_bf16(a, b, c, 0, 0, 0)
#define MFMA16K16(a, b, c) __builtin_amdgcn_mfma_f32_16x16x16bf16_1k(a, b, c, 0, 0, 0)

#define GLL16(gp, lp) \
    __builtin_amdgcn_global_load_lds((const __attribute__((address_space(1))) void*)(gp), \
                                     (__attribute__((address_space(3))) void*)(lp), 16, 0, 0)

#if __has_builtin(__builtin_amdgcn_exp2f)
#define EXP2F(x) __builtin_amdgcn_exp2f(x)
#else
#define EXP2F(x) exp2f(x)
#endif

// fp32 -> bf16 RNE (finite inputs)
static __device__ inline short f2bf(float f) {
    unsigned int u = __builtin_bit_cast(unsigned int, f);
    unsigned int r = (u + 0x7fffu + ((u >> 16) & 1u)) >> 16;
    return (short)r;
}
// fp32 -> bf16 truncation (1 VALU op; used for P where bias is negligible)
static __device__ inline short f2bf_trunc(float f) {
    return (short)(__builtin_bit_cast(unsigned int, f) >> 16);
}
// bf16 -> fp32
static __device__ inline float bf2f(short s) {
    return __builtin_bit_cast(float, ((unsigned int)(unsigned short)s) << 16);
}

// ---------------------------------------------------------------------------
// LayerNorm: one wave per row of 512, fp32 in -> bf16 out
// ---------------------------------------------------------------------------
__global__ __launch_bounds__(64) void ln_kernel(const float* __restrict__ X,
        const float* __restrict__ G, const float* __restrict__ Bb,
        short* __restrict__ Y)
{
    int row = blockIdx.x;
    int t = threadIdx.x;
    const float* xr = X + (size_t)row * D_;
    float4 v0 = *(const float4*)(xr + t * 4);
    float4 v1 = *(const float4*)(xr + 256 + t * 4);
    float sum = v0.x + v0.y + v0.z + v0.w + v1.x + v1.y + v1.z + v1.w;
    float ssq = v0.x*v0.x + v0.y*v0.y + v0.z*v0.z + v0.w*v0.w
              + v1.x*v1.x + v1.y*v1.y + v1.z*v1.z + v1.w*v1.w;
    #pragma unroll
    for (int off = 32; off > 0; off >>= 1) {
        sum += __shfl_down(sum, off);
        ssq += __shfl_down(ssq, off);
    }
    sum = __shfl(sum, 0);
    ssq = __shfl(ssq, 0);
    float mean = sum * (1.0f / D_);
    float var  = ssq * (1.0f / D_) - mean * mean;
    float rstd = rsqrtf(var + EPS_);

    float4 g0 = *(const float4*)(G + t * 4);
    float4 g1 = *(const float4*)(G + 256 + t * 4);
    float4 b0 = *(const float4*)(Bb + t * 4);
    float4 b1 = *(const float4*)(Bb + 256 + t * 4);
    short4 o0, o1;
    o0.x = f2bf((v0.x - mean) * rstd * g0.x + b0.x);
    o0.y = f2bf((v0.y - mean) * rstd * g0.y + b0.y);
    o0.z = f2bf((v0.z - mean) * rstd * g0.z + b0.z);
    o0.w = f2bf((v0.w - mean) * rstd * g0.w + b0.w);
    o1.x = f2bf((v1.x - mean) * rstd * g1.x + b1.x);
    o1.y = f2bf((v1.y - mean) * rstd * g1.y + b1.y);
    o1.z = f2bf((v1.z - mean) * rstd * g1.z + b1.z);
    o1.w = f2bf((v1.w - mean) * rstd * g1.w + b1.w);
    short* yr = Y + (size_t)row * D_;
    *(short4*)(yr + t * 4)       = o0;
    *(short4*)(yr + 256 + t * 4) = o1;
}

// ---------------------------------------------------------------------------
// All weight transposes fused into one launch. 3072 tiles of 32x32.
// block (32,8).
// ---------------------------------------------------------------------------
__global__ __launch_bounds__(256) void prep_kernel(
        const float* __restrict__ Wq, const float* __restrict__ Wk,
        const float* __restrict__ Wv, const float* __restrict__ Wp,
        const float* __restrict__ W1, const float* __restrict__ W2,
        short* __restrict__ wqkv, short* __restrict__ wpt,
        short* __restrict__ w1t, short* __restrict__ w2t)
{
    __shared__ float tile[32][33];
    int idx = blockIdx.x;
    const float* src; short* dst; int R, C, tx0, ty0;
    if (idx < 768) {            // Wq/Wk/Wv: per head [512][64] -> [64][512]
        int w = idx >> 8, rem = idx & 255;
        int hh = rem >> 5, t = rem & 31;
        const float* base = (w == 0) ? Wq : ((w == 1) ? Wk : Wv);
        src = base + hh * (D_ * DH_);
        dst = wqkv + w * (512 * 512) + hh * (DH_ * D_);
        R = 512; C = 64; tx0 = (t & 1) * 32; ty0 = (t >> 1) * 32;
    } else if (idx < 1024) {    // Wproj [512][512]
        int t = idx - 768;
        src = Wp; dst = wpt; R = 512; C = 512;
        tx0 = (t & 15) * 32; ty0 = (t >> 4) * 32;
    } else if (idx < 2048) {    // W1 [512][2048] -> [2048][512]
        int t = idx - 1024;
        src = W1; dst = w1t; R = 512; C = 2048;
        tx0 = (t & 63) * 32; ty0 = (t >> 6) * 32;
    } else {                    // W2 [2048][512] -> [512][2048]
        int t = idx - 2048;
        src = W2; dst = w2t; R = 2048; C = 512;
        tx0 = (t & 15) * 32; ty0 = (t >> 4) * 32;
    }
    int tx = threadIdx.x, ty = threadIdx.y;
    #pragma unroll
    for (int i = 0; i < 32; i += 8)
        tile[ty + i][tx] = src[(size_t)(ty0 + ty + i) * C + tx0 + tx];
    __syncthreads();
    #pragma unroll
    for (int i = 0; i < 32; i += 8)
        dst[(size_t)(tx0 + ty + i) * R + ty0 + tx] = f2bf(tile[tx][ty + i]);
}

// ---------------------------------------------------------------------------
// bf16 MFMA GEMM: C[M,N] = A[M,K] @ Bt[N,K]^T.  128x128 tile, BK=32,
// single-barrier double-buffered global_load_lds pipeline.
// grid = (M/128, N/128): M-blocks on x -> XCD-pinned A rows (L2-hot).
// ---------------------------------------------------------------------------
__global__ __launch_bounds__(256) void mm_kernel(const short* __restrict__ A,
        const short* __restrict__ Bt, void* __restrict__ C,
        const float* __restrict__ bias, const float* __restrict__ resid,
        int M, int N, int K, int relu, int out_bf16)
{
    __shared__ short As[2][128 * 32];
    __shared__ short Bs[2][128 * 32];
    const int tid = threadIdx.x;
    const int wave = tid >> 6, lane = tid & 63;
    const int quad = lane >> 4, l15 = lane & 15;
    const int m0 = blockIdx.x * 128, n0 = blockIdx.y * 128;
    const int mw = (wave & 1) * 64, nw = (wave >> 1) * 64;

#define STAGE_MM(bufi, kk) \
    { \
        for (int r = 0; r < 2; ++r) { \
            int c = r * 256 + tid; \
            int row = c >> 2, seg = (c & 3) ^ (row & 3); \
            GLL16(A + (size_t)(m0 + row) * K + (kk) + seg * 8, \
                  As[bufi] + (size_t)(r * 256 + wave * 64) * 8); \
            GLL16(Bt + (size_t)(n0 + row) * K + (kk) + seg * 8, \
                  Bs[bufi] + (size_t)(r * 256 + wave * 64) * 8); \
        } \
    }

    f32x4 acc[4][4];
    #pragma unroll
    for (int i = 0; i < 4; ++i)
        #pragma unroll
        for (int j = 0; j < 4; ++j)
            acc[i][j] = (f32x4){0.f, 0.f, 0.f, 0.f};

    STAGE_MM(0, 0);
    int buf = 0;
    for (int k0 = 0; k0 < K; k0 += 32) {
        __syncthreads();                      // drains prefetch issued last iter
        if (k0 + 32 < K) STAGE_MM(buf ^ 1, k0 + 32);
        b16x8 af[4], bf[4];
        #pragma unroll
        for (int i = 0; i < 4; ++i) {
            int row = mw + i * 16 + l15;
            af[i] = *(const b16x8*)(As[buf] + row * 32 + ((quad ^ (row & 3)) * 8));
        }
        #pragma unroll
        for (int j = 0; j < 4; ++j) {
            int row = nw + j * 16 + l15;
            bf[j] = *(const b16x8*)(Bs[buf] + row * 32 + ((quad ^ (row & 3)) * 8));
        }
        #pragma unroll
        for (int i = 0; i < 4; ++i)
            #pragma unroll
            for (int j = 0; j < 4; ++j)
                acc[i][j] = MFMA16(af[i], bf[j], acc[i][j]);
        buf ^= 1;
    }
#undef STAGE_MM

    #pragma unroll
    for (int i = 0; i < 4; ++i) {
        #pragma unroll
        for (int r = 0; r < 4; ++r) {
            size_t row = (size_t)(m0 + mw + i * 16 + quad * 4 + r);
            #pragma unroll
            for (int j = 0; j < 4; ++j) {
                int col = n0 + nw + j * 16 + l15;
                float v = acc[i][j][r];
                if (bias)  v += bias[col];
                if (resid) v += resid[row * N + col];
                if (relu)  v = fmaxf(v, 0.0f);
                if (out_bf16) ((short*)C)[row * N + col] = f2bf(v);
                else          ((float*)C)[row * N + col] = v;
            }
        }
    }
}

// ---------------------------------------------------------------------------
// bf16 MFMA GEMM, 128(M)x64(N), BK=32 dbuf pipeline (FFN2). grid=(M/128,N/64).
// ---------------------------------------------------------------------------
__global__ __launch_bounds__(256) void mm64_kernel(const short* __restrict__ A,
        const short* __restrict__ Bt, void* __restrict__ C,
        const float* __restrict__ bias, const float* __restrict__ resid,
        int M, int N, int K, int relu, int out_bf16)
{
    __shared__ short As[2][128 * 32];
    __shared__ short Bs[2][64 * 32];
    const int tid = threadIdx.x;
    const int wave = tid >> 6, lane = tid & 63;
    const int quad = lane >> 4, l15 = lane & 15;
    const int m0 = blockIdx.x * 128, n0 = blockIdx.y * 64;
    const int mw = (wave & 1) * 64, nw = (wave >> 1) * 32;

#define STAGE_M64(bufi, kk) \
    { \
        for (int r = 0; r < 2; ++r) { \
            int c = r * 256 + tid; \
            int row = c >> 2, seg = (c & 3) ^ (row & 3); \
            GLL16(A + (size_t)(m0 + row) * K + (kk) + seg * 8, \
                  As[bufi] + (size_t)(r * 256 + wave * 64) * 8); \
        } \
        { \
            int row = tid >> 2, seg = (tid & 3) ^ (row & 3); \
            GLL16(Bt + (size_t)(n0 + row) * K + (kk) + seg * 8, \
                  Bs[bufi] + (size_t)(wave * 64) * 8); \
        } \
    }

    f32x4 acc[4][2];
    #pragma unroll
    for (int i = 0; i < 4; ++i)
        #pragma unroll
        for (int j = 0; j < 2; ++j)
            acc[i][j] = (f32x4){0.f, 0.f, 0.f, 0.f};

    STAGE_M64(0, 0);
    int buf = 0;
    for (int k0 = 0; k0 < K; k0 += 32) {
        __syncthreads();
        if (k0 + 32 < K) STAGE_M64(buf ^ 1, k0 + 32);
        b16x8 af[4], bf[2];
        #pragma unroll
        for (int i = 0; i < 4; ++i) {
            int row = mw + i * 16 + l15;
            af[i] = *(const b16x8*)(As[buf] + row * 32 + ((quad ^ (row & 3)) * 8));
        }
        #pragma unroll
        for (int j = 0; j < 2; ++j) {
            int row = nw + j * 16 + l15;
            bf[j] = *(const b16x8*)(Bs[buf] + row * 32 + ((quad ^ (row & 3)) * 8));
        }
        #pragma unroll
        for (int i = 0; i < 4; ++i)
            #pragma unroll
            for (int j = 0; j < 2; ++j)
                acc[i][j] = MFMA16(af[i], bf[j], acc[i][j]);
        buf ^= 1;
    }
#undef STAGE_M64

    #pragma unroll
    for (int i = 0; i < 4; ++i) {
        #pragma unroll
        for (int r = 0; r < 4; ++r) {
            size_t row = (size_t)(m0 + mw + i * 16 + quad * 4 + r);
            #pragma unroll
            for (int j = 0; j < 2; ++j) {
                int col = n0 + nw + j * 16 + l15;
                float v = acc[i][j][r];
                if (bias)  v += bias[col];
                if (resid) v += resid[row * N + col];
                if (relu)  v = fmaxf(v, 0.0f);
                if (out_bf16) ((short*)C)[row * N + col] = f2bf(v);
                else          ((float*)C)[row * N + col] = v;
            }
        }
    }
}

// ---------------------------------------------------------------------------
// bf16 MFMA GEMM, 64x64, BK=32 dbuf pipeline (proj). grid = (M/64, N/64).
// ---------------------------------------------------------------------------
__global__ __launch_bounds__(256) void mm6464_kernel(const short* __restrict__ A,
        const short* __restrict__ Bt, void* __restrict__ C,
        const float* __restrict__ bias, const float* __restrict__ resid,
        int M, int N, int K, int relu, int out_bf16)
{
    __shared__ short As[2][64 * 32];
    __shared__ short Bs[2][64 * 32];
    const int tid = threadIdx.x;
    const int wave = tid >> 6, lane = tid & 63;
    const int quad = lane >> 4, l15 = lane & 15;
    const int m0 = blockIdx.x * 64, n0 = blockIdx.y * 64;
    const int nw = wave * 16;

#define STAGE_M66(bufi, kk) \
    { \
        int row = tid >> 2, seg = (tid & 3) ^ (row & 3); \
        GLL16(A + (size_t)(m0 + row) * K + (kk) + seg * 8, \
              As[bufi] + (size_t)(wave * 64) * 8); \
        GLL16(Bt + (size_t)(n0 + row) * K + (kk) + seg * 8, \
              Bs[bufi] + (size_t)(wave * 64) * 8); \
    }

    f32x4 acc[4];
    #pragma unroll
    for (int i = 0; i < 4; ++i) acc[i] = (f32x4){0.f, 0.f, 0.f, 0.f};

    STAGE_M66(0, 0);
    int buf = 0;
    for (int k0 = 0; k0 < K; k0 += 32) {
        __syncthreads();
        if (k0 + 32 < K) STAGE_M66(buf ^ 1, k0 + 32);
        b16x8 af[4], bf;
        #pragma unroll
        for (int i = 0; i < 4; ++i) {
            int row = i * 16 + l15;
            af[i] = *(const b16x8*)(As[buf] + row * 32 + ((quad ^ (row & 3)) * 8));
        }
        {
            int row = nw + l15;
            bf = *(const b16x8*)(Bs[buf] + row * 32 + ((quad ^ (row & 3)) * 8));
        }
        #pragma unroll
        for (int i = 0; i < 4; ++i)
            acc[i] = MFMA16(af[i], bf, acc[i]);
        buf ^= 1;
    }
#undef STAGE_M66

    #pragma unroll
    for (int i = 0; i < 4; ++i) {
        #pragma unroll
        for (int r = 0; r < 4; ++r) {
            size_t row = (size_t)(m0 + i * 16 + quad * 4 + r);
            int col = n0 + nw + l15;
            float v = acc[i][r];
            if (bias)  v += bias[col];
            if (resid) v += resid[row * N + col];
            if (relu)  v = fmaxf(v, 0.0f);
            if (out_bf16) ((short*)C)[row * N + col] = f2bf(v);
            else          ((float*)C)[row * N + col] = v;
        }
    }
}

// ---------------------------------------------------------------------------
// Flash attention, S^T formulation, SPLIT-K x2. grid (32 bh, 32 qt, 2 split).
// Each block handles half of (bh,qi)'s kj range; writes normalized partial O
// (bf16, [qrow][dh]) + per-row (m,l) fp32 to scratch. Qs aliases the epilogue
// repack buffer (Q frags are hoisted at kj==klo) -> 25.6 KB LDS, 6 blocks/CU.
// ---------------------------------------------------------------------------
__global__ __launch_bounds__(256) void attn_kernel(const short* __restrict__ qkv,
        short* __restrict__ Opart, float* __restrict__ Ml)
{
    __shared__ short Qs[64 * 72];   // [0..64*64): swizzled Q; epilogue: stride-72 repack
    __shared__ short Ks[64 * 64];   // [tok][dh], swizzled
    __shared__ short Vt[64 * 64];   // [dh][tok], granule-swizzled, stride 64

    const int tid = threadIdx.x;
    const int wave = tid >> 6, lane = tid & 63;
    const int quad = lane >> 4, l15 = lane & 15;
    const int bh = blockIdx.x;
    const int qi = 31 - (int)blockIdx.y;
    const int split = blockIdx.z;
    const int b = bh >> 3, h = bh & 7;
    const size_t tok0 = (size_t)b * T_;
    const int qrow_rel = wave * 16 + l15;
    const int half = (qi + 1) >> 1;
    const int klo = split ? half : 0;
    const int khi = split ? qi + 1 : half;
    const int pidx = split * 1024 + bh * 32 + qi;
    short* Op = Opart + (size_t)pidx * 4096;
    float* mlp = Ml + (size_t)pidx * 128;

    if (klo >= khi) {               // empty split (qi==0, split==0)
        for (int i = tid; i < 2048; i += 256) ((int*)Op)[i] = 0;
        if (tid < 64) { mlp[tid] = NEGINF_; mlp[64 + tid] = 0.0f; }
        return;
    }

    // stage Q tile (swizzled)
    #pragma unroll
    for (int r = 0; r < 2; ++r) {
        int c = r * 256 + tid;
        int tk = c >> 3;
        int seg = (c & 7) ^ (tk & 7);
        GLL16(qkv + (tok0 + qi * 64 + tk) * 1536 + h * 64 + seg * 8,
              Qs + (size_t)(r * 256 + wave * 64) * 8);
    }

    float mrow = NEGINF_, lrow = 0.0f;
    f32x4 ot[4];   // O^T: row=dh=dt*16+quad*4+rr, col=qrow=l15
    #pragma unroll
    for (int dt = 0; dt < 4; ++dt) ot[dt] = (f32x4){0.f, 0.f, 0.f, 0.f};

    b16x8 qf[2];

    for (int kj = klo; kj < khi; ++kj) {
        __syncthreads();   // prev-iter LDS reads done (and Q GLL drained on first)
        // stage K tile (swizzled)
        #pragma unroll
        for (int r = 0; r < 2; ++r) {
            int c = r * 256 + tid;
            int tk = c >> 3;
            int seg = (c & 7) ^ (tk & 7);
            GLL16(qkv + (tok0 + kj * 64 + tk) * 1536 + 512 + h * 64 + seg * 8,
                  Ks + (size_t)(r * 256 + wave * 64) * 8);
        }
        // stage V transposed, granule-swizzled: thread = (s 0..7, tp 0..31)
        {
            int s = tid >> 5, tp = tid & 31;
            const short* g0 = qkv + (tok0 + kj * 64 + tp * 2) * 1536 + 1024 + h * 64 + s * 8;
            b16x8 v0 = *(const b16x8*)g0;
            b16x8 v1 = *(const b16x8*)(g0 + 1536);
            int* vo = (int*)Vt;
            int gg = tp >> 1, hlf = tp & 1;
            #pragma unroll
            for (int e = 0; e < 8; ++e) {
                int row = s * 8 + e;
                unsigned int pk = (unsigned int)(unsigned short)v0[e]
                                | ((unsigned int)(unsigned short)v1[e] << 16);
                vo[row * 32 + ((gg ^ (row & 15)) << 1) + hlf] = pk;
            }
        }
        __syncthreads();

        if (kj == klo) {   // Q fragment (B-operand: n=l15=qrow, k=quad*8+j), hoisted
            #pragma unroll
            for (int kb = 0; kb < 2; ++kb) {
                int row = wave * 16 + l15;
                qf[kb] = *(const b16x8*)(Qs + row * 64 + (((kb * 4 + quad) ^ (row & 7)) * 8));
            }
        }

        // S^T = K Q^T  (A=K-frag, B=Q-frag)
        f32x4 st[4];   // mt token-tiles: token = mt*16+quad*4+r, qrow = l15
        #pragma unroll
        for (int mt = 0; mt < 4; ++mt) st[mt] = (f32x4){0.f, 0.f, 0.f, 0.f};
        #pragma unroll
        for (int mt = 0; mt < 4; ++mt) {
            int trow = mt * 16 + l15;
            #pragma unroll
            for (int kb = 0; kb < 2; ++kb) {
                b16x8 kf = *(const b16x8*)(Ks + trow * 64 + (((kb * 4 + quad) ^ (trow & 7)) * 8));
                st[mt] = MFMA16(kf, qf[kb], st[mt]);
            }
        }

        // causal mask + token-max (in-lane 16 + cross-quad 2 shuffles)
        const bool diag = (kj == qi);
        float mx = NEGINF_;
        #pragma unroll
        for (int mt = 0; mt < 4; ++mt)
            #pragma unroll
            for (int r = 0; r < 4; ++r) {
                if (diag && (mt * 16 + quad * 4 + r) > qrow_rel) st[mt][r] = NEGINF_;
                mx = fmaxf(mx, st[mt][r]);
            }
        mx = fmaxf(mx, __shfl_xor(mx, 16));
        mx = fmaxf(mx, __shfl_xor(mx, 32));
        float mn = fmaxf(mrow, mx);
        float alpha = EXP2F((mrow - mn) * SC2_);
        float mnsc = mn * SC2_;
        mrow = mn;
        float rs = 0.0f;
        b16x4 pf[4];   // P^T fragments: directly in 16x16x16 B-operand layout
        #pragma unroll
        for (int mt = 0; mt < 4; ++mt)
            #pragma unroll
            for (int r = 0; r < 4; ++r) {
                float e = EXP2F(fmaf(st[mt][r], SC2_, -mnsc));
                rs += e;
                pf[mt][r] = f2bf_trunc(e);
            }
        rs += __shfl_xor(rs, 16);
        rs += __shfl_xor(rs, 32);
        lrow = lrow * alpha + rs;
        #pragma unroll
        for (int dt = 0; dt < 4; ++dt) {
            ot[dt][0] *= alpha; ot[dt][1] *= alpha;
            ot[dt][2] *= alpha; ot[dt][3] *= alpha;
        }
        // O^T += V^T P^T  (16x16x16; A=V^T-frag from swizzled Vt, B=P^T in regs)
        #pragma unroll
        for (int dt = 0; dt < 4; ++dt) {
            const short* vrow = Vt + (dt * 16 + l15) * 64;
            #pragma unroll
            for (int kt = 0; kt < 4; ++kt) {
                b16x4 vf = *(const b16x4*)(vrow + (((kt * 4 + quad) ^ l15) << 2));
                ot[dt] = MFMA16K16(vf, pf[kt], ot[dt]);
            }
        }
    }

    // epilogue: normalize, repack via same-wave LDS strip (Qs alias), store
    __syncthreads();   // all waves done reading Ks/Vt AND Qs fragments
    float inv = 1.0f / lrow;
    #pragma unroll
    for (int dt = 0; dt < 4; ++dt) {
        b16x4 o4;
        o4[0] = f2bf(ot[dt][0] * inv);
        o4[1] = f2bf(ot[dt][1] * inv);
        o4[2] = f2bf(ot[dt][2] * inv);
        o4[3] = f2bf(ot[dt][3] * inv);
        *(b16x4*)(Qs + (size_t)qrow_rel * 72 + dt * 16 + quad * 4) = o4;
    }
    // rows tid>>2 land inside this wave's own strip -> DS in-order, no barrier
    {
        int row = tid >> 2, ch = tid & 3;
        b16x8 lo = *(const b16x8*)(Qs + (size_t)row * 72 + ch * 16);
        b16x8 hi = *(const b16x8*)(Qs + (size_t)row * 72 + ch * 16 + 8);
        short* dst = Op + row * 64 + ch * 16;
        *(b16x8*)dst = lo;
        *(b16x8*)(dst + 8) = hi;
    }
    if (quad == 0) {
        mlp[qrow_rel] = mrow;
        mlp[64 + qrow_rel] = lrow;
    }
}

// ---------------------------------------------------------------------------
// Combine the two split-K partials: O = w1*O1 + w2*O2,
// w_i = l_i*2^((m_i-mx)*SC2) / sum. grid 1024 (one (bh,qi) per block), 256 thr.
// ---------------------------------------------------------------------------
__global__ __launch_bounds__(256) void attn_combine_kernel(
        const short* __restrict__ Opart, const float* __restrict__ Ml,
        short* __restrict__ Ob)
{
    int pair = blockIdx.x;              // bh*32 + qi
    int bh = pair >> 5, qi = pair & 31;
    int b = bh >> 3, h = bh & 7;
    int tid = threadIdx.x;
    const short* O1 = Opart + (size_t)pair * 4096;
    const short* O2 = Opart + (size_t)(1024 + pair) * 4096;
    const float* ml1 = Ml + (size_t)pair * 128;
    const float* ml2 = Ml + (size_t)(1024 + pair) * 128;
    int ch = tid & 7;                   // 8 shorts per chunk
    #pragma unroll
    for (int it = 0; it < 2; ++it) {
        int row = it * 32 + (tid >> 3);
        float m1 = ml1[row], l1 = ml1[64 + row];
        float m2 = ml2[row], l2 = ml2[64 + row];
        float mx = fmaxf(m1, m2);
        float e1 = l1 * EXP2F((m1 - mx) * SC2_);
        float e2 = l2 * EXP2F((m2 - mx) * SC2_);
        float inv = 1.0f / (e1 + e2);
        float w1 = e1 * inv, w2 = e2 * inv;
        b16x8 a = *(const b16x8*)(O1 + row * 64 + ch * 8);
        b16x8 c = *(const b16x8*)(O2 + row * 64 + ch * 8);
        b16x8 o;
        #pragma unroll
        for (int e = 0; e < 8; ++e)
            o[e] = f2bf(w1 * bf2f(a[e]) + w2 * bf2f(c[e]));
        short* dst = Ob + ((size_t)(b * T_ + qi * 64 + row)) * 512 + h * 64 + ch * 8;
        *(b16x8*)dst = o;
    }
}

// ---------------------------------------------------------------------------
extern "C" void kernel_launch(void* const* d_in, const int* in_sizes, int n_in,
                              void* d_out, int out_size, void* d_ws, size_t ws_size,
                              hipStream_t stream) {
    (void)in_sizes; (void)n_in; (void)out_size; (void)ws_size;
    const float* x     = (const float*)d_in[0];
    const float* ln_g  = (const float*)d_in[1];
    const float* ln_b  = (const float*)d_in[2];
    const float* Wq    = (const float*)d_in[3];
    const float* Wk    = (const float*)d_in[4];
    const float* Wv    = (const float*)d_in[5];
    const float* Wproj = (const float*)d_in[6];
    const float* bproj = (const float*)d_in[7];
    const float* W1    = (const float*)d_in[8];
    const float* b1    = (const float*)d_in[9];
    const float* W2    = (const float*)d_in[10];
    const float* b2    = (const float*)d_in[11];
    float* out = (float*)d_out;

    char* W = (char*)d_ws;
    short* hbuf  = (short*)(W + 0);                    // 8 MB  (LN out, bf16)
    short* qkvb  = (short*)(W + ((size_t)8  << 20));   // 24 MB [BT][1536]
    short* attno = (short*)(W + ((size_t)32 << 20));   // 8 MB  [BT][512]
    float* x1    = (float*)(W + ((size_t)40 << 20));   // 16 MB
    short* ff1   = (short*)(W + ((size_t)56 << 20));   // 32 MB [BT][2048]
    short* wqkv  = (short*)(W + ((size_t)88 << 20));   // 1.5 MB [1536][512]
    short* wpt   = (short*)(W + ((size_t)90 << 20));   // 0.5 MB [512][512]
    short* w1t   = (short*)(W + ((size_t)91 << 20));   // 2 MB  [2048][512]
    short* w2t   = (short*)(W + ((size_t)93 << 20));   // 2 MB  [512][2048]
    // attention split-K scratch aliases the ff1 region (dead until step 6):
    short* Opart = (short*)(W + ((size_t)56 << 20));   // 16 MB [2][1024][64][64] bf16
    float* Ml    = (float*)(W + ((size_t)72 << 20));   // 1 MB  [2][1024][2][64] fp32

    // 0. all weight transposes in one launch
    prep_kernel<<<dim3(3072), dim3(32, 8), 0, stream>>>(
        Wq, Wk, Wv, Wproj, W1, W2, wqkv, wpt, w1t, w2t);
    // 1. h = LN(x) -> bf16
    ln_kernel<<<dim3(BT_), dim3(64), 0, stream>>>(x, ln_g, ln_b, hbuf);
    // 2. qkv = h @ Wqkv  [8192,1536] bf16  (grid: M-blocks on x for XCD A-reuse)
    mm_kernel<<<dim3(64, 12), dim3(256), 0, stream>>>(hbuf, wqkv, qkvb,
        nullptr, nullptr, BT_, 1536, D_, 0, 1);
    // 3. attention split-K x2 -> partials, then combine -> attno bf16
    attn_kernel<<<dim3(32, 32, 2), dim3(256), 0, stream>>>(qkvb, Opart, Ml);
    attn_combine_kernel<<<dim3(1024), dim3(256), 0, stream>>>(Opart, Ml, attno);
    // 4. x1 = x + attno @ Wproj + bproj  (fp32)
    mm6464_kernel<<<dim3(128, 8), dim3(256), 0, stream>>>(attno, wpt, x1,
        bproj, x, BT_, D_, D_, 0, 0);
    // 5. h2 = LN(x1) -> bf16 (reuse hbuf)
    ln_kernel<<<dim3(BT_), dim3(64), 0, stream>>>(x1, ln_g, ln_b, hbuf);
    // 6. ff1 = relu(h2 @ W1 + b1)  bf16
    mm_kernel<<<dim3(64, 16), dim3(256), 0, stream>>>(hbuf, w1t, ff1,
        b1, nullptr, BT_, FF_, D_, 1, 1);
    // 7. out = x1 + ff1 @ W2 + b2  (fp32)
    mm64_kernel<<<dim3(64, 8), dim3(256), 0, stream>>>(ff1, w2t, out,
        b2, x1, BT_, D_, FF_, 0, 0);
}

// Round 10
// 287.607 us; speedup vs baseline: 4.5937x; 1.0070x over previous
//
#include <hip/hip_runtime.h>
#include <math.h>

#define B_ 4
#define T_ 2048
#define D_ 512
#define H_ 8
#define DH_ 64
#define BT_ 8192
#define FF_ 2048
#define EPS_ 1e-5f
#define SCALE_ 0.04419417382415922f   // 512^-0.5
#define SC2_ 0.06375861151f           // SCALE_ * log2(e)
#define NEGINF_ -1e30f

typedef short b16x8 __attribute__((ext_vector_type(8)));
typedef short b16x4 __attribute__((ext_vector_type(4)));
typedef float f32x4 __attribute__((ext_vector_type(4)));

#define MFMA16(a, b, c) __builtin_amdgcn_mfma_f32_16x16x32_bf16(a, b, c, 0, 0, 0)
#define MFMA16K16(a, b, c) __builtin_amdgcn_mfma_f32_16x16x16bf16_1k(a, b, c, 0, 0, 0)

#define GLL16(gp, lp) \
    __builtin_amdgcn_global_load_lds((const __attribute__((address_space(1))) void*)(gp), \
                                     (__attribute__((address_space(3))) void*)(lp), 16, 0, 0)

#if __has_builtin(__builtin_amdgcn_exp2f)
#define EXP2F(x) __builtin_amdgcn_exp2f(x)
#else
#define EXP2F(x) exp2f(x)
#endif

// fp32 -> bf16 RNE (finite inputs)
static __device__ inline short f2bf(float f) {
    unsigned int u = __builtin_bit_cast(unsigned int, f);
    unsigned int r = (u + 0x7fffu + ((u >> 16) & 1u)) >> 16;
    return (short)r;
}
// fp32 -> bf16 truncation (1 VALU op; used for P where bias is negligible)
static __device__ inline short f2bf_trunc(float f) {
    return (short)(__builtin_bit_cast(unsigned int, f) >> 16);
}
// bf16 -> fp32
static __device__ inline float bf2f(short s) {
    return __builtin_bit_cast(float, ((unsigned int)(unsigned short)s) << 16);
}

// ---------------------------------------------------------------------------
// LayerNorm: one wave per row of 512, fp32 in -> bf16 out
// ---------------------------------------------------------------------------
__global__ __launch_bounds__(64) void ln_kernel(const float* __restrict__ X,
        const float* __restrict__ G, const float* __restrict__ Bb,
        short* __restrict__ Y)
{
    int row = blockIdx.x;
    int t = threadIdx.x;
    const float* xr = X + (size_t)row * D_;
    float4 v0 = *(const float4*)(xr + t * 4);
    float4 v1 = *(const float4*)(xr + 256 + t * 4);
    float sum = v0.x + v0.y + v0.z + v0.w + v1.x + v1.y + v1.z + v1.w;
    float ssq = v0.x*v0.x + v0.y*v0.y + v0.z*v0.z + v0.w*v0.w
              + v1.x*v1.x + v1.y*v1.y + v1.z*v1.z + v1.w*v1.w;
    #pragma unroll
    for (int off = 32; off > 0; off >>= 1) {
        sum += __shfl_down(sum, off);
        ssq += __shfl_down(ssq, off);
    }
    sum = __shfl(sum, 0);
    ssq = __shfl(ssq, 0);
    float mean = sum * (1.0f / D_);
    float var  = ssq * (1.0f / D_) - mean * mean;
    float rstd = rsqrtf(var + EPS_);

    float4 g0 = *(const float4*)(G + t * 4);
    float4 g1 = *(const float4*)(G + 256 + t * 4);
    float4 b0 = *(const float4*)(Bb + t * 4);
    float4 b1 = *(const float4*)(Bb + 256 + t * 4);
    short4 o0, o1;
    o0.x = f2bf((v0.x - mean) * rstd * g0.x + b0.x);
    o0.y = f2bf((v0.y - mean) * rstd * g0.y + b0.y);
    o0.z = f2bf((v0.z - mean) * rstd * g0.z + b0.z);
    o0.w = f2bf((v0.w - mean) * rstd * g0.w + b0.w);
    o1.x = f2bf((v1.x - mean) * rstd * g1.x + b1.x);
    o1.y = f2bf((v1.y - mean) * rstd * g1.y + b1.y);
    o1.z = f2bf((v1.z - mean) * rstd * g1.z + b1.z);
    o1.w = f2bf((v1.w - mean) * rstd * g1.w + b1.w);
    short* yr = Y + (size_t)row * D_;
    *(short4*)(yr + t * 4)       = o0;
    *(short4*)(yr + 256 + t * 4) = o1;
}

// ---------------------------------------------------------------------------
// All weight transposes fused into one launch. 3072 tiles of 32x32.
// block (32,8).
// ---------------------------------------------------------------------------
__global__ __launch_bounds__(256) void prep_kernel(
        const float* __restrict__ Wq, const float* __restrict__ Wk,
        const float* __restrict__ Wv, const float* __restrict__ Wp,
        const float* __restrict__ W1, const float* __restrict__ W2,
        short* __restrict__ wqkv, short* __restrict__ wpt,
        short* __restrict__ w1t, short* __restrict__ w2t)
{
    __shared__ float tile[32][33];
    int idx = blockIdx.x;
    const float* src; short* dst; int R, C, tx0, ty0;
    if (idx < 768) {            // Wq/Wk/Wv: per head [512][64] -> [64][512]
        int w = idx >> 8, rem = idx & 255;
        int hh = rem >> 5, t = rem & 31;
        const float* base = (w == 0) ? Wq : ((w == 1) ? Wk : Wv);
        src = base + hh * (D_ * DH_);
        dst = wqkv + w * (512 * 512) + hh * (DH_ * D_);
        R = 512; C = 64; tx0 = (t & 1) * 32; ty0 = (t >> 1) * 32;
    } else if (idx < 1024) {    // Wproj [512][512]
        int t = idx - 768;
        src = Wp; dst = wpt; R = 512; C = 512;
        tx0 = (t & 15) * 32; ty0 = (t >> 4) * 32;
    } else if (idx < 2048) {    // W1 [512][2048] -> [2048][512]
        int t = idx - 1024;
        src = W1; dst = w1t; R = 512; C = 2048;
        tx0 = (t & 63) * 32; ty0 = (t >> 6) * 32;
    } else {                    // W2 [2048][512] -> [512][2048]
        int t = idx - 2048;
        src = W2; dst = w2t; R = 2048; C = 512;
        tx0 = (t & 15) * 32; ty0 = (t >> 4) * 32;
    }
    int tx = threadIdx.x, ty = threadIdx.y;
    #pragma unroll
    for (int i = 0; i < 32; i += 8)
        tile[ty + i][tx] = src[(size_t)(ty0 + ty + i) * C + tx0 + tx];
    __syncthreads();
    #pragma unroll
    for (int i = 0; i < 32; i += 8)
        dst[(size_t)(tx0 + ty + i) * R + ty0 + tx] = f2bf(tile[tx][ty + i]);
}

// ---------------------------------------------------------------------------
// bf16 MFMA GEMM: C[M,N] = A[M,K] @ Bt[N,K]^T.  128x128 tile, BK=32,
// single-barrier double-buffered global_load_lds pipeline.
// Chunk swizzle f(row) = (row>>1)&3: read chunk%8 = 4(row&1) + quad^f(row)
// covers all 8 bank-quads exactly 2x across 16 lanes -> conflict-free
// (the R8 f(row)=row&3 layout was 4-way conflicted: period-4 alias).
// grid = (M/128, N/128): M-blocks on x -> XCD-pinned A rows (L2-hot).
// ---------------------------------------------------------------------------
__global__ __launch_bounds__(256) void mm_kernel(const short* __restrict__ A,
        const short* __restrict__ Bt, void* __restrict__ C,
        const float* __restrict__ bias, const float* __restrict__ resid,
        int M, int N, int K, int relu, int out_bf16)
{
    __shared__ short As[2][128 * 32];
    __shared__ short Bs[2][128 * 32];
    const int tid = threadIdx.x;
    const int wave = tid >> 6, lane = tid & 63;
    const int quad = lane >> 4, l15 = lane & 15;
    const int m0 = blockIdx.x * 128, n0 = blockIdx.y * 128;
    const int mw = (wave & 1) * 64, nw = (wave >> 1) * 64;

#define STAGE_MM(bufi, kk) \
    { \
        for (int r = 0; r < 2; ++r) { \
            int c = r * 256 + tid; \
            int row = c >> 2, seg = (c & 3) ^ ((row >> 1) & 3); \
            GLL16(A + (size_t)(m0 + row) * K + (kk) + seg * 8, \
                  As[bufi] + (size_t)(r * 256 + wave * 64) * 8); \
            GLL16(Bt + (size_t)(n0 + row) * K + (kk) + seg * 8, \
                  Bs[bufi] + (size_t)(r * 256 + wave * 64) * 8); \
        } \
    }

    f32x4 acc[4][4];
    #pragma unroll
    for (int i = 0; i < 4; ++i)
        #pragma unroll
        for (int j = 0; j < 4; ++j)
            acc[i][j] = (f32x4){0.f, 0.f, 0.f, 0.f};

    STAGE_MM(0, 0);
    int buf = 0;
    for (int k0 = 0; k0 < K; k0 += 32) {
        __syncthreads();                      // drains prefetch issued last iter
        if (k0 + 32 < K) STAGE_MM(buf ^ 1, k0 + 32);
        b16x8 af[4], bf[4];
        #pragma unroll
        for (int i = 0; i < 4; ++i) {
            int row = mw + i * 16 + l15;
            af[i] = *(const b16x8*)(As[buf] + row * 32 + ((quad ^ ((row >> 1) & 3)) * 8));
        }
        #pragma unroll
        for (int j = 0; j < 4; ++j) {
            int row = nw + j * 16 + l15;
            bf[j] = *(const b16x8*)(Bs[buf] + row * 32 + ((quad ^ ((row >> 1) & 3)) * 8));
        }
        #pragma unroll
        for (int i = 0; i < 4; ++i)
            #pragma unroll
            for (int j = 0; j < 4; ++j)
                acc[i][j] = MFMA16(af[i], bf[j], acc[i][j]);
        buf ^= 1;
    }
#undef STAGE_MM

    #pragma unroll
    for (int i = 0; i < 4; ++i) {
        #pragma unroll
        for (int r = 0; r < 4; ++r) {
            size_t row = (size_t)(m0 + mw + i * 16 + quad * 4 + r);
            #pragma unroll
            for (int j = 0; j < 4; ++j) {
                int col = n0 + nw + j * 16 + l15;
                float v = acc[i][j][r];
                if (bias)  v += bias[col];
                if (resid) v += resid[row * N + col];
                if (relu)  v = fmaxf(v, 0.0f);
                if (out_bf16) ((short*)C)[row * N + col] = f2bf(v);
                else          ((float*)C)[row * N + col] = v;
            }
        }
    }
}

// ---------------------------------------------------------------------------
// bf16 MFMA GEMM, 128(M)x64(N), BK=32 dbuf pipeline (FFN2). grid=(M/128,N/64).
// Same conflict-free f(row)=(row>>1)&3 swizzle.
// ---------------------------------------------------------------------------
__global__ __launch_bounds__(256) void mm64_kernel(const short* __restrict__ A,
        const short* __restrict__ Bt, void* __restrict__ C,
        const float* __restrict__ bias, const float* __restrict__ resid,
        int M, int N, int K, int relu, int out_bf16)
{
    __shared__ short As[2][128 * 32];
    __shared__ short Bs[2][64 * 32];
    const int tid = threadIdx.x;
    const int wave = tid >> 6, lane = tid & 63;
    const int quad = lane >> 4, l15 = lane & 15;
    const int m0 = blockIdx.x * 128, n0 = blockIdx.y * 64;
    const int mw = (wave & 1) * 64, nw = (wave >> 1) * 32;

#define STAGE_M64(bufi, kk) \
    { \
        for (int r = 0; r < 2; ++r) { \
            int c = r * 256 + tid; \
            int row = c >> 2, seg = (c & 3) ^ ((row >> 1) & 3); \
            GLL16(A + (size_t)(m0 + row) * K + (kk) + seg * 8, \
                  As[bufi] + (size_t)(r * 256 + wave * 64) * 8); \
        } \
        { \
            int row = tid >> 2, seg = (tid & 3) ^ ((row >> 1) & 3); \
            GLL16(Bt + (size_t)(n0 + row) * K + (kk) + seg * 8, \
                  Bs[bufi] + (size_t)(wave * 64) * 8); \
        } \
    }

    f32x4 acc[4][2];
    #pragma unroll
    for (int i = 0; i < 4; ++i)
        #pragma unroll
        for (int j = 0; j < 2; ++j)
            acc[i][j] = (f32x4){0.f, 0.f, 0.f, 0.f};

    STAGE_M64(0, 0);
    int buf = 0;
    for (int k0 = 0; k0 < K; k0 += 32) {
        __syncthreads();
        if (k0 + 32 < K) STAGE_M64(buf ^ 1, k0 + 32);
        b16x8 af[4], bf[2];
        #pragma unroll
        for (int i = 0; i < 4; ++i) {
            int row = mw + i * 16 + l15;
            af[i] = *(const b16x8*)(As[buf] + row * 32 + ((quad ^ ((row >> 1) & 3)) * 8));
        }
        #pragma unroll
        for (int j = 0; j < 2; ++j) {
            int row = nw + j * 16 + l15;
            bf[j] = *(const b16x8*)(Bs[buf] + row * 32 + ((quad ^ ((row >> 1) & 3)) * 8));
        }
        #pragma unroll
        for (int i = 0; i < 4; ++i)
            #pragma unroll
            for (int j = 0; j < 2; ++j)
                acc[i][j] = MFMA16(af[i], bf[j], acc[i][j]);
        buf ^= 1;
    }
#undef STAGE_M64

    #pragma unroll
    for (int i = 0; i < 4; ++i) {
        #pragma unroll
        for (int r = 0; r < 4; ++r) {
            size_t row = (size_t)(m0 + mw + i * 16 + quad * 4 + r);
            #pragma unroll
            for (int j = 0; j < 2; ++j) {
                int col = n0 + nw + j * 16 + l15;
                float v = acc[i][j][r];
                if (bias)  v += bias[col];
                if (resid) v += resid[row * N + col];
                if (relu)  v = fmaxf(v, 0.0f);
                if (out_bf16) ((short*)C)[row * N + col] = f2bf(v);
                else          ((float*)C)[row * N + col] = v;
            }
        }
    }
}

// ---------------------------------------------------------------------------
// bf16 MFMA GEMM, 64x64, BK=32 dbuf pipeline (proj). grid = (M/64, N/64).
// Same conflict-free f(row)=(row>>1)&3 swizzle.
// ---------------------------------------------------------------------------
__global__ __launch_bounds__(256) void mm6464_kernel(const short* __restrict__ A,
        const short* __restrict__ Bt, void* __restrict__ C,
        const float* __restrict__ bias, const float* __restrict__ resid,
        int M, int N, int K, int relu, int out_bf16)
{
    __shared__ short As[2][64 * 32];
    __shared__ short Bs[2][64 * 32];
    const int tid = threadIdx.x;
    const int wave = tid >> 6, lane = tid & 63;
    const int quad = lane >> 4, l15 = lane & 15;
    const int m0 = blockIdx.x * 64, n0 = blockIdx.y * 64;
    const int nw = wave * 16;

#define STAGE_M66(bufi, kk) \
    { \
        int row = tid >> 2, seg = (tid & 3) ^ ((row >> 1) & 3); \
        GLL16(A + (size_t)(m0 + row) * K + (kk) + seg * 8, \
              As[bufi] + (size_t)(wave * 64) * 8); \
        GLL16(Bt + (size_t)(n0 + row) * K + (kk) + seg * 8, \
              Bs[bufi] + (size_t)(wave * 64) * 8); \
    }

    f32x4 acc[4];
    #pragma unroll
    for (int i = 0; i < 4; ++i) acc[i] = (f32x4){0.f, 0.f, 0.f, 0.f};

    STAGE_M66(0, 0);
    int buf = 0;
    for (int k0 = 0; k0 < K; k0 += 32) {
        __syncthreads();
        if (k0 + 32 < K) STAGE_M66(buf ^ 1, k0 + 32);
        b16x8 af[4], bf;
        #pragma unroll
        for (int i = 0; i < 4; ++i) {
            int row = i * 16 + l15;
            af[i] = *(const b16x8*)(As[buf] + row * 32 + ((quad ^ ((row >> 1) & 3)) * 8));
        }
        {
            int row = nw + l15;
            bf = *(const b16x8*)(Bs[buf] + row * 32 + ((quad ^ ((row >> 1) & 3)) * 8));
        }
        #pragma unroll
        for (int i = 0; i < 4; ++i)
            acc[i] = MFMA16(af[i], bf, acc[i]);
        buf ^= 1;
    }
#undef STAGE_M66

    #pragma unroll
    for (int i = 0; i < 4; ++i) {
        #pragma unroll
        for (int r = 0; r < 4; ++r) {
            size_t row = (size_t)(m0 + i * 16 + quad * 4 + r);
            int col = n0 + nw + l15;
            float v = acc[i][r];
            if (bias)  v += bias[col];
            if (resid) v += resid[row * N + col];
            if (relu)  v = fmaxf(v, 0.0f);
            if (out_bf16) ((short*)C)[row * N + col] = f2bf(v);
            else          ((float*)C)[row * N + col] = v;
        }
    }
}

// ---------------------------------------------------------------------------
// Flash attention, S^T formulation, SPLIT-K x2. grid (32 bh, 32 qt, 2 split).
// Each block handles half of (bh,qi)'s kj range; writes normalized partial O
// (bf16, [qrow][dh]) + per-row (m,l) fp32 to scratch. Qs aliases the epilogue
// repack buffer (Q frags are hoisted at kj==klo) -> 25.6 KB LDS, 6 blocks/CU.
// ---------------------------------------------------------------------------
__global__ __launch_bounds__(256) void attn_kernel(const short* __restrict__ qkv,
        short* __restrict__ Opart, float* __restrict__ Ml)
{
    __shared__ short Qs[64 * 72];   // [0..64*64): swizzled Q; epilogue: stride-72 repack
    __shared__ short Ks[64 * 64];   // [tok][dh], swizzled
    __shared__ short Vt[64 * 64];   // [dh][tok], granule-swizzled, stride 64

    const int tid = threadIdx.x;
    const int wave = tid >> 6, lane = tid & 63;
    const int quad = lane >> 4, l15 = lane & 15;
    const int bh = blockIdx.x;
    const int qi = 31 - (int)blockIdx.y;
    const int split = blockIdx.z;
    const int b = bh >> 3, h = bh & 7;
    const size_t tok0 = (size_t)b * T_;
    const int qrow_rel = wave * 16 + l15;
    const int half = (qi + 1) >> 1;
    const int klo = split ? half : 0;
    const int khi = split ? qi + 1 : half;
    const int pidx = split * 1024 + bh * 32 + qi;
    short* Op = Opart + (size_t)pidx * 4096;
    float* mlp = Ml + (size_t)pidx * 128;

    if (klo >= khi) {               // empty split (qi==0, split==0)
        for (int i = tid; i < 2048; i += 256) ((int*)Op)[i] = 0;
        if (tid < 64) { mlp[tid] = NEGINF_; mlp[64 + tid] = 0.0f; }
        return;
    }

    // stage Q tile (swizzled)
    #pragma unroll
    for (int r = 0; r < 2; ++r) {
        int c = r * 256 + tid;
        int tk = c >> 3;
        int seg = (c & 7) ^ (tk & 7);
        GLL16(qkv + (tok0 + qi * 64 + tk) * 1536 + h * 64 + seg * 8,
              Qs + (size_t)(r * 256 + wave * 64) * 8);
    }

    float mrow = NEGINF_, lrow = 0.0f;
    f32x4 ot[4];   // O^T: row=dh=dt*16+quad*4+rr, col=qrow=l15
    #pragma unroll
    for (int dt = 0; dt < 4; ++dt) ot[dt] = (f32x4){0.f, 0.f, 0.f, 0.f};

    b16x8 qf[2];

    for (int kj = klo; kj < khi; ++kj) {
        __syncthreads();   // prev-iter LDS reads done (and Q GLL drained on first)
        // stage K tile (swizzled)
        #pragma unroll
        for (int r = 0; r < 2; ++r) {
            int c = r * 256 + tid;
            int tk = c >> 3;
            int seg = (c & 7) ^ (tk & 7);
            GLL16(qkv + (tok0 + kj * 64 + tk) * 1536 + 512 + h * 64 + seg * 8,
                  Ks + (size_t)(r * 256 + wave * 64) * 8);
        }
        // stage V transposed, granule-swizzled: thread = (s 0..7, tp 0..31)
        {
            int s = tid >> 5, tp = tid & 31;
            const short* g0 = qkv + (tok0 + kj * 64 + tp * 2) * 1536 + 1024 + h * 64 + s * 8;
            b16x8 v0 = *(const b16x8*)g0;
            b16x8 v1 = *(const b16x8*)(g0 + 1536);
            int* vo = (int*)Vt;
            int gg = tp >> 1, hlf = tp & 1;
            #pragma unroll
            for (int e = 0; e < 8; ++e) {
                int row = s * 8 + e;
                unsigned int pk = (unsigned int)(unsigned short)v0[e]
                                | ((unsigned int)(unsigned short)v1[e] << 16);
                vo[row * 32 + ((gg ^ (row & 15)) << 1) + hlf] = pk;
            }
        }
        __syncthreads();

        if (kj == klo) {   // Q fragment (B-operand: n=l15=qrow, k=quad*8+j), hoisted
            #pragma unroll
            for (int kb = 0; kb < 2; ++kb) {
                int row = wave * 16 + l15;
                qf[kb] = *(const b16x8*)(Qs + row * 64 + (((kb * 4 + quad) ^ (row & 7)) * 8));
            }
        }

        // S^T = K Q^T  (A=K-frag, B=Q-frag)
        f32x4 st[4];   // mt token-tiles: token = mt*16+quad*4+r, qrow = l15
        #pragma unroll
        for (int mt = 0; mt < 4; ++mt) st[mt] = (f32x4){0.f, 0.f, 0.f, 0.f};
        #pragma unroll
        for (int mt = 0; mt < 4; ++mt) {
            int trow = mt * 16 + l15;
            #pragma unroll
            for (int kb = 0; kb < 2; ++kb) {
                b16x8 kf = *(const b16x8*)(Ks + trow * 64 + (((kb * 4 + quad) ^ (trow & 7)) * 8));
                st[mt] = MFMA16(kf, qf[kb], st[mt]);
            }
        }

        // causal mask + token-max (in-lane 16 + cross-quad 2 shuffles)
        const bool diag = (kj == qi);
        float mx = NEGINF_;
        #pragma unroll
        for (int mt = 0; mt < 4; ++mt)
            #pragma unroll
            for (int r = 0; r < 4; ++r) {
                if (diag && (mt * 16 + quad * 4 + r) > qrow_rel) st[mt][r] = NEGINF_;
                mx = fmaxf(mx, st[mt][r]);
            }
        mx = fmaxf(mx, __shfl_xor(mx, 16));
        mx = fmaxf(mx, __shfl_xor(mx, 32));
        float mn = fmaxf(mrow, mx);
        float alpha = EXP2F((mrow - mn) * SC2_);
        float mnsc = mn * SC2_;
        mrow = mn;
        float rs = 0.0f;
        b16x4 pf[4];   // P^T fragments: directly in 16x16x16 B-operand layout
        #pragma unroll
        for (int mt = 0; mt < 4; ++mt)
            #pragma unroll
            for (int r = 0; r < 4; ++r) {
                float e = EXP2F(fmaf(st[mt][r], SC2_, -mnsc));
                rs += e;
                pf[mt][r] = f2bf_trunc(e);
            }
        rs += __shfl_xor(rs, 16);
        rs += __shfl_xor(rs, 32);
        lrow = lrow * alpha + rs;
        #pragma unroll
        for (int dt = 0; dt < 4; ++dt) {
            ot[dt][0] *= alpha; ot[dt][1] *= alpha;
            ot[dt][2] *= alpha; ot[dt][3] *= alpha;
        }
        // O^T += V^T P^T  (16x16x16; A=V^T-frag from swizzled Vt, B=P^T in regs)
        #pragma unroll
        for (int dt = 0; dt < 4; ++dt) {
            const short* vrow = Vt + (dt * 16 + l15) * 64;
            #pragma unroll
            for (int kt = 0; kt < 4; ++kt) {
                b16x4 vf = *(const b16x4*)(vrow + (((kt * 4 + quad) ^ l15) << 2));
                ot[dt] = MFMA16K16(vf, pf[kt], ot[dt]);
            }
        }
    }

    // epilogue: normalize, repack via same-wave LDS strip (Qs alias), store
    __syncthreads();   // all waves done reading Ks/Vt AND Qs fragments
    float inv = 1.0f / lrow;
    #pragma unroll
    for (int dt = 0; dt < 4; ++dt) {
        b16x4 o4;
        o4[0] = f2bf(ot[dt][0] * inv);
        o4[1] = f2bf(ot[dt][1] * inv);
        o4[2] = f2bf(ot[dt][2] * inv);
        o4[3] = f2bf(ot[dt][3] * inv);
        *(b16x4*)(Qs + (size_t)qrow_rel * 72 + dt * 16 + quad * 4) = o4;
    }
    // rows tid>>2 land inside this wave's own strip -> DS in-order, no barrier
    {
        int row = tid >> 2, ch = tid & 3;
        b16x8 lo = *(const b16x8*)(Qs + (size_t)row * 72 + ch * 16);
        b16x8 hi = *(const b16x8*)(Qs + (size_t)row * 72 + ch * 16 + 8);
        short* dst = Op + row * 64 + ch * 16;
        *(b16x8*)dst = lo;
        *(b16x8*)(dst + 8) = hi;
    }
    if (quad == 0) {
        mlp[qrow_rel] = mrow;
        mlp[64 + qrow_rel] = lrow;
    }
}

// ---------------------------------------------------------------------------
// Combine the two split-K partials: O = w1*O1 + w2*O2,
// w_i = l_i*2^((m_i-mx)*SC2) / sum. grid 1024 (one (bh,qi) per block), 256 thr.
// ---------------------------------------------------------------------------
__global__ __launch_bounds__(256) void attn_combine_kernel(
        const short* __restrict__ Opart, const float* __restrict__ Ml,
        short* __restrict__ Ob)
{
    int pair = blockIdx.x;              // bh*32 + qi
    int bh = pair >> 5, qi = pair & 31;
    int b = bh >> 3, h = bh & 7;
    int tid = threadIdx.x;
    const short* O1 = Opart + (size_t)pair * 4096;
    const short* O2 = Opart + (size_t)(1024 + pair) * 4096;
    const float* ml1 = Ml + (size_t)pair * 128;
    const float* ml2 = Ml + (size_t)(1024 + pair) * 128;
    int ch = tid & 7;                   // 8 shorts per chunk
    #pragma unroll
    for (int it = 0; it < 2; ++it) {
        int row = it * 32 + (tid >> 3);
        float m1 = ml1[row], l1 = ml1[64 + row];
        float m2 = ml2[row], l2 = ml2[64 + row];
        float mx = fmaxf(m1, m2);
        float e1 = l1 * EXP2F((m1 - mx) * SC2_);
        float e2 = l2 * EXP2F((m2 - mx) * SC2_);
        float inv = 1.0f / (e1 + e2);
        float w1 = e1 * inv, w2 = e2 * inv;
        b16x8 a = *(const b16x8*)(O1 + row * 64 + ch * 8);
        b16x8 c = *(const b16x8*)(O2 + row * 64 + ch * 8);
        b16x8 o;
        #pragma unroll
        for (int e = 0; e < 8; ++e)
            o[e] = f2bf(w1 * bf2f(a[e]) + w2 * bf2f(c[e]));
        short* dst = Ob + ((size_t)(b * T_ + qi * 64 + row)) * 512 + h * 64 + ch * 8;
        *(b16x8*)dst = o;
    }
}

// ---------------------------------------------------------------------------
extern "C" void kernel_launch(void* const* d_in, const int* in_sizes, int n_in,
                              void* d_out, int out_size, void* d_ws, size_t ws_size,
                              hipStream_t stream) {
    (void)in_sizes; (void)n_in; (void)out_size; (void)ws_size;
    const float* x     = (const float*)d_in[0];
    const float* ln_g  = (const float*)d_in[1];
    const float* ln_b  = (const float*)d_in[2];
    const float* Wq    = (const float*)d_in[3];
    const float* Wk    = (const float*)d_in[4];
    const float* Wv    = (const float*)d_in[5];
    const float* Wproj = (const float*)d_in[6];
    const float* bproj = (const float*)d_in[7];
    const float* W1    = (const float*)d_in[8];
    const float* b1    = (const float*)d_in[9];
    const float* W2    = (const float*)d_in[10];
    const float* b2    = (const float*)d_in[11];
    float* out = (float*)d_out;

    char* W = (char*)d_ws;
    short* hbuf  = (short*)(W + 0);                    // 8 MB  (LN out, bf16)
    short* qkvb  = (short*)(W + ((size_t)8  << 20));   // 24 MB [BT][1536]
    short* attno = (short*)(W + ((size_t)32 << 20));   // 8 MB  [BT][512]
    float* x1    = (float*)(W + ((size_t)40 << 20));   // 16 MB
    short* ff1   = (short*)(W + ((size_t)56 << 20));   // 32 MB [BT][2048]
    short* wqkv  = (short*)(W + ((size_t)88 << 20));   // 1.5 MB [1536][512]
    short* wpt   = (short*)(W + ((size_t)90 << 20));   // 0.5 MB [512][512]
    short* w1t   = (short*)(W + ((size_t)91 << 20));   // 2 MB  [2048][512]
    short* w2t   = (short*)(W + ((size_t)93 << 20));   // 2 MB  [512][2048]
    // attention split-K scratch aliases the ff1 region (dead until step 6):
    short* Opart = (short*)(W + ((size_t)56 << 20));   // 16 MB [2][1024][64][64] bf16
    float* Ml    = (float*)(W + ((size_t)72 << 20));   // 1 MB  [2][1024][2][64] fp32

    // 0. all weight transposes in one launch
    prep_kernel<<<dim3(3072), dim3(32, 8), 0, stream>>>(
        Wq, Wk, Wv, Wproj, W1, W2, wqkv, wpt, w1t, w2t);
    // 1. h = LN(x) -> bf16
    ln_kernel<<<dim3(BT_), dim3(64), 0, stream>>>(x, ln_g, ln_b, hbuf);
    // 2. qkv = h @ Wqkv  [8192,1536] bf16  (grid: M-blocks on x for XCD A-reuse)
    mm_kernel<<<dim3(64, 12), dim3(256), 0, stream>>>(hbuf, wqkv, qkvb,
        nullptr, nullptr, BT_, 1536, D_, 0, 1);
    // 3. attention split-K x2 -> partials, then combine -> attno bf16
    attn_kernel<<<dim3(32, 32, 2), dim3(256), 0, stream>>>(qkvb, Opart, Ml);
    attn_combine_kernel<<<dim3(1024), dim3(256), 0, stream>>>(Opart, Ml, attno);
    // 4. x1 = x + attno @ Wproj + bproj  (fp32)
    mm6464_kernel<<<dim3(128, 8), dim3(256), 0, stream>>>(attno, wpt, x1,
        bproj, x, BT_, D_, D_, 0, 0);
    // 5. h2 = LN(x1) -> bf16 (reuse hbuf)
    ln_kernel<<<dim3(BT_), dim3(64), 0, stream>>>(x1, ln_g, ln_b, hbuf);
    // 6. ff1 = relu(h2 @ W1 + b1)  bf16
    mm_kernel<<<dim3(64, 16), dim3(256), 0, stream>>>(hbuf, w1t, ff1,
        b1, nullptr, BT_, FF_, D_, 1, 1);
    // 7. out = x1 + ff1 @ W2 + b2  (fp32)
    mm64_kernel<<<dim3(64, 8), dim3(256), 0, stream>>>(ff1, w2t, out,
        b2, x1, BT_, D_, FF_, 0, 0);
}

// Round 11
// 276.189 us; speedup vs baseline: 4.7836x; 1.0413x over previous
//
#include <hip/hip_runtime.h>
#include <math.h>

#define B_ 4
#define T_ 2048
#define D_ 512
#define H_ 8
#define DH_ 64
#define BT_ 8192
#define FF_ 2048
#define EPS_ 1e-5f
#define SCALE_ 0.04419417382415922f   // 512^-0.5
#define SC2_ 0.06375861151f           // SCALE_ * log2(e)
#define NEGINF_ -1e30f

typedef short b16x8 __attribute__((ext_vector_type(8)));
typedef short b16x4 __attribute__((ext_vector_type(4)));
typedef float f32x4 __attribute__((ext_vector_type(4)));

#define MFMA16(a, b, c) __builtin_amdgcn_mfma_f32_16x16x32_bf16(a, b, c, 0, 0, 0)
#define MFMA16K16(a, b, c) __builtin_amdgcn_mfma_f32_16x16x16bf16_1k(a, b, c, 0, 0, 0)

#define GLL16(gp, lp) \
    __builtin_amdgcn_global_load_lds((const __attribute__((address_space(1))) void*)(gp), \
                                     (__attribute__((address_space(3))) void*)(lp), 16, 0, 0)

#if __has_builtin(__builtin_amdgcn_exp2f)
#define EXP2F(x) __builtin_amdgcn_exp2f(x)
#else
#define EXP2F(x) exp2f(x)
#endif

// fp32 -> bf16 RNE (finite inputs)
static __device__ inline short f2bf(float f) {
    unsigned int u = __builtin_bit_cast(unsigned int, f);
    unsigned int r = (u + 0x7fffu + ((u >> 16) & 1u)) >> 16;
    return (short)r;
}
// fp32 -> bf16 truncation (1 VALU op; used for P where bias is negligible)
static __device__ inline short f2bf_trunc(float f) {
    return (short)(__builtin_bit_cast(unsigned int, f) >> 16);
}
// bf16 -> fp32
static __device__ inline float bf2f(short s) {
    return __builtin_bit_cast(float, ((unsigned int)(unsigned short)s) << 16);
}

// ---------------------------------------------------------------------------
// LayerNorm: 256 threads = 4 waves, one row per wave (4 rows/block).
// grid = BT/4 = 2048 blocks (was 8192x64 -- cuts launch volume 4x).
// ---------------------------------------------------------------------------
__global__ __launch_bounds__(256) void ln_kernel(const float* __restrict__ X,
        const float* __restrict__ G, const float* __restrict__ Bb,
        short* __restrict__ Y)
{
    int wave = threadIdx.x >> 6, t = threadIdx.x & 63;
    int row = blockIdx.x * 4 + wave;
    const float* xr = X + (size_t)row * D_;
    float4 v0 = *(const float4*)(xr + t * 4);
    float4 v1 = *(const float4*)(xr + 256 + t * 4);
    float sum = v0.x + v0.y + v0.z + v0.w + v1.x + v1.y + v1.z + v1.w;
    float ssq = v0.x*v0.x + v0.y*v0.y + v0.z*v0.z + v0.w*v0.w
              + v1.x*v1.x + v1.y*v1.y + v1.z*v1.z + v1.w*v1.w;
    #pragma unroll
    for (int off = 32; off > 0; off >>= 1) {
        sum += __shfl_down(sum, off);
        ssq += __shfl_down(ssq, off);
    }
    sum = __shfl(sum, 0);
    ssq = __shfl(ssq, 0);
    float mean = sum * (1.0f / D_);
    float var  = ssq * (1.0f / D_) - mean * mean;
    float rstd = rsqrtf(var + EPS_);

    float4 g0 = *(const float4*)(G + t * 4);
    float4 g1 = *(const float4*)(G + 256 + t * 4);
    float4 b0 = *(const float4*)(Bb + t * 4);
    float4 b1 = *(const float4*)(Bb + 256 + t * 4);
    short4 o0, o1;
    o0.x = f2bf((v0.x - mean) * rstd * g0.x + b0.x);
    o0.y = f2bf((v0.y - mean) * rstd * g0.y + b0.y);
    o0.z = f2bf((v0.z - mean) * rstd * g0.z + b0.z);
    o0.w = f2bf((v0.w - mean) * rstd * g0.w + b0.w);
    o1.x = f2bf((v1.x - mean) * rstd * g1.x + b1.x);
    o1.y = f2bf((v1.y - mean) * rstd * g1.y + b1.y);
    o1.z = f2bf((v1.z - mean) * rstd * g1.z + b1.z);
    o1.w = f2bf((v1.w - mean) * rstd * g1.w + b1.w);
    short* yr = Y + (size_t)row * D_;
    *(short4*)(yr + t * 4)       = o0;
    *(short4*)(yr + 256 + t * 4) = o1;
}

// ---------------------------------------------------------------------------
// All weight transposes fused into one launch. 3072 tiles of 32x32.
// block (32,8).
// ---------------------------------------------------------------------------
__global__ __launch_bounds__(256) void prep_kernel(
        const float* __restrict__ Wq, const float* __restrict__ Wk,
        const float* __restrict__ Wv, const float* __restrict__ Wp,
        const float* __restrict__ W1, const float* __restrict__ W2,
        short* __restrict__ wqkv, short* __restrict__ wpt,
        short* __restrict__ w1t, short* __restrict__ w2t)
{
    __shared__ float tile[32][33];
    int idx = blockIdx.x;
    const float* src; short* dst; int R, C, tx0, ty0;
    if (idx < 768) {            // Wq/Wk/Wv: per head [512][64] -> [64][512]
        int w = idx >> 8, rem = idx & 255;
        int hh = rem >> 5, t = rem & 31;
        const float* base = (w == 0) ? Wq : ((w == 1) ? Wk : Wv);
        src = base + hh * (D_ * DH_);
        dst = wqkv + w * (512 * 512) + hh * (DH_ * D_);
        R = 512; C = 64; tx0 = (t & 1) * 32; ty0 = (t >> 1) * 32;
    } else if (idx < 1024) {    // Wproj [512][512]
        int t = idx - 768;
        src = Wp; dst = wpt; R = 512; C = 512;
        tx0 = (t & 15) * 32; ty0 = (t >> 4) * 32;
    } else if (idx < 2048) {    // W1 [512][2048] -> [2048][512]
        int t = idx - 1024;
        src = W1; dst = w1t; R = 512; C = 2048;
        tx0 = (t & 63) * 32; ty0 = (t >> 6) * 32;
    } else {                    // W2 [2048][512] -> [512][2048]
        int t = idx - 2048;
        src = W2; dst = w2t; R = 2048; C = 512;
        tx0 = (t & 15) * 32; ty0 = (t >> 4) * 32;
    }
    int tx = threadIdx.x, ty = threadIdx.y;
    #pragma unroll
    for (int i = 0; i < 32; i += 8)
        tile[ty + i][tx] = src[(size_t)(ty0 + ty + i) * C + tx0 + tx];
    __syncthreads();
    #pragma unroll
    for (int i = 0; i < 32; i += 8)
        dst[(size_t)(tx0 + ty + i) * R + ty0 + tx] = f2bf(tile[tx][ty + i]);
}

// ---------------------------------------------------------------------------
// bf16 MFMA GEMM, 128(M)x64(N), BK=32 dbuf pipeline. grid=(M/128,N/64):
// M-blocks on x -> XCD-pinned A rows (L2-hot). Conflict-free
// f(row)=(row>>1)&3 chunk swizzle (verified: SQ_LDS_BANK_CONFLICT=0).
// Now used for QKV, FFN1, FFN2: 1536-2048 blocks = 6+ blocks/CU for
// latency-hiding TLP (128x128 at 5/CU was latency-starved at ~320 TF).
// ---------------------------------------------------------------------------
__global__ __launch_bounds__(256) void mm64_kernel(const short* __restrict__ A,
        const short* __restrict__ Bt, void* __restrict__ C,
        const float* __restrict__ bias, const float* __restrict__ resid,
        int M, int N, int K, int relu, int out_bf16)
{
    __shared__ short As[2][128 * 32];
    __shared__ short Bs[2][64 * 32];
    const int tid = threadIdx.x;
    const int wave = tid >> 6, lane = tid & 63;
    const int quad = lane >> 4, l15 = lane & 15;
    const int m0 = blockIdx.x * 128, n0 = blockIdx.y * 64;
    const int mw = (wave & 1) * 64, nw = (wave >> 1) * 32;

#define STAGE_M64(bufi, kk) \
    { \
        for (int r = 0; r < 2; ++r) { \
            int c = r * 256 + tid; \
            int row = c >> 2, seg = (c & 3) ^ ((row >> 1) & 3); \
            GLL16(A + (size_t)(m0 + row) * K + (kk) + seg * 8, \
                  As[bufi] + (size_t)(r * 256 + wave * 64) * 8); \
        } \
        { \
            int row = tid >> 2, seg = (tid & 3) ^ ((row >> 1) & 3); \
            GLL16(Bt + (size_t)(n0 + row) * K + (kk) + seg * 8, \
                  Bs[bufi] + (size_t)(wave * 64) * 8); \
        } \
    }

    f32x4 acc[4][2];
    #pragma unroll
    for (int i = 0; i < 4; ++i)
        #pragma unroll
        for (int j = 0; j < 2; ++j)
            acc[i][j] = (f32x4){0.f, 0.f, 0.f, 0.f};

    STAGE_M64(0, 0);
    int buf = 0;
    for (int k0 = 0; k0 < K; k0 += 32) {
        __syncthreads();
        if (k0 + 32 < K) STAGE_M64(buf ^ 1, k0 + 32);
        b16x8 af[4], bf[2];
        #pragma unroll
        for (int i = 0; i < 4; ++i) {
            int row = mw + i * 16 + l15;
            af[i] = *(const b16x8*)(As[buf] + row * 32 + ((quad ^ ((row >> 1) & 3)) * 8));
        }
        #pragma unroll
        for (int j = 0; j < 2; ++j) {
            int row = nw + j * 16 + l15;
            bf[j] = *(const b16x8*)(Bs[buf] + row * 32 + ((quad ^ ((row >> 1) & 3)) * 8));
        }
        #pragma unroll
        for (int i = 0; i < 4; ++i)
            #pragma unroll
            for (int j = 0; j < 2; ++j)
                acc[i][j] = MFMA16(af[i], bf[j], acc[i][j]);
        buf ^= 1;
    }
#undef STAGE_M64

    #pragma unroll
    for (int i = 0; i < 4; ++i) {
        #pragma unroll
        for (int r = 0; r < 4; ++r) {
            size_t row = (size_t)(m0 + mw + i * 16 + quad * 4 + r);
            #pragma unroll
            for (int j = 0; j < 2; ++j) {
                int col = n0 + nw + j * 16 + l15;
                float v = acc[i][j][r];
                if (bias)  v += bias[col];
                if (resid) v += resid[row * N + col];
                if (relu)  v = fmaxf(v, 0.0f);
                if (out_bf16) ((short*)C)[row * N + col] = f2bf(v);
                else          ((float*)C)[row * N + col] = v;
            }
        }
    }
}

// ---------------------------------------------------------------------------
// bf16 MFMA GEMM, 64x64, BK=32 dbuf pipeline (proj). grid = (M/64, N/64).
// Same conflict-free f(row)=(row>>1)&3 swizzle.
// ---------------------------------------------------------------------------
__global__ __launch_bounds__(256) void mm6464_kernel(const short* __restrict__ A,
        const short* __restrict__ Bt, void* __restrict__ C,
        const float* __restrict__ bias, const float* __restrict__ resid,
        int M, int N, int K, int relu, int out_bf16)
{
    __shared__ short As[2][64 * 32];
    __shared__ short Bs[2][64 * 32];
    const int tid = threadIdx.x;
    const int wave = tid >> 6, lane = tid & 63;
    const int quad = lane >> 4, l15 = lane & 15;
    const int m0 = blockIdx.x * 64, n0 = blockIdx.y * 64;
    const int nw = wave * 16;

#define STAGE_M66(bufi, kk) \
    { \
        int row = tid >> 2, seg = (tid & 3) ^ ((row >> 1) & 3); \
        GLL16(A + (size_t)(m0 + row) * K + (kk) + seg * 8, \
              As[bufi] + (size_t)(wave * 64) * 8); \
        GLL16(Bt + (size_t)(n0 + row) * K + (kk) + seg * 8, \
              Bs[bufi] + (size_t)(wave * 64) * 8); \
    }

    f32x4 acc[4];
    #pragma unroll
    for (int i = 0; i < 4; ++i) acc[i] = (f32x4){0.f, 0.f, 0.f, 0.f};

    STAGE_M66(0, 0);
    int buf = 0;
    for (int k0 = 0; k0 < K; k0 += 32) {
        __syncthreads();
        if (k0 + 32 < K) STAGE_M66(buf ^ 1, k0 + 32);
        b16x8 af[4], bf;
        #pragma unroll
        for (int i = 0; i < 4; ++i) {
            int row = i * 16 + l15;
            af[i] = *(const b16x8*)(As[buf] + row * 32 + ((quad ^ ((row >> 1) & 3)) * 8));
        }
        {
            int row = nw + l15;
            bf = *(const b16x8*)(Bs[buf] + row * 32 + ((quad ^ ((row >> 1) & 3)) * 8));
        }
        #pragma unroll
        for (int i = 0; i < 4; ++i)
            acc[i] = MFMA16(af[i], bf, acc[i]);
        buf ^= 1;
    }
#undef STAGE_M66

    #pragma unroll
    for (int i = 0; i < 4; ++i) {
        #pragma unroll
        for (int r = 0; r < 4; ++r) {
            size_t row = (size_t)(m0 + i * 16 + quad * 4 + r);
            int col = n0 + nw + l15;
            float v = acc[i][r];
            if (bias)  v += bias[col];
            if (resid) v += resid[row * N + col];
            if (relu)  v = fmaxf(v, 0.0f);
            if (out_bf16) ((short*)C)[row * N + col] = f2bf(v);
            else          ((float*)C)[row * N + col] = v;
        }
    }
}

// ---------------------------------------------------------------------------
// Flash attention, S^T formulation, SPLIT-K x2. grid (32 bh, 32 qt, 2 split).
// Each block handles half of (bh,qi)'s kj range; writes normalized partial O
// (bf16, [qrow][dh]) + per-row (m,l) fp32 to scratch. Qs aliases the epilogue
// repack buffer (Q frags are hoisted at kj==klo) -> 25.6 KB LDS, 6 blocks/CU.
// ---------------------------------------------------------------------------
__global__ __launch_bounds__(256) void attn_kernel(const short* __restrict__ qkv,
        short* __restrict__ Opart, float* __restrict__ Ml)
{
    __shared__ short Qs[64 * 72];   // [0..64*64): swizzled Q; epilogue: stride-72 repack
    __shared__ short Ks[64 * 64];   // [tok][dh], swizzled
    __shared__ short Vt[64 * 64];   // [dh][tok], granule-swizzled, stride 64

    const int tid = threadIdx.x;
    const int wave = tid >> 6, lane = tid & 63;
    const int quad = lane >> 4, l15 = lane & 15;
    const int bh = blockIdx.x;
    const int qi = 31 - (int)blockIdx.y;
    const int split = blockIdx.z;
    const int b = bh >> 3, h = bh & 7;
    const size_t tok0 = (size_t)b * T_;
    const int qrow_rel = wave * 16 + l15;
    const int half = (qi + 1) >> 1;
    const int klo = split ? half : 0;
    const int khi = split ? qi + 1 : half;
    const int pidx = split * 1024 + bh * 32 + qi;
    short* Op = Opart + (size_t)pidx * 4096;
    float* mlp = Ml + (size_t)pidx * 128;

    if (klo >= khi) {               // empty split (qi==0, split==0)
        for (int i = tid; i < 2048; i += 256) ((int*)Op)[i] = 0;
        if (tid < 64) { mlp[tid] = NEGINF_; mlp[64 + tid] = 0.0f; }
        return;
    }

    // stage Q tile (swizzled)
    #pragma unroll
    for (int r = 0; r < 2; ++r) {
        int c = r * 256 + tid;
        int tk = c >> 3;
        int seg = (c & 7) ^ (tk & 7);
        GLL16(qkv + (tok0 + qi * 64 + tk) * 1536 + h * 64 + seg * 8,
              Qs + (size_t)(r * 256 + wave * 64) * 8);
    }

    float mrow = NEGINF_, lrow = 0.0f;
    f32x4 ot[4];   // O^T: row=dh=dt*16+quad*4+rr, col=qrow=l15
    #pragma unroll
    for (int dt = 0; dt < 4; ++dt) ot[dt] = (f32x4){0.f, 0.f, 0.f, 0.f};

    b16x8 qf[2];

    for (int kj = klo; kj < khi; ++kj) {
        __syncthreads();   // prev-iter LDS reads done (and Q GLL drained on first)
        // stage K tile (swizzled)
        #pragma unroll
        for (int r = 0; r < 2; ++r) {
            int c = r * 256 + tid;
            int tk = c >> 3;
            int seg = (c & 7) ^ (tk & 7);
            GLL16(qkv + (tok0 + kj * 64 + tk) * 1536 + 512 + h * 64 + seg * 8,
                  Ks + (size_t)(r * 256 + wave * 64) * 8);
        }
        // stage V transposed, granule-swizzled: thread = (s 0..7, tp 0..31)
        {
            int s = tid >> 5, tp = tid & 31;
            const short* g0 = qkv + (tok0 + kj * 64 + tp * 2) * 1536 + 1024 + h * 64 + s * 8;
            b16x8 v0 = *(const b16x8*)g0;
            b16x8 v1 = *(const b16x8*)(g0 + 1536);
            int* vo = (int*)Vt;
            int gg = tp >> 1, hlf = tp & 1;
            #pragma unroll
            for (int e = 0; e < 8; ++e) {
                int row = s * 8 + e;
                unsigned int pk = (unsigned int)(unsigned short)v0[e]
                                | ((unsigned int)(unsigned short)v1[e] << 16);
                vo[row * 32 + ((gg ^ (row & 15)) << 1) + hlf] = pk;
            }
        }
        __syncthreads();

        if (kj == klo) {   // Q fragment (B-operand: n=l15=qrow, k=quad*8+j), hoisted
            #pragma unroll
            for (int kb = 0; kb < 2; ++kb) {
                int row = wave * 16 + l15;
                qf[kb] = *(const b16x8*)(Qs + row * 64 + (((kb * 4 + quad) ^ (row & 7)) * 8));
            }
        }

        // S^T = K Q^T  (A=K-frag, B=Q-frag)
        f32x4 st[4];   // mt token-tiles: token = mt*16+quad*4+r, qrow = l15
        #pragma unroll
        for (int mt = 0; mt < 4; ++mt) st[mt] = (f32x4){0.f, 0.f, 0.f, 0.f};
        #pragma unroll
        for (int mt = 0; mt < 4; ++mt) {
            int trow = mt * 16 + l15;
            #pragma unroll
            for (int kb = 0; kb < 2; ++kb) {
                b16x8 kf = *(const b16x8*)(Ks + trow * 64 + (((kb * 4 + quad) ^ (trow & 7)) * 8));
                st[mt] = MFMA16(kf, qf[kb], st[mt]);
            }
        }

        // causal mask + token-max (in-lane 16 + cross-quad 2 shuffles)
        const bool diag = (kj == qi);
        float mx = NEGINF_;
        #pragma unroll
        for (int mt = 0; mt < 4; ++mt)
            #pragma unroll
            for (int r = 0; r < 4; ++r) {
                if (diag && (mt * 16 + quad * 4 + r) > qrow_rel) st[mt][r] = NEGINF_;
                mx = fmaxf(mx, st[mt][r]);
            }
        mx = fmaxf(mx, __shfl_xor(mx, 16));
        mx = fmaxf(mx, __shfl_xor(mx, 32));
        float mn = fmaxf(mrow, mx);
        float alpha = EXP2F((mrow - mn) * SC2_);
        float mnsc = mn * SC2_;
        mrow = mn;
        float rs = 0.0f;
        b16x4 pf[4];   // P^T fragments: directly in 16x16x16 B-operand layout
        #pragma unroll
        for (int mt = 0; mt < 4; ++mt)
            #pragma unroll
            for (int r = 0; r < 4; ++r) {
                float e = EXP2F(fmaf(st[mt][r], SC2_, -mnsc));
                rs += e;
                pf[mt][r] = f2bf_trunc(e);
            }
        rs += __shfl_xor(rs, 16);
        rs += __shfl_xor(rs, 32);
        lrow = lrow * alpha + rs;
        #pragma unroll
        for (int dt = 0; dt < 4; ++dt) {
            ot[dt][0] *= alpha; ot[dt][1] *= alpha;
            ot[dt][2] *= alpha; ot[dt][3] *= alpha;
        }
        // O^T += V^T P^T  (16x16x16; A=V^T-frag from swizzled Vt, B=P^T in regs)
        #pragma unroll
        for (int dt = 0; dt < 4; ++dt) {
            const short* vrow = Vt + (dt * 16 + l15) * 64;
            #pragma unroll
            for (int kt = 0; kt < 4; ++kt) {
                b16x4 vf = *(const b16x4*)(vrow + (((kt * 4 + quad) ^ l15) << 2));
                ot[dt] = MFMA16K16(vf, pf[kt], ot[dt]);
            }
        }
    }

    // epilogue: normalize, repack via same-wave LDS strip (Qs alias), store
    __syncthreads();   // all waves done reading Ks/Vt AND Qs fragments
    float inv = 1.0f / lrow;
    #pragma unroll
    for (int dt = 0; dt < 4; ++dt) {
        b16x4 o4;
        o4[0] = f2bf(ot[dt][0] * inv);
        o4[1] = f2bf(ot[dt][1] * inv);
        o4[2] = f2bf(ot[dt][2] * inv);
        o4[3] = f2bf(ot[dt][3] * inv);
        *(b16x4*)(Qs + (size_t)qrow_rel * 72 + dt * 16 + quad * 4) = o4;
    }
    // rows tid>>2 land inside this wave's own strip -> DS in-order, no barrier
    {
        int row = tid >> 2, ch = tid & 3;
        b16x8 lo = *(const b16x8*)(Qs + (size_t)row * 72 + ch * 16);
        b16x8 hi = *(const b16x8*)(Qs + (size_t)row * 72 + ch * 16 + 8);
        short* dst = Op + row * 64 + ch * 16;
        *(b16x8*)dst = lo;
        *(b16x8*)(dst + 8) = hi;
    }
    if (quad == 0) {
        mlp[qrow_rel] = mrow;
        mlp[64 + qrow_rel] = lrow;
    }
}

// ---------------------------------------------------------------------------
// Combine the two split-K partials: O = w1*O1 + w2*O2,
// w_i = l_i*2^((m_i-mx)*SC2) / sum. grid 1024 (one (bh,qi) per block), 256 thr.
// ---------------------------------------------------------------------------
__global__ __launch_bounds__(256) void attn_combine_kernel(
        const short* __restrict__ Opart, const float* __restrict__ Ml,
        short* __restrict__ Ob)
{
    int pair = blockIdx.x;              // bh*32 + qi
    int bh = pair >> 5, qi = pair & 31;
    int b = bh >> 3, h = bh & 7;
    int tid = threadIdx.x;
    const short* O1 = Opart + (size_t)pair * 4096;
    const short* O2 = Opart + (size_t)(1024 + pair) * 4096;
    const float* ml1 = Ml + (size_t)pair * 128;
    const float* ml2 = Ml + (size_t)(1024 + pair) * 128;
    int ch = tid & 7;                   // 8 shorts per chunk
    #pragma unroll
    for (int it = 0; it < 2; ++it) {
        int row = it * 32 + (tid >> 3);
        float m1 = ml1[row], l1 = ml1[64 + row];
        float m2 = ml2[row], l2 = ml2[64 + row];
        float mx = fmaxf(m1, m2);
        float e1 = l1 * EXP2F((m1 - mx) * SC2_);
        float e2 = l2 * EXP2F((m2 - mx) * SC2_);
        float inv = 1.0f / (e1 + e2);
        float w1 = e1 * inv, w2 = e2 * inv;
        b16x8 a = *(const b16x8*)(O1 + row * 64 + ch * 8);
        b16x8 c = *(const b16x8*)(O2 + row * 64 + ch * 8);
        b16x8 o;
        #pragma unroll
        for (int e = 0; e < 8; ++e)
            o[e] = f2bf(w1 * bf2f(a[e]) + w2 * bf2f(c[e]));
        short* dst = Ob + ((size_t)(b * T_ + qi * 64 + row)) * 512 + h * 64 + ch * 8;
        *(b16x8*)dst = o;
    }
}

// ---------------------------------------------------------------------------
extern "C" void kernel_launch(void* const* d_in, const int* in_sizes, int n_in,
                              void* d_out, int out_size, void* d_ws, size_t ws_size,
                              hipStream_t stream) {
    (void)in_sizes; (void)n_in; (void)out_size; (void)ws_size;
    const float* x     = (const float*)d_in[0];
    const float* ln_g  = (const float*)d_in[1];
    const float* ln_b  = (const float*)d_in[2];
    const float* Wq    = (const float*)d_in[3];
    const float* Wk    = (const float*)d_in[4];
    const float* Wv    = (const float*)d_in[5];
    const float* Wproj = (const float*)d_in[6];
    const float* bproj = (const float*)d_in[7];
    const float* W1    = (const float*)d_in[8];
    const float* b1    = (const float*)d_in[9];
    const float* W2    = (const float*)d_in[10];
    const float* b2    = (const float*)d_in[11];
    float* out = (float*)d_out;

    char* W = (char*)d_ws;
    short* hbuf  = (short*)(W + 0);                    // 8 MB  (LN out, bf16)
    short* qkvb  = (short*)(W + ((size_t)8  << 20));   // 24 MB [BT][1536]
    short* attno = (short*)(W + ((size_t)32 << 20));   // 8 MB  [BT][512]
    float* x1    = (float*)(W + ((size_t)40 << 20));   // 16 MB
    short* ff1   = (short*)(W + ((size_t)56 << 20));   // 32 MB [BT][2048]
    short* wqkv  = (short*)(W + ((size_t)88 << 20));   // 1.5 MB [1536][512]
    short* wpt   = (short*)(W + ((size_t)90 << 20));   // 0.5 MB [512][512]
    short* w1t   = (short*)(W + ((size_t)91 << 20));   // 2 MB  [2048][512]
    short* w2t   = (short*)(W + ((size_t)93 << 20));   // 2 MB  [512][2048]
    // attention split-K scratch aliases the ff1 region (dead until step 6):
    short* Opart = (short*)(W + ((size_t)56 << 20));   // 16 MB [2][1024][64][64] bf16
    float* Ml    = (float*)(W + ((size_t)72 << 20));   // 1 MB  [2][1024][2][64] fp32

    // 0. all weight transposes in one launch
    prep_kernel<<<dim3(3072), dim3(32, 8), 0, stream>>>(
        Wq, Wk, Wv, Wproj, W1, W2, wqkv, wpt, w1t, w2t);
    // 1. h = LN(x) -> bf16
    ln_kernel<<<dim3(BT_ / 4), dim3(256), 0, stream>>>(x, ln_g, ln_b, hbuf);
    // 2. qkv = h @ Wqkv  [8192,1536] bf16  (128x64 tiles -> 1536 blocks, 6/CU)
    mm64_kernel<<<dim3(64, 24), dim3(256), 0, stream>>>(hbuf, wqkv, qkvb,
        nullptr, nullptr, BT_, 1536, D_, 0, 1);
    // 3. attention split-K x2 -> partials, then combine -> attno bf16
    attn_kernel<<<dim3(32, 32, 2), dim3(256), 0, stream>>>(qkvb, Opart, Ml);
    attn_combine_kernel<<<dim3(1024), dim3(256), 0, stream>>>(Opart, Ml, attno);
    // 4. x1 = x + attno @ Wproj + bproj  (fp32)
    mm6464_kernel<<<dim3(128, 8), dim3(256), 0, stream>>>(attno, wpt, x1,
        bproj, x, BT_, D_, D_, 0, 0);
    // 5. h2 = LN(x1) -> bf16 (reuse hbuf)
    ln_kernel<<<dim3(BT_ / 4), dim3(256), 0, stream>>>(x1, ln_g, ln_b, hbuf);
    // 6. ff1 = relu(h2 @ W1 + b1)  bf16  (128x64 tiles -> 2048 blocks, 6/CU)
    mm64_kernel<<<dim3(64, 32), dim3(256), 0, stream>>>(hbuf, w1t, ff1,
        b1, nullptr, BT_, FF_, D_, 1, 1);
    // 7. out = x1 + ff1 @ W2 + b2  (fp32)
    mm64_kernel<<<dim3(64, 8), dim3(256), 0, stream>>>(ff1, w2t, out,
        b2, x1, BT_, D_, FF_, 0, 0);
}

// Round 12
// 268.629 us; speedup vs baseline: 4.9182x; 1.0281x over previous
//
#include <hip/hip_runtime.h>
#include <math.h>

#define B_ 4
#define T_ 2048
#define D_ 512
#define H_ 8
#define DH_ 64
#define BT_ 8192
#define FF_ 2048
#define EPS_ 1e-5f
#define SCALE_ 0.04419417382415922f   // 512^-0.5
#define SC2_ 0.06375861151f           // SCALE_ * log2(e)
#define NEGINF_ -1e30f

typedef short b16x8 __attribute__((ext_vector_type(8)));
typedef short b16x4 __attribute__((ext_vector_type(4)));
typedef float f32x4 __attribute__((ext_vector_type(4)));

#define MFMA16(a, b, c) __builtin_amdgcn_mfma_f32_16x16x32_bf16(a, b, c, 0, 0, 0)
#define MFMA16K16(a, b, c) __builtin_amdgcn_mfma_f32_16x16x16bf16_1k(a, b, c, 0, 0, 0)

#define GLL16(gp, lp) \
    __builtin_amdgcn_global_load_lds((const __attribute__((address_space(1))) void*)(gp), \
                                     (__attribute__((address_space(3))) void*)(lp), 16, 0, 0)

#if __has_builtin(__builtin_amdgcn_exp2f)
#define EXP2F(x) __builtin_amdgcn_exp2f(x)
#else
#define EXP2F(x) exp2f(x)
#endif

// fp32 -> bf16 RNE (finite inputs)
static __device__ inline short f2bf(float f) {
    unsigned int u = __builtin_bit_cast(unsigned int, f);
    unsigned int r = (u + 0x7fffu + ((u >> 16) & 1u)) >> 16;
    return (short)r;
}
// fp32 -> bf16 truncation (1 VALU op; used for P where bias is negligible)
static __device__ inline short f2bf_trunc(float f) {
    return (short)(__builtin_bit_cast(unsigned int, f) >> 16);
}
// bf16 -> fp32
static __device__ inline float bf2f(short s) {
    return __builtin_bit_cast(float, ((unsigned int)(unsigned short)s) << 16);
}

// ---------------------------------------------------------------------------
// LayerNorm: 256 threads = 4 waves, one row per wave (4 rows/block).
// grid = BT/4 = 2048 blocks.
// ---------------------------------------------------------------------------
__global__ __launch_bounds__(256) void ln_kernel(const float* __restrict__ X,
        const float* __restrict__ G, const float* __restrict__ Bb,
        short* __restrict__ Y)
{
    int wave = threadIdx.x >> 6, t = threadIdx.x & 63;
    int row = blockIdx.x * 4 + wave;
    const float* xr = X + (size_t)row * D_;
    float4 v0 = *(const float4*)(xr + t * 4);
    float4 v1 = *(const float4*)(xr + 256 + t * 4);
    float sum = v0.x + v0.y + v0.z + v0.w + v1.x + v1.y + v1.z + v1.w;
    float ssq = v0.x*v0.x + v0.y*v0.y + v0.z*v0.z + v0.w*v0.w
              + v1.x*v1.x + v1.y*v1.y + v1.z*v1.z + v1.w*v1.w;
    #pragma unroll
    for (int off = 32; off > 0; off >>= 1) {
        sum += __shfl_down(sum, off);
        ssq += __shfl_down(ssq, off);
    }
    sum = __shfl(sum, 0);
    ssq = __shfl(ssq, 0);
    float mean = sum * (1.0f / D_);
    float var  = ssq * (1.0f / D_) - mean * mean;
    float rstd = rsqrtf(var + EPS_);

    float4 g0 = *(const float4*)(G + t * 4);
    float4 g1 = *(const float4*)(G + 256 + t * 4);
    float4 b0 = *(const float4*)(Bb + t * 4);
    float4 b1 = *(const float4*)(Bb + 256 + t * 4);
    short4 o0, o1;
    o0.x = f2bf((v0.x - mean) * rstd * g0.x + b0.x);
    o0.y = f2bf((v0.y - mean) * rstd * g0.y + b0.y);
    o0.z = f2bf((v0.z - mean) * rstd * g0.z + b0.z);
    o0.w = f2bf((v0.w - mean) * rstd * g0.w + b0.w);
    o1.x = f2bf((v1.x - mean) * rstd * g1.x + b1.x);
    o1.y = f2bf((v1.y - mean) * rstd * g1.y + b1.y);
    o1.z = f2bf((v1.z - mean) * rstd * g1.z + b1.z);
    o1.w = f2bf((v1.w - mean) * rstd * g1.w + b1.w);
    short* yr = Y + (size_t)row * D_;
    *(short4*)(yr + t * 4)       = o0;
    *(short4*)(yr + 256 + t * 4) = o1;
}

// ---------------------------------------------------------------------------
// All weight transposes fused into one launch. 3072 tiles of 32x32.
// block (32,8).
// ---------------------------------------------------------------------------
__global__ __launch_bounds__(256) void prep_kernel(
        const float* __restrict__ Wq, const float* __restrict__ Wk,
        const float* __restrict__ Wv, const float* __restrict__ Wp,
        const float* __restrict__ W1, const float* __restrict__ W2,
        short* __restrict__ wqkv, short* __restrict__ wpt,
        short* __restrict__ w1t, short* __restrict__ w2t)
{
    __shared__ float tile[32][33];
    int idx = blockIdx.x;
    const float* src; short* dst; int R, C, tx0, ty0;
    if (idx < 768) {            // Wq/Wk/Wv: per head [512][64] -> [64][512]
        int w = idx >> 8, rem = idx & 255;
        int hh = rem >> 5, t = rem & 31;
        const float* base = (w == 0) ? Wq : ((w == 1) ? Wk : Wv);
        src = base + hh * (D_ * DH_);
        dst = wqkv + w * (512 * 512) + hh * (DH_ * D_);
        R = 512; C = 64; tx0 = (t & 1) * 32; ty0 = (t >> 1) * 32;
    } else if (idx < 1024) {    // Wproj [512][512]
        int t = idx - 768;
        src = Wp; dst = wpt; R = 512; C = 512;
        tx0 = (t & 15) * 32; ty0 = (t >> 4) * 32;
    } else if (idx < 2048) {    // W1 [512][2048] -> [2048][512]
        int t = idx - 1024;
        src = W1; dst = w1t; R = 512; C = 2048;
        tx0 = (t & 63) * 32; ty0 = (t >> 6) * 32;
    } else {                    // W2 [2048][512] -> [512][2048]
        int t = idx - 2048;
        src = W2; dst = w2t; R = 2048; C = 512;
        tx0 = (t & 15) * 32; ty0 = (t >> 4) * 32;
    }
    int tx = threadIdx.x, ty = threadIdx.y;
    #pragma unroll
    for (int i = 0; i < 32; i += 8)
        tile[ty + i][tx] = src[(size_t)(ty0 + ty + i) * C + tx0 + tx];
    __syncthreads();
    #pragma unroll
    for (int i = 0; i < 32; i += 8)
        dst[(size_t)(tx0 + ty + i) * R + ty0 + tx] = f2bf(tile[tx][ty + i]);
}

// ---------------------------------------------------------------------------
// bf16 MFMA GEMM, 128(M)x64(N), BK=32 dbuf pipeline. grid=(M/128,N/64):
// M-blocks on x -> XCD-pinned A rows (L2-hot). Conflict-free
// f(row)=(row>>1)&3 chunk swizzle. Used for QKV, FFN1 (6+ blocks/CU).
// ---------------------------------------------------------------------------
__global__ __launch_bounds__(256) void mm64_kernel(const short* __restrict__ A,
        const short* __restrict__ Bt, void* __restrict__ C,
        const float* __restrict__ bias, const float* __restrict__ resid,
        int M, int N, int K, int relu, int out_bf16)
{
    __shared__ short As[2][128 * 32];
    __shared__ short Bs[2][64 * 32];
    const int tid = threadIdx.x;
    const int wave = tid >> 6, lane = tid & 63;
    const int quad = lane >> 4, l15 = lane & 15;
    const int m0 = blockIdx.x * 128, n0 = blockIdx.y * 64;
    const int mw = (wave & 1) * 64, nw = (wave >> 1) * 32;

#define STAGE_M64(bufi, kk) \
    { \
        for (int r = 0; r < 2; ++r) { \
            int c = r * 256 + tid; \
            int row = c >> 2, seg = (c & 3) ^ ((row >> 1) & 3); \
            GLL16(A + (size_t)(m0 + row) * K + (kk) + seg * 8, \
                  As[bufi] + (size_t)(r * 256 + wave * 64) * 8); \
        } \
        { \
            int row = tid >> 2, seg = (tid & 3) ^ ((row >> 1) & 3); \
            GLL16(Bt + (size_t)(n0 + row) * K + (kk) + seg * 8, \
                  Bs[bufi] + (size_t)(wave * 64) * 8); \
        } \
    }

    f32x4 acc[4][2];
    #pragma unroll
    for (int i = 0; i < 4; ++i)
        #pragma unroll
        for (int j = 0; j < 2; ++j)
            acc[i][j] = (f32x4){0.f, 0.f, 0.f, 0.f};

    STAGE_M64(0, 0);
    int buf = 0;
    for (int k0 = 0; k0 < K; k0 += 32) {
        __syncthreads();
        if (k0 + 32 < K) STAGE_M64(buf ^ 1, k0 + 32);
        b16x8 af[4], bf[2];
        #pragma unroll
        for (int i = 0; i < 4; ++i) {
            int row = mw + i * 16 + l15;
            af[i] = *(const b16x8*)(As[buf] + row * 32 + ((quad ^ ((row >> 1) & 3)) * 8));
        }
        #pragma unroll
        for (int j = 0; j < 2; ++j) {
            int row = nw + j * 16 + l15;
            bf[j] = *(const b16x8*)(Bs[buf] + row * 32 + ((quad ^ ((row >> 1) & 3)) * 8));
        }
        #pragma unroll
        for (int i = 0; i < 4; ++i)
            #pragma unroll
            for (int j = 0; j < 2; ++j)
                acc[i][j] = MFMA16(af[i], bf[j], acc[i][j]);
        buf ^= 1;
    }
#undef STAGE_M64

    #pragma unroll
    for (int i = 0; i < 4; ++i) {
        #pragma unroll
        for (int r = 0; r < 4; ++r) {
            size_t row = (size_t)(m0 + mw + i * 16 + quad * 4 + r);
            #pragma unroll
            for (int j = 0; j < 2; ++j) {
                int col = n0 + nw + j * 16 + l15;
                float v = acc[i][j][r];
                if (bias)  v += bias[col];
                if (resid) v += resid[row * N + col];
                if (relu)  v = fmaxf(v, 0.0f);
                if (out_bf16) ((short*)C)[row * N + col] = f2bf(v);
                else          ((float*)C)[row * N + col] = v;
            }
        }
    }
}

// ---------------------------------------------------------------------------
// bf16 MFMA GEMM, 64x64, BK=32 dbuf pipeline (proj, FFN2). grid = (M/64, N/64)
// = 1024 blocks = 4/CU: the TLP-maximizing shape for latency-bound GEMMs.
// Same conflict-free f(row)=(row>>1)&3 swizzle.
// ---------------------------------------------------------------------------
__global__ __launch_bounds__(256) void mm6464_kernel(const short* __restrict__ A,
        const short* __restrict__ Bt, void* __restrict__ C,
        const float* __restrict__ bias, const float* __restrict__ resid,
        int M, int N, int K, int relu, int out_bf16)
{
    __shared__ short As[2][64 * 32];
    __shared__ short Bs[2][64 * 32];
    const int tid = threadIdx.x;
    const int wave = tid >> 6, lane = tid & 63;
    const int quad = lane >> 4, l15 = lane & 15;
    const int m0 = blockIdx.x * 64, n0 = blockIdx.y * 64;
    const int nw = wave * 16;

#define STAGE_M66(bufi, kk) \
    { \
        int row = tid >> 2, seg = (tid & 3) ^ ((row >> 1) & 3); \
        GLL16(A + (size_t)(m0 + row) * K + (kk) + seg * 8, \
              As[bufi] + (size_t)(wave * 64) * 8); \
        GLL16(Bt + (size_t)(n0 + row) * K + (kk) + seg * 8, \
              Bs[bufi] + (size_t)(wave * 64) * 8); \
    }

    f32x4 acc[4];
    #pragma unroll
    for (int i = 0; i < 4; ++i) acc[i] = (f32x4){0.f, 0.f, 0.f, 0.f};

    STAGE_M66(0, 0);
    int buf = 0;
    for (int k0 = 0; k0 < K; k0 += 32) {
        __syncthreads();
        if (k0 + 32 < K) STAGE_M66(buf ^ 1, k0 + 32);
        b16x8 af[4], bf;
        #pragma unroll
        for (int i = 0; i < 4; ++i) {
            int row = i * 16 + l15;
            af[i] = *(const b16x8*)(As[buf] + row * 32 + ((quad ^ ((row >> 1) & 3)) * 8));
        }
        {
            int row = nw + l15;
            bf = *(const b16x8*)(Bs[buf] + row * 32 + ((quad ^ ((row >> 1) & 3)) * 8));
        }
        #pragma unroll
        for (int i = 0; i < 4; ++i)
            acc[i] = MFMA16(af[i], bf, acc[i]);
        buf ^= 1;
    }
#undef STAGE_M66

    #pragma unroll
    for (int i = 0; i < 4; ++i) {
        #pragma unroll
        for (int r = 0; r < 4; ++r) {
            size_t row = (size_t)(m0 + i * 16 + quad * 4 + r);
            int col = n0 + nw + l15;
            float v = acc[i][r];
            if (bias)  v += bias[col];
            if (resid) v += resid[row * N + col];
            if (relu)  v = fmaxf(v, 0.0f);
            if (out_bf16) ((short*)C)[row * N + col] = f2bf(v);
            else          ((float*)C)[row * N + col] = v;
        }
    }
}

// ---------------------------------------------------------------------------
// Flash attention, S^T formulation, SPLIT-K x2. grid (32 bh, 32 qt, 2 split).
// Each block handles half of (bh,qi)'s kj range; writes normalized partial O
// (bf16, [qrow][dh]) + per-row (m,l) fp32 to scratch. Qs aliases the epilogue
// repack buffer (Q frags are hoisted at kj==klo) -> 25.6 KB LDS, 6 blocks/CU.
// ---------------------------------------------------------------------------
__global__ __launch_bounds__(256) void attn_kernel(const short* __restrict__ qkv,
        short* __restrict__ Opart, float* __restrict__ Ml)
{
    __shared__ short Qs[64 * 72];   // [0..64*64): swizzled Q; epilogue: stride-72 repack
    __shared__ short Ks[64 * 64];   // [tok][dh], swizzled
    __shared__ short Vt[64 * 64];   // [dh][tok], granule-swizzled, stride 64

    const int tid = threadIdx.x;
    const int wave = tid >> 6, lane = tid & 63;
    const int quad = lane >> 4, l15 = lane & 15;
    const int bh = blockIdx.x;
    const int qi = 31 - (int)blockIdx.y;
    const int split = blockIdx.z;
    const int b = bh >> 3, h = bh & 7;
    const size_t tok0 = (size_t)b * T_;
    const int qrow_rel = wave * 16 + l15;
    const int half = (qi + 1) >> 1;
    const int klo = split ? half : 0;
    const int khi = split ? qi + 1 : half;
    const int pidx = split * 1024 + bh * 32 + qi;
    short* Op = Opart + (size_t)pidx * 4096;
    float* mlp = Ml + (size_t)pidx * 128;

    if (klo >= khi) {               // empty split (qi==0, split==0)
        for (int i = tid; i < 2048; i += 256) ((int*)Op)[i] = 0;
        if (tid < 64) { mlp[tid] = NEGINF_; mlp[64 + tid] = 0.0f; }
        return;
    }

    // stage Q tile (swizzled)
    #pragma unroll
    for (int r = 0; r < 2; ++r) {
        int c = r * 256 + tid;
        int tk = c >> 3;
        int seg = (c & 7) ^ (tk & 7);
        GLL16(qkv + (tok0 + qi * 64 + tk) * 1536 + h * 64 + seg * 8,
              Qs + (size_t)(r * 256 + wave * 64) * 8);
    }

    float mrow = NEGINF_, lrow = 0.0f;
    f32x4 ot[4];   // O^T: row=dh=dt*16+quad*4+rr, col=qrow=l15
    #pragma unroll
    for (int dt = 0; dt < 4; ++dt) ot[dt] = (f32x4){0.f, 0.f, 0.f, 0.f};

    b16x8 qf[2];

    for (int kj = klo; kj < khi; ++kj) {
        __syncthreads();   // prev-iter LDS reads done (and Q GLL drained on first)
        // stage K tile (swizzled)
        #pragma unroll
        for (int r = 0; r < 2; ++r) {
            int c = r * 256 + tid;
            int tk = c >> 3;
            int seg = (c & 7) ^ (tk & 7);
            GLL16(qkv + (tok0 + kj * 64 + tk) * 1536 + 512 + h * 64 + seg * 8,
                  Ks + (size_t)(r * 256 + wave * 64) * 8);
        }
        // stage V transposed, granule-swizzled: thread = (s 0..7, tp 0..31)
        {
            int s = tid >> 5, tp = tid & 31;
            const short* g0 = qkv + (tok0 + kj * 64 + tp * 2) * 1536 + 1024 + h * 64 + s * 8;
            b16x8 v0 = *(const b16x8*)g0;
            b16x8 v1 = *(const b16x8*)(g0 + 1536);
            int* vo = (int*)Vt;
            int gg = tp >> 1, hlf = tp & 1;
            #pragma unroll
            for (int e = 0; e < 8; ++e) {
                int row = s * 8 + e;
                unsigned int pk = (unsigned int)(unsigned short)v0[e]
                                | ((unsigned int)(unsigned short)v1[e] << 16);
                vo[row * 32 + ((gg ^ (row & 15)) << 1) + hlf] = pk;
            }
        }
        __syncthreads();

        if (kj == klo) {   // Q fragment (B-operand: n=l15=qrow, k=quad*8+j), hoisted
            #pragma unroll
            for (int kb = 0; kb < 2; ++kb) {
                int row = wave * 16 + l15;
                qf[kb] = *(const b16x8*)(Qs + row * 64 + (((kb * 4 + quad) ^ (row & 7)) * 8));
            }
        }

        // S^T = K Q^T  (A=K-frag, B=Q-frag)
        f32x4 st[4];   // mt token-tiles: token = mt*16+quad*4+r, qrow = l15
        #pragma unroll
        for (int mt = 0; mt < 4; ++mt) st[mt] = (f32x4){0.f, 0.f, 0.f, 0.f};
        #pragma unroll
        for (int mt = 0; mt < 4; ++mt) {
            int trow = mt * 16 + l15;
            #pragma unroll
            for (int kb = 0; kb < 2; ++kb) {
                b16x8 kf = *(const b16x8*)(Ks + trow * 64 + (((kb * 4 + quad) ^ (trow & 7)) * 8));
                st[mt] = MFMA16(kf, qf[kb], st[mt]);
            }
        }

        // causal mask + token-max (in-lane 16 + cross-quad 2 shuffles)
        const bool diag = (kj == qi);
        float mx = NEGINF_;
        #pragma unroll
        for (int mt = 0; mt < 4; ++mt)
            #pragma unroll
            for (int r = 0; r < 4; ++r) {
                if (diag && (mt * 16 + quad * 4 + r) > qrow_rel) st[mt][r] = NEGINF_;
                mx = fmaxf(mx, st[mt][r]);
            }
        mx = fmaxf(mx, __shfl_xor(mx, 16));
        mx = fmaxf(mx, __shfl_xor(mx, 32));
        float mn = fmaxf(mrow, mx);
        float alpha = EXP2F((mrow - mn) * SC2_);
        float mnsc = mn * SC2_;
        mrow = mn;
        float rs = 0.0f;
        b16x4 pf[4];   // P^T fragments: directly in 16x16x16 B-operand layout
        #pragma unroll
        for (int mt = 0; mt < 4; ++mt)
            #pragma unroll
            for (int r = 0; r < 4; ++r) {
                float e = EXP2F(fmaf(st[mt][r], SC2_, -mnsc));
                rs += e;
                pf[mt][r] = f2bf_trunc(e);
            }
        rs += __shfl_xor(rs, 16);
        rs += __shfl_xor(rs, 32);
        lrow = lrow * alpha + rs;
        #pragma unroll
        for (int dt = 0; dt < 4; ++dt) {
            ot[dt][0] *= alpha; ot[dt][1] *= alpha;
            ot[dt][2] *= alpha; ot[dt][3] *= alpha;
        }
        // O^T += V^T P^T  (16x16x16; A=V^T-frag from swizzled Vt, B=P^T in regs)
        #pragma unroll
        for (int dt = 0; dt < 4; ++dt) {
            const short* vrow = Vt + (dt * 16 + l15) * 64;
            #pragma unroll
            for (int kt = 0; kt < 4; ++kt) {
                b16x4 vf = *(const b16x4*)(vrow + (((kt * 4 + quad) ^ l15) << 2));
                ot[dt] = MFMA16K16(vf, pf[kt], ot[dt]);
            }
        }
    }

    // epilogue: normalize, repack via same-wave LDS strip (Qs alias), store
    __syncthreads();   // all waves done reading Ks/Vt AND Qs fragments
    float inv = 1.0f / lrow;
    #pragma unroll
    for (int dt = 0; dt < 4; ++dt) {
        b16x4 o4;
        o4[0] = f2bf(ot[dt][0] * inv);
        o4[1] = f2bf(ot[dt][1] * inv);
        o4[2] = f2bf(ot[dt][2] * inv);
        o4[3] = f2bf(ot[dt][3] * inv);
        *(b16x4*)(Qs + (size_t)qrow_rel * 72 + dt * 16 + quad * 4) = o4;
    }
    // rows tid>>2 land inside this wave's own strip -> DS in-order, no barrier
    {
        int row = tid >> 2, ch = tid & 3;
        b16x8 lo = *(const b16x8*)(Qs + (size_t)row * 72 + ch * 16);
        b16x8 hi = *(const b16x8*)(Qs + (size_t)row * 72 + ch * 16 + 8);
        short* dst = Op + row * 64 + ch * 16;
        *(b16x8*)dst = lo;
        *(b16x8*)(dst + 8) = hi;
    }
    if (quad == 0) {
        mlp[qrow_rel] = mrow;
        mlp[64 + qrow_rel] = lrow;
    }
}

// ---------------------------------------------------------------------------
// Combine the two split-K partials: O = w1*O1 + w2*O2,
// w_i = l_i*2^((m_i-mx)*SC2) / sum. grid 1024 (one (bh,qi) per block), 256 thr.
// ---------------------------------------------------------------------------
__global__ __launch_bounds__(256) void attn_combine_kernel(
        const short* __restrict__ Opart, const float* __restrict__ Ml,
        short* __restrict__ Ob)
{
    int pair = blockIdx.x;              // bh*32 + qi
    int bh = pair >> 5, qi = pair & 31;
    int b = bh >> 3, h = bh & 7;
    int tid = threadIdx.x;
    const short* O1 = Opart + (size_t)pair * 4096;
    const short* O2 = Opart + (size_t)(1024 + pair) * 4096;
    const float* ml1 = Ml + (size_t)pair * 128;
    const float* ml2 = Ml + (size_t)(1024 + pair) * 128;
    int ch = tid & 7;                   // 8 shorts per chunk
    #pragma unroll
    for (int it = 0; it < 2; ++it) {
        int row = it * 32 + (tid >> 3);
        float m1 = ml1[row], l1 = ml1[64 + row];
        float m2 = ml2[row], l2 = ml2[64 + row];
        float mx = fmaxf(m1, m2);
        float e1 = l1 * EXP2F((m1 - mx) * SC2_);
        float e2 = l2 * EXP2F((m2 - mx) * SC2_);
        float inv = 1.0f / (e1 + e2);
        float w1 = e1 * inv, w2 = e2 * inv;
        b16x8 a = *(const b16x8*)(O1 + row * 64 + ch * 8);
        b16x8 c = *(const b16x8*)(O2 + row * 64 + ch * 8);
        b16x8 o;
        #pragma unroll
        for (int e = 0; e < 8; ++e)
            o[e] = f2bf(w1 * bf2f(a[e]) + w2 * bf2f(c[e]));
        short* dst = Ob + ((size_t)(b * T_ + qi * 64 + row)) * 512 + h * 64 + ch * 8;
        *(b16x8*)dst = o;
    }
}

// ---------------------------------------------------------------------------
extern "C" void kernel_launch(void* const* d_in, const int* in_sizes, int n_in,
                              void* d_out, int out_size, void* d_ws, size_t ws_size,
                              hipStream_t stream) {
    (void)in_sizes; (void)n_in; (void)out_size; (void)ws_size;
    const float* x     = (const float*)d_in[0];
    const float* ln_g  = (const float*)d_in[1];
    const float* ln_b  = (const float*)d_in[2];
    const float* Wq    = (const float*)d_in[3];
    const float* Wk    = (const float*)d_in[4];
    const float* Wv    = (const float*)d_in[5];
    const float* Wproj = (const float*)d_in[6];
    const float* bproj = (const float*)d_in[7];
    const float* W1    = (const float*)d_in[8];
    const float* b1    = (const float*)d_in[9];
    const float* W2    = (const float*)d_in[10];
    const float* b2    = (const float*)d_in[11];
    float* out = (float*)d_out;

    char* W = (char*)d_ws;
    short* hbuf  = (short*)(W + 0);                    // 8 MB  (LN out, bf16)
    short* qkvb  = (short*)(W + ((size_t)8  << 20));   // 24 MB [BT][1536]
    short* attno = (short*)(W + ((size_t)32 << 20));   // 8 MB  [BT][512]
    float* x1    = (float*)(W + ((size_t)40 << 20));   // 16 MB
    short* ff1   = (short*)(W + ((size_t)56 << 20));   // 32 MB [BT][2048]
    short* wqkv  = (short*)(W + ((size_t)88 << 20));   // 1.5 MB [1536][512]
    short* wpt   = (short*)(W + ((size_t)90 << 20));   // 0.5 MB [512][512]
    short* w1t   = (short*)(W + ((size_t)91 << 20));   // 2 MB  [2048][512]
    short* w2t   = (short*)(W + ((size_t)93 << 20));   // 2 MB  [512][2048]
    // attention split-K scratch aliases the ff1 region (dead until step 6):
    short* Opart = (short*)(W + ((size_t)56 << 20));   // 16 MB [2][1024][64][64] bf16
    float* Ml    = (float*)(W + ((size_t)72 << 20));   // 1 MB  [2][1024][2][64] fp32

    // 0. all weight transposes in one launch
    prep_kernel<<<dim3(3072), dim3(32, 8), 0, stream>>>(
        Wq, Wk, Wv, Wproj, W1, W2, wqkv, wpt, w1t, w2t);
    // 1. h = LN(x) -> bf16
    ln_kernel<<<dim3(BT_ / 4), dim3(256), 0, stream>>>(x, ln_g, ln_b, hbuf);
    // 2. qkv = h @ Wqkv  [8192,1536] bf16  (128x64 tiles -> 1536 blocks, 6/CU)
    mm64_kernel<<<dim3(64, 24), dim3(256), 0, stream>>>(hbuf, wqkv, qkvb,
        nullptr, nullptr, BT_, 1536, D_, 0, 1);
    // 3. attention split-K x2 -> partials, then combine -> attno bf16
    attn_kernel<<<dim3(32, 32, 2), dim3(256), 0, stream>>>(qkvb, Opart, Ml);
    attn_combine_kernel<<<dim3(1024), dim3(256), 0, stream>>>(Opart, Ml, attno);
    // 4. x1 = x + attno @ Wproj + bproj  (fp32)
    mm6464_kernel<<<dim3(128, 8), dim3(256), 0, stream>>>(attno, wpt, x1,
        bproj, x, BT_, D_, D_, 0, 0);
    // 5. h2 = LN(x1) -> bf16 (reuse hbuf)
    ln_kernel<<<dim3(BT_ / 4), dim3(256), 0, stream>>>(x1, ln_g, ln_b, hbuf);
    // 6. ff1 = relu(h2 @ W1 + b1)  bf16  (128x64 tiles -> 2048 blocks, 6/CU)
    mm64_kernel<<<dim3(64, 32), dim3(256), 0, stream>>>(hbuf, w1t, ff1,
        b1, nullptr, BT_, FF_, D_, 1, 1);
    // 7. out = x1 + ff1 @ W2 + b2  (fp32, 64x64 tiles -> 1024 blocks, 4/CU)
    mm6464_kernel<<<dim3(128, 8), dim3(256), 0, stream>>>(ff1, w2t, out,
        b2, x1, BT_, D_, FF_, 0, 0);
}